// Round 17
// baseline (2598.117 us; speedup 1.0000x reference)
//
#include <hip/hip_runtime.h>
#include <math.h>

#define NPAD   16384
#define PADR   254
#define NTOK   16130
#define NPIX   16129
#define SG     127
#define DD     512
#define NH     8
#define CHK    64          // key-chunks per head for a3v

typedef __attribute__((ext_vector_type(8))) short bf16x8;
typedef __attribute__((ext_vector_type(4))) float f32x4;

__device__ __forceinline__ ushort f2bf(float f) {
  uint u = __float_as_uint(f);
  u = (u + 0x7fffu + ((u >> 16) & 1u)) >> 16;
  return (ushort)u;
}

// ---------------- elementwise fp32 -> bf16 (vectorized x8) ----------------
__global__ __launch_bounds__(256) void cvt_bf_kernel(
    const float* __restrict__ src, ushort* __restrict__ dst, int n)
{
  int i = (blockIdx.x * 256 + threadIdx.x) * 8;
  if (i >= n) return;
  float4 a = *(const float4*)(src + i);
  float4 b = *(const float4*)(src + i + 4);
  bf16x8 v;
  v[0] = f2bf(a.x); v[1] = f2bf(a.y); v[2] = f2bf(a.z); v[3] = f2bf(a.w);
  v[4] = f2bf(b.x); v[5] = f2bf(b.y); v[6] = f2bf(b.z); v[7] = f2bf(b.w);
  *(bf16x8*)(dst + i) = v;
}

// ---------------- weight transpose+cvt: src fp32 [K][N] -> dst bf16 [N][K] ----------------
__global__ __launch_bounds__(256) void wtrans_bf(
    const float* __restrict__ src, ushort* __restrict__ dst, int K, int N)
{
  __shared__ float tile[32][33];
  int tx = threadIdx.x & 31, ty = threadIdx.x >> 5;   // 32 x 8
#pragma unroll
  for (int i = 0; i < 4; ++i) {
    int k = blockIdx.y * 32 + ty + i * 8, n = blockIdx.x * 32 + tx;
    tile[ty + i * 8][tx] = src[(size_t)k * N + n];
  }
  __syncthreads();
#pragma unroll
  for (int i = 0; i < 4; ++i) {
    int n = blockIdx.x * 32 + ty + i * 8, k = blockIdx.y * 32 + tx;
    dst[(size_t)n * K + k] = f2bf(tile[tx][ty + i * 8]);
  }
}

// ---------------- bf16 MFMA GEMM (bf16 A): C fp32 = A_bf16 @ Bt_bf16^T ----------------
__global__ __launch_bounds__(256) void gemm_bb(
    const ushort* __restrict__ A, int lda,
    const ushort* __restrict__ Bt, int ldb,
    float* __restrict__ C, int ldc,
    int M, int K, int mode, const float* __restrict__ bias)
{
  const int t = threadIdx.x;
  const int w = t >> 6, l = t & 63, lr = l & 15, lg = l >> 4;
  const int wr = w >> 1, wc = w & 1;
  const int m0 = blockIdx.y * 128, n0 = blockIdx.x * 128;
  __shared__ __align__(16) ushort As[128 * 64];
  __shared__ __align__(16) ushort Bs[128 * 64];
  f32x4 acc[4][4];
#pragma unroll
  for (int i = 0; i < 4; ++i)
#pragma unroll
    for (int j = 0; j < 4; ++j) acc[i][j] = (f32x4){0.f, 0.f, 0.f, 0.f};

  for (int k0 = 0; k0 < K; k0 += 64) {
    __syncthreads();
#pragma unroll
    for (int i = 0; i < 4; ++i) {
      int id = t + i * 256;
      int r = id >> 3, blk = id & 7;
      int gr = m0 + r;
      bf16x8 v = (bf16x8){0, 0, 0, 0, 0, 0, 0, 0};
      if (gr < M) v = *(const bf16x8*)(A + (size_t)gr * lda + k0 + blk * 8);
      *(bf16x8*)(As + r * 64 + ((blk ^ (r & 7)) << 3)) = v;
    }
#pragma unroll
    for (int i = 0; i < 4; ++i) {
      int id = t + i * 256;
      int r = id >> 3, blk = id & 7;
      bf16x8 v = *(const bf16x8*)(Bt + (size_t)(n0 + r) * ldb + k0 + blk * 8);
      *(bf16x8*)(Bs + r * 64 + ((blk ^ (r & 7)) << 3)) = v;
    }
    __syncthreads();
    bf16x8 af[4][2], bfr[4][2];
#pragma unroll
    for (int rt = 0; rt < 4; ++rt) {
      int row = wr * 64 + rt * 16 + lr;
#pragma unroll
      for (int kc = 0; kc < 2; ++kc)
        af[rt][kc] = *(const bf16x8*)(As + row * 64 + (((kc * 4 + lg) ^ (row & 7)) << 3));
    }
#pragma unroll
    for (int nt = 0; nt < 4; ++nt) {
      int row = wc * 64 + nt * 16 + lr;
#pragma unroll
      for (int kc = 0; kc < 2; ++kc)
        bfr[nt][kc] = *(const bf16x8*)(Bs + row * 64 + (((kc * 4 + lg) ^ (row & 7)) << 3));
    }
#pragma unroll
    for (int rt = 0; rt < 4; ++rt)
#pragma unroll
      for (int nt = 0; nt < 4; ++nt) {
        acc[rt][nt] = __builtin_amdgcn_mfma_f32_16x16x32_bf16(af[rt][0], bfr[nt][0], acc[rt][nt], 0, 0, 0);
        acc[rt][nt] = __builtin_amdgcn_mfma_f32_16x16x32_bf16(af[rt][1], bfr[nt][1], acc[rt][nt], 0, 0, 0);
      }
  }
#pragma unroll
  for (int rt = 0; rt < 4; ++rt) {
#pragma unroll
    for (int r = 0; r < 4; ++r) {
      int gi = m0 + wr * 64 + rt * 16 + lg * 4 + r;
      if (gi >= M) continue;
#pragma unroll
      for (int nt = 0; nt < 4; ++nt) {
        int gj = n0 + wc * 64 + nt * 16 + lr;
        float d = acc[rt][nt][r];
        if (mode == 1) d = fmaxf(d + bias[gj], 0.f);
        else if (mode == 2) { if (gj < 512) d *= 0.125f; }
        else if (mode == 3) d += C[(size_t)gi * ldc + gj] + bias[gj];
        C[(size_t)gi * ldc + gj] = d;
      }
    }
  }
}

// ---------------- bf16 MFMA GEMM (fp32 A): C fp32 = A_f32 @ Bt_bf16^T ----------------
__global__ __launch_bounds__(256) void gemm_bt(
    const float* __restrict__ A, int lda,
    const ushort* __restrict__ Bt, int ldb,
    float* __restrict__ C, int ldc,
    int M, int K, int mode, const float* __restrict__ bias)
{
  const int t = threadIdx.x;
  const int w = t >> 6, l = t & 63, lr = l & 15, lg = l >> 4;
  const int wr = w >> 1, wc = w & 1;
  const int m0 = blockIdx.y * 128, n0 = blockIdx.x * 128;
  __shared__ __align__(16) ushort As[128 * 64];
  __shared__ __align__(16) ushort Bs[128 * 64];
  f32x4 acc[4][4];
#pragma unroll
  for (int i = 0; i < 4; ++i)
#pragma unroll
    for (int j = 0; j < 4; ++j) acc[i][j] = (f32x4){0.f, 0.f, 0.f, 0.f};

  for (int k0 = 0; k0 < K; k0 += 64) {
    __syncthreads();
#pragma unroll
    for (int i = 0; i < 2; ++i) {
      int id = t + i * 256;
      int r = id >> 2, db = id & 3;
      const float* src = A + (size_t)(m0 + r) * lda + k0 + db * 16;
      float4 g0 = *(const float4*)(src + 0);
      float4 g1 = *(const float4*)(src + 4);
      float4 g2 = *(const float4*)(src + 8);
      float4 g3 = *(const float4*)(src + 12);
      bf16x8 e0, e1;
      e0[0] = f2bf(g0.x); e0[1] = f2bf(g0.y); e0[2] = f2bf(g0.z); e0[3] = f2bf(g0.w);
      e0[4] = f2bf(g1.x); e0[5] = f2bf(g1.y); e0[6] = f2bf(g1.z); e0[7] = f2bf(g1.w);
      e1[0] = f2bf(g2.x); e1[1] = f2bf(g2.y); e1[2] = f2bf(g2.z); e1[3] = f2bf(g2.w);
      e1[4] = f2bf(g3.x); e1[5] = f2bf(g3.y); e1[6] = f2bf(g3.z); e1[7] = f2bf(g3.w);
      ushort* dst = As + r * 64;
      *(bf16x8*)(dst + (((db * 2 + 0) ^ (r & 7)) << 3)) = e0;
      *(bf16x8*)(dst + (((db * 2 + 1) ^ (r & 7)) << 3)) = e1;
    }
#pragma unroll
    for (int i = 0; i < 4; ++i) {
      int id = t + i * 256;
      int r = id >> 3, blk = id & 7;
      bf16x8 v = *(const bf16x8*)(Bt + (size_t)(n0 + r) * ldb + k0 + blk * 8);
      *(bf16x8*)(Bs + r * 64 + ((blk ^ (r & 7)) << 3)) = v;
    }
    __syncthreads();
    bf16x8 af[4][2], bfr[4][2];
#pragma unroll
    for (int rt = 0; rt < 4; ++rt) {
      int row = wr * 64 + rt * 16 + lr;
#pragma unroll
      for (int kc = 0; kc < 2; ++kc)
        af[rt][kc] = *(const bf16x8*)(As + row * 64 + (((kc * 4 + lg) ^ (row & 7)) << 3));
    }
#pragma unroll
    for (int nt = 0; nt < 4; ++nt) {
      int row = wc * 64 + nt * 16 + lr;
#pragma unroll
      for (int kc = 0; kc < 2; ++kc)
        bfr[nt][kc] = *(const bf16x8*)(Bs + row * 64 + (((kc * 4 + lg) ^ (row & 7)) << 3));
    }
#pragma unroll
    for (int rt = 0; rt < 4; ++rt)
#pragma unroll
      for (int nt = 0; nt < 4; ++nt) {
        acc[rt][nt] = __builtin_amdgcn_mfma_f32_16x16x32_bf16(af[rt][0], bfr[nt][0], acc[rt][nt], 0, 0, 0);
        acc[rt][nt] = __builtin_amdgcn_mfma_f32_16x16x32_bf16(af[rt][1], bfr[nt][1], acc[rt][nt], 0, 0, 0);
      }
  }
#pragma unroll
  for (int rt = 0; rt < 4; ++rt) {
#pragma unroll
    for (int r = 0; r < 4; ++r) {
      int gi = m0 + wr * 64 + rt * 16 + lg * 4 + r;
      if (gi >= M) continue;
#pragma unroll
      for (int nt = 0; nt < 4; ++nt) {
        int gj = n0 + wc * 64 + nt * 16 + lr;
        float d = acc[rt][nt][r];
        if (mode == 1) d = fmaxf(d + bias[gj], 0.f);
        else if (mode == 2) { if (gj < 512) d *= 0.125f; }
        else if (mode == 3) d += C[(size_t)gi * ldc + gj] + bias[gj];
        C[(size_t)gi * ldc + gj] = d;
      }
    }
  }
}

// ---------------- pinv: whole Newton chain in ONE BLOCK PER HEAD ----------------
// grid (8); block 1024 = 16 waves (4x4 of 64x64 output tiles). No cross-block
// communication at all: stages separated by __syncthreads (compiler drains
// vmcnt before s_barrier; a single block lives on one CU/XCD so its global
// writes are visible to its own subsequent reads). Round-15/16 lesson:
// cross-XCD barrier visibility is ~29us/phase -- unusable at this granularity.
// k-chunk/MFMA order identical to the old nmm kernel -> bitwise-same results.
__device__ __forceinline__ void mm256(
    const float* Ah, const float* Bh, float* Ch, int mode,
    ushort* As, ushort* Bs)
{
  const int t = threadIdx.x;
  const int w = t >> 6, l = t & 63, lr = l & 15, lg = l >> 4;
  const int wr = w >> 2, wc = w & 3;
  f32x4 acc[4][4];
#pragma unroll
  for (int i = 0; i < 4; ++i)
#pragma unroll
    for (int j = 0; j < 4; ++j) acc[i][j] = (f32x4){0.f, 0.f, 0.f, 0.f};

  for (int k0 = 0; k0 < 256; k0 += 64) {
    __syncthreads();
    // stage A (fp32->bf16): 256 rows x 4 chunks of 16 = 1024 tasks, 1/thread
    {
      int r = t >> 2, db = t & 3;
      const float* src = Ah + (size_t)r * 256 + k0 + db * 16;
      float4 g0 = *(const float4*)(src + 0);
      float4 g1 = *(const float4*)(src + 4);
      float4 g2 = *(const float4*)(src + 8);
      float4 g3 = *(const float4*)(src + 12);
      bf16x8 e0, e1;
      e0[0] = f2bf(g0.x); e0[1] = f2bf(g0.y); e0[2] = f2bf(g0.z); e0[3] = f2bf(g0.w);
      e0[4] = f2bf(g1.x); e0[5] = f2bf(g1.y); e0[6] = f2bf(g1.z); e0[7] = f2bf(g1.w);
      e1[0] = f2bf(g2.x); e1[1] = f2bf(g2.y); e1[2] = f2bf(g2.z); e1[3] = f2bf(g2.w);
      e1[4] = f2bf(g3.x); e1[5] = f2bf(g3.y); e1[6] = f2bf(g3.z); e1[7] = f2bf(g3.w);
      ushort* dst = As + r * 64;
      *(bf16x8*)(dst + (((db * 2 + 0) ^ (r & 7)) << 3)) = e0;
      *(bf16x8*)(dst + (((db * 2 + 1) ^ (r & 7)) << 3)) = e1;
    }
    // stage B transposed: 64 k-rows x 64 float4 (256 n) = 4096 tasks, 4/thread
#pragma unroll
    for (int i = 0; i < 4; ++i) {
      int id = t + i * 1024;
      int k = id >> 6, q = id & 63;
      float4 v = *(const float4*)(Bh + (size_t)(k0 + k) * 256 + q * 4);
      int kb = k >> 3, ke = k & 7;
      Bs[(q * 4 + 0) * 64 + ((kb ^ ((q * 4 + 0) & 7)) << 3) + ke] = f2bf(v.x);
      Bs[(q * 4 + 1) * 64 + ((kb ^ ((q * 4 + 1) & 7)) << 3) + ke] = f2bf(v.y);
      Bs[(q * 4 + 2) * 64 + ((kb ^ ((q * 4 + 2) & 7)) << 3) + ke] = f2bf(v.z);
      Bs[(q * 4 + 3) * 64 + ((kb ^ ((q * 4 + 3) & 7)) << 3) + ke] = f2bf(v.w);
    }
    __syncthreads();
    bf16x8 af[4][2], bfr[4][2];
#pragma unroll
    for (int rt = 0; rt < 4; ++rt) {
      int row = wr * 64 + rt * 16 + lr;
#pragma unroll
      for (int kc = 0; kc < 2; ++kc)
        af[rt][kc] = *(const bf16x8*)(As + row * 64 + (((kc * 4 + lg) ^ (row & 7)) << 3));
    }
#pragma unroll
    for (int nt = 0; nt < 4; ++nt) {
      int row = wc * 64 + nt * 16 + lr;
#pragma unroll
      for (int kc = 0; kc < 2; ++kc)
        bfr[nt][kc] = *(const bf16x8*)(Bs + row * 64 + (((kc * 4 + lg) ^ (row & 7)) << 3));
    }
#pragma unroll
    for (int rt = 0; rt < 4; ++rt)
#pragma unroll
      for (int nt = 0; nt < 4; ++nt) {
        acc[rt][nt] = __builtin_amdgcn_mfma_f32_16x16x32_bf16(af[rt][0], bfr[nt][0], acc[rt][nt], 0, 0, 0);
        acc[rt][nt] = __builtin_amdgcn_mfma_f32_16x16x32_bf16(af[rt][1], bfr[nt][1], acc[rt][nt], 0, 0, 0);
      }
  }
#pragma unroll
  for (int rt = 0; rt < 4; ++rt) {
#pragma unroll
    for (int r = 0; r < 4; ++r) {
      int gi = wr * 64 + rt * 16 + lg * 4 + r;
#pragma unroll
      for (int nt = 0; nt < 4; ++nt) {
        int gj = wc * 64 + nt * 16 + lr;
        float d = acc[rt][nt][r];
        if (mode == 1)      d = 7.f * Ah[(size_t)gi * 256 + gj] - d;
        else if (mode == 2) d = 15.f * Ah[(size_t)gi * 256 + gj] - d;
        else if (mode == 3) d = 0.25f * (13.f * Ah[(size_t)gi * 256 + gj] - d);
        Ch[(size_t)gi * 256 + gj] = d;
      }
    }
  }
}

__global__ __launch_bounds__(1024) void pinv_head(
    const float* __restrict__ a2, const float* __restrict__ red,
    float* __restrict__ z0, float* __restrict__ z1,
    float* __restrict__ xzb, float* __restrict__ tb, float* __restrict__ ub)
{
  __shared__ __align__(16) ushort As[256 * 64];   // 32 KB
  __shared__ __align__(16) ushort Bs[256 * 64];   // 32 KB
  const int h_ = blockIdx.x;
  const float* a2h = a2 + (size_t)h_ * 65536;
  float* z0h = z0 + (size_t)h_ * 65536;
  float* z1h = z1 + (size_t)h_ * 65536;
  float* xzh = xzb + (size_t)h_ * 65536;
  float* tbh = tb + (size_t)h_ * 65536;
  float* ubh = ub + (size_t)h_ * 65536;

  // init: z0 = a2^T * inv (64 elems/thread)
  {
    float inv = red[16];
    int t = threadIdx.x;
#pragma unroll 1
    for (int e = 0; e < 64; ++e) {
      int idx = e * 1024 + t;
      int i = idx >> 8, j = idx & 255;
      z0h[(size_t)i * 256 + j] = a2h[(size_t)j * 256 + i] * inv;
    }
  }

  float* zc = z0h; float* zn = z1h;
  for (int it = 0; it < 6; ++it) {
    mm256(a2h, zc, xzh, 0, As, Bs);   // xz = a2 @ z
    mm256(xzh, xzh, tbh, 1, As, Bs);  // t = 7xz - xz@xz
    mm256(xzh, tbh, ubh, 2, As, Bs);  // u = 15xz - xz@t
    mm256(zc, ubh, zn, 3, As, Bs);    // z' = .25(13z - z@u)
    float* sw = zc; zc = zn; zn = sw;
  }
  // final z lands in z0 (6 swaps)
}

// ---------------- assemble: h[0]=cls, h[16001+i]=h[1+i] (i<129) ----------------
__global__ __launch_bounds__(256) void assemble_kernel(float* __restrict__ h,
                                                       const float* __restrict__ cls)
{
  int idx = blockIdx.x * 256 + threadIdx.x;
  if (idx < 512) { h[idx] = cls[idx]; return; }
  idx -= 512;
  int i = idx >> 9, c = idx & 511;
  h[(size_t)(16001 + i) * DD + c] = h[(size_t)(1 + i) * DD + c];
}

// ---------------- LayerNorm rows of h -> xn (bf16 out; front-padded) ----------------
__global__ __launch_bounds__(256) void ln_pad_kernel(
    const float* __restrict__ h, ushort* __restrict__ xn,
    const float* __restrict__ g, const float* __restrict__ b)
{
  int row = blockIdx.x;
  int t = threadIdx.x;
  if (row < PADR) {
    xn[(size_t)row * DD + t] = 0;
    xn[(size_t)row * DD + t + 256] = 0;
    return;
  }
  const float* x = h + (size_t)(row - PADR) * DD;
  __shared__ float red[256];
  float v0 = x[t], v1 = x[t + 256];
  red[t] = v0 + v1;
  __syncthreads();
  for (int s = 128; s > 0; s >>= 1) { if (t < s) red[t] += red[t + s]; __syncthreads(); }
  float mu = red[0] * (1.f / 512.f);
  __syncthreads();
  float d0 = v0 - mu, d1 = v1 - mu;
  red[t] = d0 * d0 + d1 * d1;
  __syncthreads();
  for (int s = 128; s > 0; s >>= 1) { if (t < s) red[t] += red[t + s]; __syncthreads(); }
  float rs = rsqrtf(red[0] * (1.f / 512.f) + 1e-5f);
  ushort* o = xn + (size_t)row * DD;
  o[t]       = f2bf(d0 * rs * g[t] + b[t]);
  o[t + 256] = f2bf(d1 * rs * g[t + 256] + b[t + 256]);
}

// ---------------- landmarks ----------------
__global__ __launch_bounds__(256) void landmark_kernel(
    const float* __restrict__ qkv, float* __restrict__ ql, float* __restrict__ kl)
{
  int i = blockIdx.x;
  int c = blockIdx.y * 256 + threadIdx.x;
  const float* p = qkv + (size_t)(i * 64) * 1536 + c;
  float s = 0.f;
  for (int j = 0; j < 64; ++j) s += p[(size_t)j * 1536];
  s *= (1.f / 64.f);
  if (c < 512) ql[(size_t)i * 512 + c] = s;
  else         kl[(size_t)i * 512 + (c - 512)] = s;
}

// ---------------- a2 = softmax(ql . kl^T) per head ----------------
__global__ __launch_bounds__(256) void a2_kernel(
    const float* __restrict__ ql, const float* __restrict__ kl, float* __restrict__ a2)
{
  int h_ = blockIdx.x, i = blockIdx.y;
  int t = threadIdx.x;
  __shared__ float q[64];
  __shared__ float red[256];
  if (t < 64) q[t] = ql[(size_t)i * 512 + h_ * 64 + t];
  __syncthreads();
  const float* kr = kl + (size_t)t * 512 + h_ * 64;
  float s = 0.f;
#pragma unroll
  for (int d = 0; d < 64; ++d) s = fmaf(q[d], kr[d], s);
  red[t] = s;
  __syncthreads();
  for (int st = 128; st > 0; st >>= 1) { if (t < st) red[t] = fmaxf(red[t], red[t + st]); __syncthreads(); }
  float mx = red[0];
  __syncthreads();
  float e = __expf(s - mx);
  red[t] = e;
  __syncthreads();
  for (int st = 128; st > 0; st >>= 1) { if (t < st) red[t] += red[t + st]; __syncthreads(); }
  a2[((size_t)h_ * 256 + i) * 256 + t] = e / red[0];
}

// ---------------- pinv init reductions ----------------
__global__ __launch_bounds__(256) void pinv_red1(const float* __restrict__ a2, float* __restrict__ red)
{
  int h_ = blockIdx.x, t = threadIdx.x;
  const float* X = a2 + (size_t)h_ * 65536;
  float rs = 0.f, cs = 0.f;
  for (int j = 0; j < 256; ++j) rs += fabsf(X[(size_t)t * 256 + j]);
  for (int i = 0; i < 256; ++i) cs += fabsf(X[(size_t)i * 256 + t]);
  __shared__ float r1[256], r2[256];
  r1[t] = rs; r2[t] = cs;
  __syncthreads();
  for (int s = 128; s > 0; s >>= 1) {
    if (t < s) { r1[t] = fmaxf(r1[t], r1[t + s]); r2[t] = fmaxf(r2[t], r2[t + s]); }
    __syncthreads();
  }
  if (t == 0) { red[h_ * 2] = r1[0]; red[h_ * 2 + 1] = r2[0]; }
}
__global__ void pinv_red2(float* __restrict__ red)
{
  float mr = 0.f, mc = 0.f;
  for (int h_ = 0; h_ < 8; ++h_) { mr = fmaxf(mr, red[h_ * 2]); mc = fmaxf(mc, red[h_ * 2 + 1]); }
  red[16] = 1.f / (mr * mc);
}

// ---------------- batched matmul per head: C = alpha*(A @ B), A 256x256, B 256xN ----------------
__global__ __launch_bounds__(256) void mmb_kernel(
    const float* __restrict__ A, const float* __restrict__ B, float* __restrict__ C,
    int N, float alpha)
{
  int h_ = blockIdx.z;
  const float* Ah = A + (size_t)h_ * 256 * 256;
  const float* Bh = B + (size_t)h_ * 256 * N;
  float* Ch = C + (size_t)h_ * 256 * N;
  int m0 = blockIdx.y * 64, n0 = blockIdx.x * 64;
  __shared__ float As[16][68];
  __shared__ float Bs[16][68];
  int tid = threadIdx.x, tx = tid & 15, ty = tid >> 4;
  float acc[4][4];
#pragma unroll
  for (int i = 0; i < 4; ++i)
#pragma unroll
    for (int j = 0; j < 4; ++j) acc[i][j] = 0.f;
  for (int k0 = 0; k0 < 256; k0 += 16) {
    {
      int row = tid >> 2, k4 = (tid & 3) << 2;
      float4 v = *(const float4*)(Ah + (size_t)(m0 + row) * 256 + k0 + k4);
      As[k4 + 0][row] = v.x; As[k4 + 1][row] = v.y;
      As[k4 + 2][row] = v.z; As[k4 + 3][row] = v.w;
    }
    {
      int row = tid >> 4, c4 = (tid & 15) << 2;
      *(float4*)&Bs[row][c4] = *(const float4*)(Bh + (size_t)(k0 + row) * N + n0 + c4);
    }
    __syncthreads();
#pragma unroll
    for (int k = 0; k < 16; ++k) {
      float a[4], b[4];
      *(float4*)a = *(const float4*)&As[k][ty * 4];
      *(float4*)b = *(const float4*)&Bs[k][tx * 4];
#pragma unroll
      for (int i = 0; i < 4; ++i)
#pragma unroll
        for (int j = 0; j < 4; ++j) acc[i][j] = fmaf(a[i], b[j], acc[i][j]);
    }
    __syncthreads();
  }
#pragma unroll
  for (int i = 0; i < 4; ++i) {
    float4 r;
    r.x = alpha * acc[i][0]; r.y = alpha * acc[i][1];
    r.z = alpha * acc[i][2]; r.w = alpha * acc[i][3];
    *(float4*)(Ch + (size_t)(m0 + ty * 4 + i) * N + n0 + tx * 4) = r;
  }
}

// ---------------- a3@v partials via bf16 MFMA flash (no-max exp, ones-column den) ----------
__global__ __launch_bounds__(256) void a3v_mfma(
    const float* __restrict__ qkv, const float* __restrict__ ql,
    float* __restrict__ pacc, float* __restrict__ den)
{
  const int h_ = blockIdx.x;
  const int ch = blockIdx.y;
  const int t  = threadIdx.x;
  const int w  = t >> 6;
  const int l  = t & 63;
  const int lr = l & 15;
  const int lg = l >> 4;

  __shared__ __align__(16) ushort kls[64 * 64];
  __shared__ __align__(16) ushort vls[80 * 64];
  __shared__ __align__(16) ushort pls[4][64 * 64];

  bf16x8 qf[4][2];
#pragma unroll
  for (int rt = 0; rt < 4; ++rt)
#pragma unroll
    for (int dc = 0; dc < 2; ++dc) {
      const float* p = ql + (size_t)(64 * w + rt * 16 + lr) * 512 + h_ * 64 + dc * 32 + lg * 8;
      float4 f0 = *(const float4*)p;
      float4 f1 = *(const float4*)(p + 4);
      bf16x8 v;
      v[0] = f2bf(f0.x); v[1] = f2bf(f0.y); v[2] = f2bf(f0.z); v[3] = f2bf(f0.w);
      v[4] = f2bf(f1.x); v[5] = f2bf(f1.y); v[6] = f2bf(f1.z); v[7] = f2bf(f1.w);
      qf[rt][dc] = v;
    }

  if (t < 128) {
    int rr = t >> 3, cb = t & 7;
    ushort val = (rr == 0) ? (ushort)0x3f80 : (ushort)0;
    bf16x8 vv;
#pragma unroll
    for (int k = 0; k < 8; ++k) vv[k] = (short)val;
    *(bf16x8*)(vls + (64 + rr) * 64 + ((cb ^ (rr & 7)) << 3)) = vv;
  }

  f32x4 acc[4][5];
#pragma unroll
  for (int rt = 0; rt < 4; ++rt)
#pragma unroll
    for (int dt = 0; dt < 5; ++dt) acc[rt][dt] = (f32x4){0.f, 0.f, 0.f, 0.f};

  const int j0base = ch * 256;
  for (int jt = 0; jt < 4; ++jt) {
    const int j0 = j0base + jt * 64;
    __syncthreads();
    {
      int r = t >> 2, db = t & 3;
      const float* src = qkv + (size_t)(j0 + r) * 1536 + 512 + h_ * 64 + db * 16;
      float4 g0 = *(const float4*)(src + 0);
      float4 g1 = *(const float4*)(src + 4);
      float4 g2 = *(const float4*)(src + 8);
      float4 g3 = *(const float4*)(src + 12);
      bf16x8 e0, e1;
      e0[0] = f2bf(g0.x); e0[1] = f2bf(g0.y); e0[2] = f2bf(g0.z); e0[3] = f2bf(g0.w);
      e0[4] = f2bf(g1.x); e0[5] = f2bf(g1.y); e0[6] = f2bf(g1.z); e0[7] = f2bf(g1.w);
      e1[0] = f2bf(g2.x); e1[1] = f2bf(g2.y); e1[2] = f2bf(g2.z); e1[3] = f2bf(g2.w);
      e1[4] = f2bf(g3.x); e1[5] = f2bf(g3.y); e1[6] = f2bf(g3.z); e1[7] = f2bf(g3.w);
      ushort* base = kls + r * 64;
      *(bf16x8*)(base + (((db * 2 + 0) ^ (r & 7)) << 3)) = e0;
      *(bf16x8*)(base + (((db * 2 + 1) ^ (r & 7)) << 3)) = e1;
    }
    {
      int d = t & 63, jg = t >> 6;
#pragma unroll
      for (int half = 0; half < 2; ++half) {
        int jb = jg + half * 4;
        bf16x8 e;
#pragma unroll
        for (int jj = 0; jj < 8; ++jj)
          e[jj] = f2bf(qkv[(size_t)(j0 + jb * 8 + jj) * 1536 + 1024 + h_ * 64 + d]);
        *(bf16x8*)(vls + d * 64 + ((jb ^ (d & 7)) << 3)) = e;
      }
    }
    __syncthreads();

    ushort* pw = pls[w];
#pragma unroll
    for (int sjt = 0; sjt < 4; ++sjt) {
      const int krow = sjt * 16 + lr;
      bf16x8 kf0 = *(const bf16x8*)(kls + krow * 64 + (((0 * 4 + lg) ^ (lr & 7)) << 3));
      bf16x8 kf1 = *(const bf16x8*)(kls + krow * 64 + (((1 * 4 + lg) ^ (lr & 7)) << 3));
#pragma unroll
      for (int rt = 0; rt < 4; ++rt) {
        f32x4 s = (f32x4){0.f, 0.f, 0.f, 0.f};
        s = __builtin_amdgcn_mfma_f32_16x16x32_bf16(qf[rt][0], kf0, s, 0, 0, 0);
        s = __builtin_amdgcn_mfma_f32_16x16x32_bf16(qf[rt][1], kf1, s, 0, 0, 0);
#pragma unroll
        for (int r = 0; r < 4; ++r) {
          int i  = rt * 16 + lg * 4 + r;
          int jj = sjt * 16 + lr;
          pw[i * 64 + ((((jj >> 3) ^ (i & 7)) << 3)) + (jj & 7)] = (short)f2bf(__expf(s[r]));
        }
      }
    }
    bf16x8 pf[4][2];
#pragma unroll
    for (int rt = 0; rt < 4; ++rt)
#pragma unroll
      for (int jc = 0; jc < 2; ++jc)
        pf[rt][jc] = *(const bf16x8*)(pw + (rt * 16 + lr) * 64 + (((jc * 4 + lg) ^ (lr & 7)) << 3));
#pragma unroll
    for (int dt = 0; dt < 5; ++dt) {
      const int vrow = dt * 16 + lr;
      bf16x8 vf0 = *(const bf16x8*)(vls + vrow * 64 + (((0 * 4 + lg) ^ (lr & 7)) << 3));
      bf16x8 vf1 = *(const bf16x8*)(vls + vrow * 64 + (((1 * 4 + lg) ^ (lr & 7)) << 3));
#pragma unroll
      for (int rt = 0; rt < 4; ++rt) {
        acc[rt][dt] = __builtin_amdgcn_mfma_f32_16x16x32_bf16(pf[rt][0], vf0, acc[rt][dt], 0, 0, 0);
        acc[rt][dt] = __builtin_amdgcn_mfma_f32_16x16x32_bf16(pf[rt][1], vf1, acc[rt][dt], 0, 0, 0);
      }
    }
  }

  const size_t pbase = (size_t)(h_ * CHK + ch) * 256;
#pragma unroll
  for (int rt = 0; rt < 4; ++rt) {
    int i = 64 * w + rt * 16 + lg * 4;
#pragma unroll
    for (int dt = 0; dt < 4; ++dt)
#pragma unroll
      for (int r = 0; r < 4; ++r)
        pacc[(pbase + i + r) * 64 + dt * 16 + lr] = acc[rt][dt][r];
    if (lr == 0) {
#pragma unroll
      for (int r = 0; r < 4; ++r)
        den[pbase + i + r] = acc[rt][4][r];
    }
  }
}

// ---------------- merge a3v partials ----------------
__global__ __launch_bounds__(64) void a3v_merge_kernel(
    const float* __restrict__ pacc, const float* __restrict__ den, float* __restrict__ a3v)
{
  int h_ = blockIdx.x, i = blockIdx.y, d = threadIdx.x;
  float S = 0.f, o = 0.f;
  for (int c = 0; c < CHK; ++c) {
    size_t b = (size_t)(h_ * CHK + c) * 256 + i;
    o += pacc[b * 64 + d];
    S += den[b];
  }
  a3v[((size_t)h_ * 256 + i) * 64 + d] = o / S;
}

// ---------------- a1: out = softmax(q . kl^T) @ w2 via bf16 MFMA ----------------
__global__ __launch_bounds__(256) void a1_mfma(
    const float* __restrict__ qkv, const float* __restrict__ kl,
    const float* __restrict__ w2, float* __restrict__ attn)
{
  const int h_ = blockIdx.x;
  const int rb = blockIdx.y;
  const int t  = threadIdx.x;
  const int w  = t >> 6, l = t & 63, lr = l & 15, lg = l >> 4;

  __shared__ __align__(16) ushort kls[64 * 64];
  __shared__ __align__(16) ushort wls[80 * 64];
  __shared__ __align__(16) ushort pls[4][64 * 64];

  bf16x8 qf[4][2];
#pragma unroll
  for (int rt = 0; rt < 4; ++rt)
#pragma unroll
    for (int dc = 0; dc < 2; ++dc) {
      const float* p = qkv + (size_t)(rb * 256 + w * 64 + rt * 16 + lr) * 1536 + h_ * 64 + dc * 32 + lg * 8;
      float4 f0 = *(const float4*)p;
      float4 f1 = *(const float4*)(p + 4);
      bf16x8 v;
      v[0] = f2bf(f0.x); v[1] = f2bf(f0.y); v[2] = f2bf(f0.z); v[3] = f2bf(f0.w);
      v[4] = f2bf(f1.x); v[5] = f2bf(f1.y); v[6] = f2bf(f1.z); v[7] = f2bf(f1.w);
      qf[rt][dc] = v;
    }

  if (t < 128) {
    int rr = t >> 3, cb = t & 7;
    ushort val = (rr == 0) ? (ushort)0x3f80 : (ushort)0;
    bf16x8 vv;
#pragma unroll
    for (int k = 0; k < 8; ++k) vv[k] = (short)val;
    *(bf16x8*)(wls + (64 + rr) * 64 + ((cb ^ (rr & 7)) << 3)) = vv;
  }

  f32x4 acc[4][5];
#pragma unroll
  for (int rt = 0; rt < 4; ++rt)
#pragma unroll
    for (int dt = 0; dt < 5; ++dt) acc[rt][dt] = (f32x4){0.f, 0.f, 0.f, 0.f};

  for (int kc = 0; kc < 4; ++kc) {
    const int j0 = kc * 64;
    __syncthreads();
    {
      int r = t >> 2, db = t & 3;
      const float* src = kl + (size_t)(j0 + r) * 512 + h_ * 64 + db * 16;
      float4 g0 = *(const float4*)(src + 0);
      float4 g1 = *(const float4*)(src + 4);
      float4 g2 = *(const float4*)(src + 8);
      float4 g3 = *(const float4*)(src + 12);
      bf16x8 e0, e1;
      e0[0] = f2bf(g0.x); e0[1] = f2bf(g0.y); e0[2] = f2bf(g0.z); e0[3] = f2bf(g0.w);
      e0[4] = f2bf(g1.x); e0[5] = f2bf(g1.y); e0[6] = f2bf(g1.z); e0[7] = f2bf(g1.w);
      e1[0] = f2bf(g2.x); e1[1] = f2bf(g2.y); e1[2] = f2bf(g2.z); e1[3] = f2bf(g2.w);
      e1[4] = f2bf(g3.x); e1[5] = f2bf(g3.y); e1[6] = f2bf(g3.z); e1[7] = f2bf(g3.w);
      ushort* base = kls + r * 64;
      *(bf16x8*)(base + (((db * 2 + 0) ^ (r & 7)) << 3)) = e0;
      *(bf16x8*)(base + (((db * 2 + 1) ^ (r & 7)) << 3)) = e1;
    }
    {
      int d = t & 63, jg = t >> 6;
#pragma unroll
      for (int half = 0; half < 2; ++half) {
        int jb = jg + half * 4;
        bf16x8 e;
#pragma unroll
        for (int jj = 0; jj < 8; ++jj)
          e[jj] = f2bf(w2[((size_t)h_ * 256 + j0 + jb * 8 + jj) * 64 + d]);
        *(bf16x8*)(wls + d * 64 + ((jb ^ (d & 7)) << 3)) = e;
      }
    }
    __syncthreads();

    ushort* pw = pls[w];
#pragma unroll
    for (int sjt = 0; sjt < 4; ++sjt) {
      const int krow = sjt * 16 + lr;
      bf16x8 kf0 = *(const bf16x8*)(kls + krow * 64 + (((0 * 4 + lg) ^ (lr & 7)) << 3));
      bf16x8 kf1 = *(const bf16x8*)(kls + krow * 64 + (((1 * 4 + lg) ^ (lr & 7)) << 3));
#pragma unroll
      for (int rt = 0; rt < 4; ++rt) {
        f32x4 s = (f32x4){0.f, 0.f, 0.f, 0.f};
        s = __builtin_amdgcn_mfma_f32_16x16x32_bf16(qf[rt][0], kf0, s, 0, 0, 0);
        s = __builtin_amdgcn_mfma_f32_16x16x32_bf16(qf[rt][1], kf1, s, 0, 0, 0);
#pragma unroll
        for (int r = 0; r < 4; ++r) {
          int i  = rt * 16 + lg * 4 + r;
          int jj = sjt * 16 + lr;
          pw[i * 64 + ((((jj >> 3) ^ (i & 7)) << 3)) + (jj & 7)] = (short)f2bf(__expf(s[r]));
        }
      }
    }
    bf16x8 pf[4][2];
#pragma unroll
    for (int rt = 0; rt < 4; ++rt)
#pragma unroll
      for (int jc = 0; jc < 2; ++jc)
        pf[rt][jc] = *(const bf16x8*)(pw + (rt * 16 + lr) * 64 + (((jc * 4 + lg) ^ (lr & 7)) << 3));
#pragma unroll
    for (int dt = 0; dt < 5; ++dt) {
      const int vrow = dt * 16 + lr;
      bf16x8 vf0 = *(const bf16x8*)(wls + vrow * 64 + (((0 * 4 + lg) ^ (lr & 7)) << 3));
      bf16x8 vf1 = *(const bf16x8*)(wls + vrow * 64 + (((1 * 4 + lg) ^ (lr & 7)) << 3));
#pragma unroll
      for (int rt = 0; rt < 4; ++rt) {
        acc[rt][dt] = __builtin_amdgcn_mfma_f32_16x16x32_bf16(pf[rt][0], vf0, acc[rt][dt], 0, 0, 0);
        acc[rt][dt] = __builtin_amdgcn_mfma_f32_16x16x32_bf16(pf[rt][1], vf1, acc[rt][dt], 0, 0, 0);
      }
    }
  }

#pragma unroll
  for (int rt = 0; rt < 4; ++rt) {
#pragma unroll
    for (int r = 0; r < 4; ++r) {
      float dn = __shfl(acc[rt][4][r], l & 48);
      float inv = 1.f / dn;
      int gr = rb * 256 + w * 64 + rt * 16 + lg * 4 + r;
      float* op = attn + (size_t)gr * 512 + h_ * 64;
#pragma unroll
      for (int dt = 0; dt < 4; ++dt)
        op[dt * 16 + lr] = acc[rt][dt][r] * inv;
    }
  }
}

// ---------------- depthwise res conv (kernel 33): register sliding window ----------------
__global__ __launch_bounds__(256) void resconv_kernel(
    const float* __restrict__ qkv, const float* __restrict__ rw, float* __restrict__ attn)
{
  const int bid = blockIdx.x;                 // 0..2047 (2048 % 8 == 0 -> bijective)
  const int rb  = (bid & 7) * 256 + (bid >> 3);
  const int r0  = rb * 8;
  const int c   = blockIdx.y * 256 + threadIdx.x;
  const int h_  = c >> 6;

  float wreg[33];
#pragma unroll
  for (int tp = 0; tp < 33; ++tp) wreg[tp] = rw[h_ * 33 + tp];   // wave-uniform broadcast

  float v[40];
#pragma unroll
  for (int k = 0; k < 40; ++k) {
    int rr = r0 - 16 + k;
    v[k] = (rr >= 0 && rr < NPAD) ? qkv[(size_t)rr * 1536 + 1024 + c] : 0.f;
  }
#pragma unroll
  for (int i = 0; i < 8; ++i) {
    float s = 0.f;
#pragma unroll
    for (int tp = 0; tp < 33; ++tp)
      s = fmaf(v[i + tp], wreg[tp], s);
    attn[(size_t)(r0 + i) * 512 + c] += s;
  }
}

// ---------------- weight transpose for ppeg: wt[k*512+c] ----------------
__global__ __launch_bounds__(256) void wtrans_kernel(
    const float* __restrict__ w7, const float* __restrict__ w5,
    const float* __restrict__ w3, float* __restrict__ wt)
{
  int c = blockIdx.x * 256 + threadIdx.x;
  for (int k = 0; k < 49; ++k) wt[(size_t)k * 512 + c]        = w7[(size_t)c * 49 + k];
  for (int k = 0; k < 25; ++k) wt[(size_t)(49 + k) * 512 + c] = w5[(size_t)c * 25 + k];
  for (int k = 0; k < 9;  ++k) wt[(size_t)(74 + k) * 512 + c] = w3[(size_t)c * 9 + k];
}

// ---------------- PPEG: 64 ch/block, x-sliding window, column prefetch ----------------
__global__ __launch_bounds__(256) void ppeg_kernel(
    const float* __restrict__ h, float* __restrict__ tmp,
    const float* __restrict__ wt,
    const float* __restrict__ b7, const float* __restrict__ b5,
    const float* __restrict__ b3)
{
  __shared__ float wl[83 * 64];            // 21,248 B
  const int t  = threadIdx.x;
  const int tc = t & 63;
  const int xo = (blockIdx.x & 3) * 4 + (t >> 6);   // x-octet 0..15, wave-uniform
  const int y  = blockIdx.x >> 2;                    // 0..126
  const int c  = blockIdx.y * 64 + tc;
  for (int idx = t; idx < 83 * 64; idx += 256)
    wl[idx] = wt[(size_t)(idx >> 6) * 512 + blockIdx.y * 64 + (idx & 63)];
  const float bsum = b7[c] + b5[c] + b3[c];
  __syncthreads();

  const int x0 = xo * 8;
  float acc[8];
#pragma unroll
  for (int i = 0; i < 8; ++i) acc[i] = 0.f;

  float vcur[7];
  {
    int xx = x0 - 3;
    bool okx = (xx >= 0 && xx < SG);
#pragma unroll
    for (int ky = 0; ky < 7; ++ky) {
      int yy = y + ky - 3;
      vcur[ky] = (okx && yy >= 0 && yy < SG)
                   ? h[(size_t)(1 + yy * SG + xx) * DD + c] : 0.f;
    }
  }

#pragma unroll 1
  for (int j = 0; j < 14; ++j) {
    float vnext[7];
    if (j < 13) {                                    // wave-uniform
      int xx = x0 + j - 2;
      bool okx = (xx >= 0 && xx < SG);
#pragma unroll
      for (int ky = 0; ky < 7; ++ky) {
        int yy = y + ky - 3;
        vnext[ky] = (okx && yy >= 0 && yy < SG)
                      ? h[(size_t)(1 + yy * SG + xx) * DD + c] : 0.f;
      }
    }
#pragma unroll
    for (int i = 0; i < 8; ++i) {
      const int k7 = j - i;                          // runtime, but wl is LDS
      if (k7 >= 0 && k7 <= 6) {
        const float* w7p = wl + k7 * 64 + tc;
#pragma unroll
        for (int ky = 0; ky < 7; ++ky)
          acc[i] = fmaf(vcur[ky], w7p[ky * 7 * 64], acc[i]);
      }
      const int k5 = j - i - 1;
      if (k5 >= 0 && k5 <= 4) {
        const float* w5p = wl + (49 + k5) * 64 + tc;
#pragma unroll
        for (int ky = 0; ky < 5; ++ky)
          acc[i] = fmaf(vcur[ky + 1], w5p[ky * 5 * 64], acc[i]);
      }
      const int k3 = j - i - 2;
      if (k3 >= 0 && k3 <= 2) {
        const float* w3p = wl + (74 + k3) * 64 + tc;
#pragma unroll
        for (int ky = 0; ky < 3; ++ky)
          acc[i] = fmaf(vcur[ky + 2], w3p[ky * 3 * 64], acc[i]);
      }
    }
    if (j < 13) {
#pragma unroll
      for (int ky = 0; ky < 7; ++ky) vcur[ky] = vnext[ky];
    }
  }
#pragma unroll
  for (int i = 0; i < 8; ++i) {
    int x = x0 + i;
    if (x < SG) {
      int p = y * SG + x;
      tmp[(size_t)p * DD + c] = h[(size_t)(1 + p) * DD + c] + bsum + acc[i];
    }
  }
}

// ---------------- final: LN(row0) -> fc2 -> softmax/argmax ----------------
__global__ __launch_bounds__(256) void final_kernel(
    const float* __restrict__ h, const float* __restrict__ g, const float* __restrict__ b,
    const float* __restrict__ w, const float* __restrict__ bias, float* __restrict__ out)
{
  __shared__ float red[256];
  int t = threadIdx.x;
  float v0 = h[t], v1 = h[t + 256];
  red[t] = v0 + v1;
  __syncthreads();
  for (int s = 128; s > 0; s >>= 1) { if (t < s) red[t] += red[t + s]; __syncthreads(); }
  float mu = red[0] * (1.f / 512.f);
  __syncthreads();
  float d0 = v0 - mu, d1 = v1 - mu;
  red[t] = d0 * d0 + d1 * d1;
  __syncthreads();
  for (int s = 128; s > 0; s >>= 1) { if (t < s) red[t] += red[t + s]; __syncthreads(); }
  float rs = rsqrtf(red[0] * (1.f / 512.f) + 1e-5f);
  __syncthreads();
  float x0 = d0 * rs * g[t] + b[t];
  float x1 = d1 * rs * g[t + 256] + b[t + 256];
  red[t] = x0 * w[t * 2] + x1 * w[(t + 256) * 2];
  __syncthreads();
  for (int s = 128; s > 0; s >>= 1) { if (t < s) red[t] += red[t + s]; __syncthreads(); }
  float l0 = red[0] + bias[0];
  __syncthreads();
  red[t] = x0 * w[t * 2 + 1] + x1 * w[(t + 256) * 2 + 1];
  __syncthreads();
  for (int s = 128; s > 0; s >>= 1) { if (t < s) red[t] += red[t + s]; __syncthreads(); }
  float l1 = red[0] + bias[1];
  if (t == 0) {
    out[0] = l0; out[1] = l1;
    float mx = fmaxf(l0, l1);
    float e0 = __expf(l0 - mx), e1 = __expf(l1 - mx);
    float inv = 1.f / (e0 + e1);
    out[2] = e0 * inv; out[3] = e1 * inv;
    out[4] = (l1 > l0) ? 1.f : 0.f;
  }
}

extern "C" void kernel_launch(void* const* d_in, const int* in_sizes, int n_in,
                              void* d_out, int out_size, void* d_ws, size_t ws_size,
                              hipStream_t stream)
{
  const float* data   = (const float*)d_in[0];
  const float* fc1_w  = (const float*)d_in[1];
  const float* fc1_b  = (const float*)d_in[2];
  const float* cls    = (const float*)d_in[3];
  const float* l1_g   = (const float*)d_in[4];
  const float* l1_b   = (const float*)d_in[5];
  const float* l1_qkv = (const float*)d_in[6];
  const float* l1_ow  = (const float*)d_in[7];
  const float* l1_ob  = (const float*)d_in[8];
  const float* l1_rw  = (const float*)d_in[9];
  const float* w7     = (const float*)d_in[10];
  const float* b7     = (const float*)d_in[11];
  const float* w5     = (const float*)d_in[12];
  const float* b5     = (const float*)d_in[13];
  const float* w3     = (const float*)d_in[14];
  const float* b3     = (const float*)d_in[15];
  const float* l2_g   = (const float*)d_in[16];
  const float* l2_b   = (const float*)d_in[17];
  const float* l2_qkv = (const float*)d_in[18];
  const float* l2_ow  = (const float*)d_in[19];
  const float* l2_ob  = (const float*)d_in[20];
  const float* l2_rw  = (const float*)d_in[21];
  const float* ng     = (const float*)d_in[22];
  const float* nb     = (const float*)d_in[23];
  const float* fc2_w  = (const float*)d_in[24];
  const float* fc2_b  = (const float*)d_in[25];
  float* out = (float*)d_out;

  float* ws   = (float*)d_ws;
  float* h    = ws;
  float* xn   = h    + (size_t)16384 * 512;
  float* qkv  = xn   + (size_t)16384 * 512;
  float* attn = qkv  + (size_t)16384 * 1536;
  float* ql   = attn + (size_t)16384 * 512;
  float* kl   = ql   + 256 * 512;
  float* a2b  = kl   + 256 * 512;
  float* z0   = a2b  + 8 * 256 * 256;
  float* z1   = z0   + 8 * 256 * 256;
  float* xzb  = z1   + 8 * 256 * 256;
  float* tb   = xzb  + 8 * 256 * 256;
  float* ub   = tb   + 8 * 256 * 256;
  float* a3v  = ub   + 8 * 256 * 256;
  float* w2   = a3v  + 8 * 256 * 64;
  float* pacc = w2   + 8 * 256 * 64;           // dead region: 4,194,304 floats (16 MiB)
  float* pms  = pacc + (size_t)8 * 32 * 256 * 64;
  float* red  = pms  + (size_t)8 * 32 * 256 * 2;
  float* wtb  = red  + 256;                      // ppeg weights fp32 (83*512)

  // bf16 transposed weights at start of pacc region: 2.62M ushorts = 1.31M floats
  ushort* fc1_wt  = (ushort*)pacc;
  ushort* qkv_wt0 = fc1_wt + 512 * 1024;
  ushort* qkv_wt1 = qkv_wt0 + 1536 * 512;
  ushort* out_wt0 = qkv_wt1 + 1536 * 512;
  ushort* out_wt1 = out_wt0 + 512 * 512;

  // bf16 activations: xn region as bf16 LN output; data bf16 in qkv region
  ushort* xnb    = (ushort*)xn;
  ushort* databf = (ushort*)qkv;

  // a3v MFMA partial buffers (alias xn scratch / pms)
  float* a3v_pacc = xn;
  float* a3v_den  = pms;

  // weight prep (bf16 transposes) + data cvt + fc1 + assemble
  wtrans_bf<<<dim3(16, 32), 256, 0, stream>>>(fc1_w, fc1_wt, 1024, 512);
  wtrans_bf<<<dim3(48, 16), 256, 0, stream>>>(l1_qkv, qkv_wt0, 512, 1536);
  wtrans_bf<<<dim3(48, 16), 256, 0, stream>>>(l2_qkv, qkv_wt1, 512, 1536);
  wtrans_bf<<<dim3(16, 16), 256, 0, stream>>>(l1_ow, out_wt0, 512, 512);
  wtrans_bf<<<dim3(16, 16), 256, 0, stream>>>(l2_ow, out_wt1, 512, 512);
  wtrans_kernel<<<2, 256, 0, stream>>>(w7, w5, w3, wtb);
  cvt_bf_kernel<<<8000, 256, 0, stream>>>(data, databf, 16000 * 1024);

  gemm_bb<<<dim3(4, 125), 256, 0, stream>>>(databf, 1024, fc1_wt, 1024, h + 512, 512,
                                            16000, 1024, 1, fc1_b);
  assemble_kernel<<<260, 256, 0, stream>>>(h, cls);

  for (int layer = 0; layer < 2; ++layer) {
    const float* gg = layer ? l2_g   : l1_g;
    const float* bb = layer ? l2_b   : l1_b;
    const ushort* qw = layer ? qkv_wt1 : qkv_wt0;
    const ushort* ow = layer ? out_wt1 : out_wt0;
    const float* ob = layer ? l2_ob  : l1_ob;
    const float* rw = layer ? l2_rw  : l1_rw;

    ln_pad_kernel<<<16384, 256, 0, stream>>>(h, xnb, gg, bb);
    gemm_bb<<<dim3(12, 128), 256, 0, stream>>>(xnb, 512, qw, 512, qkv, 1536,
                                               16384, 512, 2, nullptr);
    landmark_kernel<<<dim3(256, 4), 256, 0, stream>>>(qkv, ql, kl);
    a2_kernel<<<dim3(8, 256), 256, 0, stream>>>(ql, kl, a2b);
    pinv_red1<<<8, 256, 0, stream>>>(a2b, red);
    pinv_red2<<<1, 1, 0, stream>>>(red);
    pinv_head<<<8, 1024, 0, stream>>>(a2b, red, z0, z1, xzb, tb, ub);
    // final z in z0 (6 swaps inside pinv_head)
    a3v_mfma<<<dim3(8, CHK), 256, 0, stream>>>(qkv, ql, a3v_pacc, a3v_den);
    a3v_merge_kernel<<<dim3(8, 256), 64, 0, stream>>>(a3v_pacc, a3v_den, a3v);
    mmb_kernel<<<dim3(1, 4, 8), 256, 0, stream>>>(z0, a3v, w2, 64, 1.f);
    a1_mfma<<<dim3(8, 64), 256, 0, stream>>>(qkv, kl, w2, attn);
    resconv_kernel<<<dim3(2048, 2), 256, 0, stream>>>(qkv, rw, attn);
    gemm_bt<<<dim3(4, 127), 256, 0, stream>>>(attn + (size_t)254 * 512, 512, ow, 512,
                                              h, 512, 16130, 512, 3, ob);
    if (layer == 0) {
      // ppeg -> qkv scratch (dead until layer-1 recomputes it), memcpy back
      ppeg_kernel<<<dim3(127 * 4, 8), 256, 0, stream>>>(h, qkv, wtb, b7, b5, b3);
      hipMemcpyAsync(h + 512, qkv, (size_t)16129 * 512 * 4,
                     hipMemcpyDeviceToDevice, stream);
    }
  }
  final_kernel<<<1, 256, 0, stream>>>(h, ng, nb, fc2_w, fc2_b, out);
}

// Round 18
// 1265.925 us; speedup vs baseline: 2.0523x; 2.0523x over previous
//
#include <hip/hip_runtime.h>
#include <math.h>

#define NPAD   16384
#define PADR   254
#define NTOK   16130
#define NPIX   16129
#define SG     127
#define DD     512
#define NH     8
#define CHK    64          // key-chunks per head for a3v

typedef __attribute__((ext_vector_type(8))) short bf16x8;
typedef __attribute__((ext_vector_type(4))) float f32x4;

__device__ __forceinline__ ushort f2bf(float f) {
  uint u = __float_as_uint(f);
  u = (u + 0x7fffu + ((u >> 16) & 1u)) >> 16;
  return (ushort)u;
}

// ---------------- elementwise fp32 -> bf16 (vectorized x8) ----------------
__global__ __launch_bounds__(256) void cvt_bf_kernel(
    const float* __restrict__ src, ushort* __restrict__ dst, int n)
{
  int i = (blockIdx.x * 256 + threadIdx.x) * 8;
  if (i >= n) return;
  float4 a = *(const float4*)(src + i);
  float4 b = *(const float4*)(src + i + 4);
  bf16x8 v;
  v[0] = f2bf(a.x); v[1] = f2bf(a.y); v[2] = f2bf(a.z); v[3] = f2bf(a.w);
  v[4] = f2bf(b.x); v[5] = f2bf(b.y); v[6] = f2bf(b.z); v[7] = f2bf(b.w);
  *(bf16x8*)(dst + i) = v;
}

// ---------------- weight transpose+cvt: src fp32 [K][N] -> dst bf16 [N][K] ----------------
__global__ __launch_bounds__(256) void wtrans_bf(
    const float* __restrict__ src, ushort* __restrict__ dst, int K, int N)
{
  __shared__ float tile[32][33];
  int tx = threadIdx.x & 31, ty = threadIdx.x >> 5;   // 32 x 8
#pragma unroll
  for (int i = 0; i < 4; ++i) {
    int k = blockIdx.y * 32 + ty + i * 8, n = blockIdx.x * 32 + tx;
    tile[ty + i * 8][tx] = src[(size_t)k * N + n];
  }
  __syncthreads();
#pragma unroll
  for (int i = 0; i < 4; ++i) {
    int n = blockIdx.x * 32 + ty + i * 8, k = blockIdx.y * 32 + tx;
    dst[(size_t)n * K + k] = f2bf(tile[tx][ty + i * 8]);
  }
}

// ---------------- bf16 MFMA GEMM (bf16 A): C fp32 = A_bf16 @ Bt_bf16^T ----------------
__global__ __launch_bounds__(256) void gemm_bb(
    const ushort* __restrict__ A, int lda,
    const ushort* __restrict__ Bt, int ldb,
    float* __restrict__ C, int ldc,
    int M, int K, int mode, const float* __restrict__ bias)
{
  const int t = threadIdx.x;
  const int w = t >> 6, l = t & 63, lr = l & 15, lg = l >> 4;
  const int wr = w >> 1, wc = w & 1;
  const int m0 = blockIdx.y * 128, n0 = blockIdx.x * 128;
  __shared__ __align__(16) ushort As[128 * 64];
  __shared__ __align__(16) ushort Bs[128 * 64];
  f32x4 acc[4][4];
#pragma unroll
  for (int i = 0; i < 4; ++i)
#pragma unroll
    for (int j = 0; j < 4; ++j) acc[i][j] = (f32x4){0.f, 0.f, 0.f, 0.f};

  for (int k0 = 0; k0 < K; k0 += 64) {
    __syncthreads();
#pragma unroll
    for (int i = 0; i < 4; ++i) {
      int id = t + i * 256;
      int r = id >> 3, blk = id & 7;
      int gr = m0 + r;
      bf16x8 v = (bf16x8){0, 0, 0, 0, 0, 0, 0, 0};
      if (gr < M) v = *(const bf16x8*)(A + (size_t)gr * lda + k0 + blk * 8);
      *(bf16x8*)(As + r * 64 + ((blk ^ (r & 7)) << 3)) = v;
    }
#pragma unroll
    for (int i = 0; i < 4; ++i) {
      int id = t + i * 256;
      int r = id >> 3, blk = id & 7;
      bf16x8 v = *(const bf16x8*)(Bt + (size_t)(n0 + r) * ldb + k0 + blk * 8);
      *(bf16x8*)(Bs + r * 64 + ((blk ^ (r & 7)) << 3)) = v;
    }
    __syncthreads();
    bf16x8 af[4][2], bfr[4][2];
#pragma unroll
    for (int rt = 0; rt < 4; ++rt) {
      int row = wr * 64 + rt * 16 + lr;
#pragma unroll
      for (int kc = 0; kc < 2; ++kc)
        af[rt][kc] = *(const bf16x8*)(As + row * 64 + (((kc * 4 + lg) ^ (row & 7)) << 3));
    }
#pragma unroll
    for (int nt = 0; nt < 4; ++nt) {
      int row = wc * 64 + nt * 16 + lr;
#pragma unroll
      for (int kc = 0; kc < 2; ++kc)
        bfr[nt][kc] = *(const bf16x8*)(Bs + row * 64 + (((kc * 4 + lg) ^ (row & 7)) << 3));
    }
#pragma unroll
    for (int rt = 0; rt < 4; ++rt)
#pragma unroll
      for (int nt = 0; nt < 4; ++nt) {
        acc[rt][nt] = __builtin_amdgcn_mfma_f32_16x16x32_bf16(af[rt][0], bfr[nt][0], acc[rt][nt], 0, 0, 0);
        acc[rt][nt] = __builtin_amdgcn_mfma_f32_16x16x32_bf16(af[rt][1], bfr[nt][1], acc[rt][nt], 0, 0, 0);
      }
  }
#pragma unroll
  for (int rt = 0; rt < 4; ++rt) {
#pragma unroll
    for (int r = 0; r < 4; ++r) {
      int gi = m0 + wr * 64 + rt * 16 + lg * 4 + r;
      if (gi >= M) continue;
#pragma unroll
      for (int nt = 0; nt < 4; ++nt) {
        int gj = n0 + wc * 64 + nt * 16 + lr;
        float d = acc[rt][nt][r];
        if (mode == 1) d = fmaxf(d + bias[gj], 0.f);
        else if (mode == 2) { if (gj < 512) d *= 0.125f; }
        else if (mode == 3) d += C[(size_t)gi * ldc + gj] + bias[gj];
        C[(size_t)gi * ldc + gj] = d;
      }
    }
  }
}

// ---------------- bf16 MFMA GEMM (fp32 A): C fp32 = A_f32 @ Bt_bf16^T ----------------
__global__ __launch_bounds__(256) void gemm_bt(
    const float* __restrict__ A, int lda,
    const ushort* __restrict__ Bt, int ldb,
    float* __restrict__ C, int ldc,
    int M, int K, int mode, const float* __restrict__ bias)
{
  const int t = threadIdx.x;
  const int w = t >> 6, l = t & 63, lr = l & 15, lg = l >> 4;
  const int wr = w >> 1, wc = w & 1;
  const int m0 = blockIdx.y * 128, n0 = blockIdx.x * 128;
  __shared__ __align__(16) ushort As[128 * 64];
  __shared__ __align__(16) ushort Bs[128 * 64];
  f32x4 acc[4][4];
#pragma unroll
  for (int i = 0; i < 4; ++i)
#pragma unroll
    for (int j = 0; j < 4; ++j) acc[i][j] = (f32x4){0.f, 0.f, 0.f, 0.f};

  for (int k0 = 0; k0 < K; k0 += 64) {
    __syncthreads();
#pragma unroll
    for (int i = 0; i < 2; ++i) {
      int id = t + i * 256;
      int r = id >> 2, db = id & 3;
      const float* src = A + (size_t)(m0 + r) * lda + k0 + db * 16;
      float4 g0 = *(const float4*)(src + 0);
      float4 g1 = *(const float4*)(src + 4);
      float4 g2 = *(const float4*)(src + 8);
      float4 g3 = *(const float4*)(src + 12);
      bf16x8 e0, e1;
      e0[0] = f2bf(g0.x); e0[1] = f2bf(g0.y); e0[2] = f2bf(g0.z); e0[3] = f2bf(g0.w);
      e0[4] = f2bf(g1.x); e0[5] = f2bf(g1.y); e0[6] = f2bf(g1.z); e0[7] = f2bf(g1.w);
      e1[0] = f2bf(g2.x); e1[1] = f2bf(g2.y); e1[2] = f2bf(g2.z); e1[3] = f2bf(g2.w);
      e1[4] = f2bf(g3.x); e1[5] = f2bf(g3.y); e1[6] = f2bf(g3.z); e1[7] = f2bf(g3.w);
      ushort* dst = As + r * 64;
      *(bf16x8*)(dst + (((db * 2 + 0) ^ (r & 7)) << 3)) = e0;
      *(bf16x8*)(dst + (((db * 2 + 1) ^ (r & 7)) << 3)) = e1;
    }
#pragma unroll
    for (int i = 0; i < 4; ++i) {
      int id = t + i * 256;
      int r = id >> 3, blk = id & 7;
      bf16x8 v = *(const bf16x8*)(Bt + (size_t)(n0 + r) * ldb + k0 + blk * 8);
      *(bf16x8*)(Bs + r * 64 + ((blk ^ (r & 7)) << 3)) = v;
    }
    __syncthreads();
    bf16x8 af[4][2], bfr[4][2];
#pragma unroll
    for (int rt = 0; rt < 4; ++rt) {
      int row = wr * 64 + rt * 16 + lr;
#pragma unroll
      for (int kc = 0; kc < 2; ++kc)
        af[rt][kc] = *(const bf16x8*)(As + row * 64 + (((kc * 4 + lg) ^ (row & 7)) << 3));
    }
#pragma unroll
    for (int nt = 0; nt < 4; ++nt) {
      int row = wc * 64 + nt * 16 + lr;
#pragma unroll
      for (int kc = 0; kc < 2; ++kc)
        bfr[nt][kc] = *(const bf16x8*)(Bs + row * 64 + (((kc * 4 + lg) ^ (row & 7)) << 3));
    }
#pragma unroll
    for (int rt = 0; rt < 4; ++rt)
#pragma unroll
      for (int nt = 0; nt < 4; ++nt) {
        acc[rt][nt] = __builtin_amdgcn_mfma_f32_16x16x32_bf16(af[rt][0], bfr[nt][0], acc[rt][nt], 0, 0, 0);
        acc[rt][nt] = __builtin_amdgcn_mfma_f32_16x16x32_bf16(af[rt][1], bfr[nt][1], acc[rt][nt], 0, 0, 0);
      }
  }
#pragma unroll
  for (int rt = 0; rt < 4; ++rt) {
#pragma unroll
    for (int r = 0; r < 4; ++r) {
      int gi = m0 + wr * 64 + rt * 16 + lg * 4 + r;
      if (gi >= M) continue;
#pragma unroll
      for (int nt = 0; nt < 4; ++nt) {
        int gj = n0 + wc * 64 + nt * 16 + lr;
        float d = acc[rt][nt][r];
        if (mode == 1) d = fmaxf(d + bias[gj], 0.f);
        else if (mode == 2) { if (gj < 512) d *= 0.125f; }
        else if (mode == 3) d += C[(size_t)gi * ldc + gj] + bias[gj];
        C[(size_t)gi * ldc + gj] = d;
      }
    }
  }
}

// ---------------- fused Newton-step matmul: D = A@B (bf16 MFMA), C = f(A[ij], D) ----------
// batched 8 heads of 256x256. B transposed during staging. modes:
// 0: C=D ; 1: C=7A-D ; 2: C=15A-D ; 3: C=0.25*(13A-D)
// [round 15-17 post-mortem: all three pinv-fusion variants (global barrier,
//  per-head barrier, single-block-per-head) were 3-8x SLOWER than this launch
//  train -- cross-block sync on this chip costs ~30us/phase and one CU can't
//  pipeline the chain. The 24-launch graph-replayed train is the measured best.]
__global__ __launch_bounds__(256) void nmm_kernel(
    const float* __restrict__ A, const float* __restrict__ B,
    float* __restrict__ C, int mode)
{
  const int h_ = blockIdx.z;
  const int m0 = blockIdx.y * 64, n0 = blockIdx.x * 64;
  const float* Ah = A + (size_t)h_ * 65536;
  const float* Bh = B + (size_t)h_ * 65536;
  float* Ch = C + (size_t)h_ * 65536;
  const int t = threadIdx.x, w = t >> 6, l = t & 63, lr = l & 15, lg = l >> 4;
  __shared__ __align__(16) ushort Xs[64 * 64];
  __shared__ __align__(16) ushort Ys[64 * 64];
  f32x4 acc[4];
#pragma unroll
  for (int nt = 0; nt < 4; ++nt) acc[nt] = (f32x4){0.f, 0.f, 0.f, 0.f};

  for (int k0 = 0; k0 < 256; k0 += 64) {
    __syncthreads();
    {
      int r = t >> 2, db = t & 3;
      const float* src = Ah + (size_t)(m0 + r) * 256 + k0 + db * 16;
      float4 g0 = *(const float4*)(src + 0);
      float4 g1 = *(const float4*)(src + 4);
      float4 g2 = *(const float4*)(src + 8);
      float4 g3 = *(const float4*)(src + 12);
      bf16x8 e0, e1;
      e0[0] = f2bf(g0.x); e0[1] = f2bf(g0.y); e0[2] = f2bf(g0.z); e0[3] = f2bf(g0.w);
      e0[4] = f2bf(g1.x); e0[5] = f2bf(g1.y); e0[6] = f2bf(g1.z); e0[7] = f2bf(g1.w);
      e1[0] = f2bf(g2.x); e1[1] = f2bf(g2.y); e1[2] = f2bf(g2.z); e1[3] = f2bf(g2.w);
      e1[4] = f2bf(g3.x); e1[5] = f2bf(g3.y); e1[6] = f2bf(g3.z); e1[7] = f2bf(g3.w);
      ushort* dst = Xs + r * 64;
      *(bf16x8*)(dst + (((db * 2 + 0) ^ (r & 7)) << 3)) = e0;
      *(bf16x8*)(dst + (((db * 2 + 1) ^ (r & 7)) << 3)) = e1;
    }
#pragma unroll
    for (int i = 0; i < 4; ++i) {
      int id = t + i * 256;
      int k = id >> 4, q = id & 15;
      float4 v = *(const float4*)(Bh + (size_t)(k0 + k) * 256 + n0 + q * 4);
      int kb = k >> 3, ke = k & 7;
      Ys[(q * 4 + 0) * 64 + ((kb ^ ((q * 4 + 0) & 7)) << 3) + ke] = f2bf(v.x);
      Ys[(q * 4 + 1) * 64 + ((kb ^ ((q * 4 + 1) & 7)) << 3) + ke] = f2bf(v.y);
      Ys[(q * 4 + 2) * 64 + ((kb ^ ((q * 4 + 2) & 7)) << 3) + ke] = f2bf(v.z);
      Ys[(q * 4 + 3) * 64 + ((kb ^ ((q * 4 + 3) & 7)) << 3) + ke] = f2bf(v.w);
    }
    __syncthreads();
    int arow = w * 16 + lr;
    bf16x8 af0 = *(const bf16x8*)(Xs + arow * 64 + (((0 + lg) ^ (arow & 7)) << 3));
    bf16x8 af1 = *(const bf16x8*)(Xs + arow * 64 + (((4 + lg) ^ (arow & 7)) << 3));
#pragma unroll
    for (int nt = 0; nt < 4; ++nt) {
      int brow = nt * 16 + lr;
      bf16x8 bf0 = *(const bf16x8*)(Ys + brow * 64 + (((0 + lg) ^ (brow & 7)) << 3));
      bf16x8 bf1 = *(const bf16x8*)(Ys + brow * 64 + (((4 + lg) ^ (brow & 7)) << 3));
      acc[nt] = __builtin_amdgcn_mfma_f32_16x16x32_bf16(af0, bf0, acc[nt], 0, 0, 0);
      acc[nt] = __builtin_amdgcn_mfma_f32_16x16x32_bf16(af1, bf1, acc[nt], 0, 0, 0);
    }
  }
#pragma unroll
  for (int nt = 0; nt < 4; ++nt) {
#pragma unroll
    for (int r = 0; r < 4; ++r) {
      int gi = m0 + w * 16 + lg * 4 + r;
      int gj = n0 + nt * 16 + lr;
      float d = acc[nt][r];
      if (mode == 1)      d = 7.f * Ah[(size_t)gi * 256 + gj] - d;
      else if (mode == 2) d = 15.f * Ah[(size_t)gi * 256 + gj] - d;
      else if (mode == 3) d = 0.25f * (13.f * Ah[(size_t)gi * 256 + gj] - d);
      Ch[(size_t)gi * 256 + gj] = d;
    }
  }
}

// ---------------- assemble: h[0]=cls, h[16001+i]=h[1+i] (i<129) ----------------
__global__ __launch_bounds__(256) void assemble_kernel(float* __restrict__ h,
                                                       const float* __restrict__ cls)
{
  int idx = blockIdx.x * 256 + threadIdx.x;
  if (idx < 512) { h[idx] = cls[idx]; return; }
  idx -= 512;
  int i = idx >> 9, c = idx & 511;
  h[(size_t)(16001 + i) * DD + c] = h[(size_t)(1 + i) * DD + c];
}

// ---------------- LayerNorm rows of h -> xn (bf16 out; front-padded) ----------------
__global__ __launch_bounds__(256) void ln_pad_kernel(
    const float* __restrict__ h, ushort* __restrict__ xn,
    const float* __restrict__ g, const float* __restrict__ b)
{
  int row = blockIdx.x;
  int t = threadIdx.x;
  if (row < PADR) {
    xn[(size_t)row * DD + t] = 0;
    xn[(size_t)row * DD + t + 256] = 0;
    return;
  }
  const float* x = h + (size_t)(row - PADR) * DD;
  __shared__ float red[256];
  float v0 = x[t], v1 = x[t + 256];
  red[t] = v0 + v1;
  __syncthreads();
  for (int s = 128; s > 0; s >>= 1) { if (t < s) red[t] += red[t + s]; __syncthreads(); }
  float mu = red[0] * (1.f / 512.f);
  __syncthreads();
  float d0 = v0 - mu, d1 = v1 - mu;
  red[t] = d0 * d0 + d1 * d1;
  __syncthreads();
  for (int s = 128; s > 0; s >>= 1) { if (t < s) red[t] += red[t + s]; __syncthreads(); }
  float rs = rsqrtf(red[0] * (1.f / 512.f) + 1e-5f);
  ushort* o = xn + (size_t)row * DD;
  o[t]       = f2bf(d0 * rs * g[t] + b[t]);
  o[t + 256] = f2bf(d1 * rs * g[t + 256] + b[t + 256]);
}

// ---------------- landmarks ----------------
__global__ __launch_bounds__(256) void landmark_kernel(
    const float* __restrict__ qkv, float* __restrict__ ql, float* __restrict__ kl)
{
  int i = blockIdx.x;
  int c = blockIdx.y * 256 + threadIdx.x;
  const float* p = qkv + (size_t)(i * 64) * 1536 + c;
  float s = 0.f;
  for (int j = 0; j < 64; ++j) s += p[(size_t)j * 1536];
  s *= (1.f / 64.f);
  if (c < 512) ql[(size_t)i * 512 + c] = s;
  else         kl[(size_t)i * 512 + (c - 512)] = s;
}

// ---------------- a2 = softmax(ql . kl^T) per head ----------------
__global__ __launch_bounds__(256) void a2_kernel(
    const float* __restrict__ ql, const float* __restrict__ kl, float* __restrict__ a2)
{
  int h_ = blockIdx.x, i = blockIdx.y;
  int t = threadIdx.x;
  __shared__ float q[64];
  __shared__ float red[256];
  if (t < 64) q[t] = ql[(size_t)i * 512 + h_ * 64 + t];
  __syncthreads();
  const float* kr = kl + (size_t)t * 512 + h_ * 64;
  float s = 0.f;
#pragma unroll
  for (int d = 0; d < 64; ++d) s = fmaf(q[d], kr[d], s);
  red[t] = s;
  __syncthreads();
  for (int st = 128; st > 0; st >>= 1) { if (t < st) red[t] = fmaxf(red[t], red[t + st]); __syncthreads(); }
  float mx = red[0];
  __syncthreads();
  float e = __expf(s - mx);
  red[t] = e;
  __syncthreads();
  for (int st = 128; st > 0; st >>= 1) { if (t < st) red[t] += red[t + st]; __syncthreads(); }
  a2[((size_t)h_ * 256 + i) * 256 + t] = e / red[0];
}

// ---------------- pinv init reductions ----------------
__global__ __launch_bounds__(256) void pinv_red1(const float* __restrict__ a2, float* __restrict__ red)
{
  int h_ = blockIdx.x, t = threadIdx.x;
  const float* X = a2 + (size_t)h_ * 65536;
  float rs = 0.f, cs = 0.f;
  for (int j = 0; j < 256; ++j) rs += fabsf(X[(size_t)t * 256 + j]);
  for (int i = 0; i < 256; ++i) cs += fabsf(X[(size_t)i * 256 + t]);
  __shared__ float r1[256], r2[256];
  r1[t] = rs; r2[t] = cs;
  __syncthreads();
  for (int s = 128; s > 0; s >>= 1) {
    if (t < s) { r1[t] = fmaxf(r1[t], r1[t + s]); r2[t] = fmaxf(r2[t], r2[t + s]); }
    __syncthreads();
  }
  if (t == 0) { red[h_ * 2] = r1[0]; red[h_ * 2 + 1] = r2[0]; }
}
__global__ void pinv_red2(float* __restrict__ red)
{
  float mr = 0.f, mc = 0.f;
  for (int h_ = 0; h_ < 8; ++h_) { mr = fmaxf(mr, red[h_ * 2]); mc = fmaxf(mc, red[h_ * 2 + 1]); }
  red[16] = 1.f / (mr * mc);
}
__global__ __launch_bounds__(256) void pinv_init(
    const float* __restrict__ a2, const float* __restrict__ red, float* __restrict__ z)
{
  int h_ = blockIdx.x, i = blockIdx.y, j = threadIdx.x;
  float inv = red[16];
  z[((size_t)h_ * 256 + i) * 256 + j] = a2[((size_t)h_ * 256 + j) * 256 + i] * inv;
}

// ---------------- batched matmul per head: C = alpha*(A @ B), A 256x256, B 256xN ----------------
__global__ __launch_bounds__(256) void mmb_kernel(
    const float* __restrict__ A, const float* __restrict__ B, float* __restrict__ C,
    int N, float alpha)
{
  int h_ = blockIdx.z;
  const float* Ah = A + (size_t)h_ * 256 * 256;
  const float* Bh = B + (size_t)h_ * 256 * N;
  float* Ch = C + (size_t)h_ * 256 * N;
  int m0 = blockIdx.y * 64, n0 = blockIdx.x * 64;
  __shared__ float As[16][68];
  __shared__ float Bs[16][68];
  int tid = threadIdx.x, tx = tid & 15, ty = tid >> 4;
  float acc[4][4];
#pragma unroll
  for (int i = 0; i < 4; ++i)
#pragma unroll
    for (int j = 0; j < 4; ++j) acc[i][j] = 0.f;
  for (int k0 = 0; k0 < 256; k0 += 16) {
    {
      int row = tid >> 2, k4 = (tid & 3) << 2;
      float4 v = *(const float4*)(Ah + (size_t)(m0 + row) * 256 + k0 + k4);
      As[k4 + 0][row] = v.x; As[k4 + 1][row] = v.y;
      As[k4 + 2][row] = v.z; As[k4 + 3][row] = v.w;
    }
    {
      int row = tid >> 4, c4 = (tid & 15) << 2;
      *(float4*)&Bs[row][c4] = *(const float4*)(Bh + (size_t)(k0 + row) * N + n0 + c4);
    }
    __syncthreads();
#pragma unroll
    for (int k = 0; k < 16; ++k) {
      float a[4], b[4];
      *(float4*)a = *(const float4*)&As[k][ty * 4];
      *(float4*)b = *(const float4*)&Bs[k][tx * 4];
#pragma unroll
      for (int i = 0; i < 4; ++i)
#pragma unroll
        for (int j = 0; j < 4; ++j) acc[i][j] = fmaf(a[i], b[j], acc[i][j]);
    }
    __syncthreads();
  }
#pragma unroll
  for (int i = 0; i < 4; ++i) {
    float4 r;
    r.x = alpha * acc[i][0]; r.y = alpha * acc[i][1];
    r.z = alpha * acc[i][2]; r.w = alpha * acc[i][3];
    *(float4*)(Ch + (size_t)(m0 + ty * 4 + i) * N + n0 + tx * 4) = r;
  }
}

// ---------------- a3@v partials via bf16 MFMA flash (no-max exp, ones-column den) ----------
__global__ __launch_bounds__(256) void a3v_mfma(
    const float* __restrict__ qkv, const float* __restrict__ ql,
    float* __restrict__ pacc, float* __restrict__ den)
{
  const int h_ = blockIdx.x;
  const int ch = blockIdx.y;
  const int t  = threadIdx.x;
  const int w  = t >> 6;
  const int l  = t & 63;
  const int lr = l & 15;
  const int lg = l >> 4;

  __shared__ __align__(16) ushort kls[64 * 64];
  __shared__ __align__(16) ushort vls[80 * 64];
  __shared__ __align__(16) ushort pls[4][64 * 64];

  bf16x8 qf[4][2];
#pragma unroll
  for (int rt = 0; rt < 4; ++rt)
#pragma unroll
    for (int dc = 0; dc < 2; ++dc) {
      const float* p = ql + (size_t)(64 * w + rt * 16 + lr) * 512 + h_ * 64 + dc * 32 + lg * 8;
      float4 f0 = *(const float4*)p;
      float4 f1 = *(const float4*)(p + 4);
      bf16x8 v;
      v[0] = f2bf(f0.x); v[1] = f2bf(f0.y); v[2] = f2bf(f0.z); v[3] = f2bf(f0.w);
      v[4] = f2bf(f1.x); v[5] = f2bf(f1.y); v[6] = f2bf(f1.z); v[7] = f2bf(f1.w);
      qf[rt][dc] = v;
    }

  if (t < 128) {
    int rr = t >> 3, cb = t & 7;
    ushort val = (rr == 0) ? (ushort)0x3f80 : (ushort)0;
    bf16x8 vv;
#pragma unroll
    for (int k = 0; k < 8; ++k) vv[k] = (short)val;
    *(bf16x8*)(vls + (64 + rr) * 64 + ((cb ^ (rr & 7)) << 3)) = vv;
  }

  f32x4 acc[4][5];
#pragma unroll
  for (int rt = 0; rt < 4; ++rt)
#pragma unroll
    for (int dt = 0; dt < 5; ++dt) acc[rt][dt] = (f32x4){0.f, 0.f, 0.f, 0.f};

  const int j0base = ch * 256;
  for (int jt = 0; jt < 4; ++jt) {
    const int j0 = j0base + jt * 64;
    __syncthreads();
    {
      int r = t >> 2, db = t & 3;
      const float* src = qkv + (size_t)(j0 + r) * 1536 + 512 + h_ * 64 + db * 16;
      float4 g0 = *(const float4*)(src + 0);
      float4 g1 = *(const float4*)(src + 4);
      float4 g2 = *(const float4*)(src + 8);
      float4 g3 = *(const float4*)(src + 12);
      bf16x8 e0, e1;
      e0[0] = f2bf(g0.x); e0[1] = f2bf(g0.y); e0[2] = f2bf(g0.z); e0[3] = f2bf(g0.w);
      e0[4] = f2bf(g1.x); e0[5] = f2bf(g1.y); e0[6] = f2bf(g1.z); e0[7] = f2bf(g1.w);
      e1[0] = f2bf(g2.x); e1[1] = f2bf(g2.y); e1[2] = f2bf(g2.z); e1[3] = f2bf(g2.w);
      e1[4] = f2bf(g3.x); e1[5] = f2bf(g3.y); e1[6] = f2bf(g3.z); e1[7] = f2bf(g3.w);
      ushort* base = kls + r * 64;
      *(bf16x8*)(base + (((db * 2 + 0) ^ (r & 7)) << 3)) = e0;
      *(bf16x8*)(base + (((db * 2 + 1) ^ (r & 7)) << 3)) = e1;
    }
    {
      int d = t & 63, jg = t >> 6;
#pragma unroll
      for (int half = 0; half < 2; ++half) {
        int jb = jg + half * 4;
        bf16x8 e;
#pragma unroll
        for (int jj = 0; jj < 8; ++jj)
          e[jj] = f2bf(qkv[(size_t)(j0 + jb * 8 + jj) * 1536 + 1024 + h_ * 64 + d]);
        *(bf16x8*)(vls + d * 64 + ((jb ^ (d & 7)) << 3)) = e;
      }
    }
    __syncthreads();

    ushort* pw = pls[w];
#pragma unroll
    for (int sjt = 0; sjt < 4; ++sjt) {
      const int krow = sjt * 16 + lr;
      bf16x8 kf0 = *(const bf16x8*)(kls + krow * 64 + (((0 * 4 + lg) ^ (lr & 7)) << 3));
      bf16x8 kf1 = *(const bf16x8*)(kls + krow * 64 + (((1 * 4 + lg) ^ (lr & 7)) << 3));
#pragma unroll
      for (int rt = 0; rt < 4; ++rt) {
        f32x4 s = (f32x4){0.f, 0.f, 0.f, 0.f};
        s = __builtin_amdgcn_mfma_f32_16x16x32_bf16(qf[rt][0], kf0, s, 0, 0, 0);
        s = __builtin_amdgcn_mfma_f32_16x16x32_bf16(qf[rt][1], kf1, s, 0, 0, 0);
#pragma unroll
        for (int r = 0; r < 4; ++r) {
          int i  = rt * 16 + lg * 4 + r;
          int jj = sjt * 16 + lr;
          pw[i * 64 + ((((jj >> 3) ^ (i & 7)) << 3)) + (jj & 7)] = (short)f2bf(__expf(s[r]));
        }
      }
    }
    bf16x8 pf[4][2];
#pragma unroll
    for (int rt = 0; rt < 4; ++rt)
#pragma unroll
      for (int jc = 0; jc < 2; ++jc)
        pf[rt][jc] = *(const bf16x8*)(pw + (rt * 16 + lr) * 64 + (((jc * 4 + lg) ^ (lr & 7)) << 3));
#pragma unroll
    for (int dt = 0; dt < 5; ++dt) {
      const int vrow = dt * 16 + lr;
      bf16x8 vf0 = *(const bf16x8*)(vls + vrow * 64 + (((0 * 4 + lg) ^ (lr & 7)) << 3));
      bf16x8 vf1 = *(const bf16x8*)(vls + vrow * 64 + (((1 * 4 + lg) ^ (lr & 7)) << 3));
#pragma unroll
      for (int rt = 0; rt < 4; ++rt) {
        acc[rt][dt] = __builtin_amdgcn_mfma_f32_16x16x32_bf16(pf[rt][0], vf0, acc[rt][dt], 0, 0, 0);
        acc[rt][dt] = __builtin_amdgcn_mfma_f32_16x16x32_bf16(pf[rt][1], vf1, acc[rt][dt], 0, 0, 0);
      }
    }
  }

  const size_t pbase = (size_t)(h_ * CHK + ch) * 256;
#pragma unroll
  for (int rt = 0; rt < 4; ++rt) {
    int i = 64 * w + rt * 16 + lg * 4;
#pragma unroll
    for (int dt = 0; dt < 4; ++dt)
#pragma unroll
      for (int r = 0; r < 4; ++r)
        pacc[(pbase + i + r) * 64 + dt * 16 + lr] = acc[rt][dt][r];
    if (lr == 0) {
#pragma unroll
      for (int r = 0; r < 4; ++r)
        den[pbase + i + r] = acc[rt][4][r];
    }
  }
}

// ---------------- merge a3v partials ----------------
__global__ __launch_bounds__(64) void a3v_merge_kernel(
    const float* __restrict__ pacc, const float* __restrict__ den, float* __restrict__ a3v)
{
  int h_ = blockIdx.x, i = blockIdx.y, d = threadIdx.x;
  float S = 0.f, o = 0.f;
  for (int c = 0; c < CHK; ++c) {
    size_t b = (size_t)(h_ * CHK + c) * 256 + i;
    o += pacc[b * 64 + d];
    S += den[b];
  }
  a3v[((size_t)h_ * 256 + i) * 64 + d] = o / S;
}

// ---------------- a1: out = softmax(q . kl^T) @ w2 via bf16 MFMA ----------------
__global__ __launch_bounds__(256) void a1_mfma(
    const float* __restrict__ qkv, const float* __restrict__ kl,
    const float* __restrict__ w2, float* __restrict__ attn)
{
  const int h_ = blockIdx.x;
  const int rb = blockIdx.y;
  const int t  = threadIdx.x;
  const int w  = t >> 6, l = t & 63, lr = l & 15, lg = l >> 4;

  __shared__ __align__(16) ushort kls[64 * 64];
  __shared__ __align__(16) ushort wls[80 * 64];
  __shared__ __align__(16) ushort pls[4][64 * 64];

  bf16x8 qf[4][2];
#pragma unroll
  for (int rt = 0; rt < 4; ++rt)
#pragma unroll
    for (int dc = 0; dc < 2; ++dc) {
      const float* p = qkv + (size_t)(rb * 256 + w * 64 + rt * 16 + lr) * 1536 + h_ * 64 + dc * 32 + lg * 8;
      float4 f0 = *(const float4*)p;
      float4 f1 = *(const float4*)(p + 4);
      bf16x8 v;
      v[0] = f2bf(f0.x); v[1] = f2bf(f0.y); v[2] = f2bf(f0.z); v[3] = f2bf(f0.w);
      v[4] = f2bf(f1.x); v[5] = f2bf(f1.y); v[6] = f2bf(f1.z); v[7] = f2bf(f1.w);
      qf[rt][dc] = v;
    }

  if (t < 128) {
    int rr = t >> 3, cb = t & 7;
    ushort val = (rr == 0) ? (ushort)0x3f80 : (ushort)0;
    bf16x8 vv;
#pragma unroll
    for (int k = 0; k < 8; ++k) vv[k] = (short)val;
    *(bf16x8*)(wls + (64 + rr) * 64 + ((cb ^ (rr & 7)) << 3)) = vv;
  }

  f32x4 acc[4][5];
#pragma unroll
  for (int rt = 0; rt < 4; ++rt)
#pragma unroll
    for (int dt = 0; dt < 5; ++dt) acc[rt][dt] = (f32x4){0.f, 0.f, 0.f, 0.f};

  for (int kc = 0; kc < 4; ++kc) {
    const int j0 = kc * 64;
    __syncthreads();
    {
      int r = t >> 2, db = t & 3;
      const float* src = kl + (size_t)(j0 + r) * 512 + h_ * 64 + db * 16;
      float4 g0 = *(const float4*)(src + 0);
      float4 g1 = *(const float4*)(src + 4);
      float4 g2 = *(const float4*)(src + 8);
      float4 g3 = *(const float4*)(src + 12);
      bf16x8 e0, e1;
      e0[0] = f2bf(g0.x); e0[1] = f2bf(g0.y); e0[2] = f2bf(g0.z); e0[3] = f2bf(g0.w);
      e0[4] = f2bf(g1.x); e0[5] = f2bf(g1.y); e0[6] = f2bf(g1.z); e0[7] = f2bf(g1.w);
      e1[0] = f2bf(g2.x); e1[1] = f2bf(g2.y); e1[2] = f2bf(g2.z); e1[3] = f2bf(g2.w);
      e1[4] = f2bf(g3.x); e1[5] = f2bf(g3.y); e1[6] = f2bf(g3.z); e1[7] = f2bf(g3.w);
      ushort* base = kls + r * 64;
      *(bf16x8*)(base + (((db * 2 + 0) ^ (r & 7)) << 3)) = e0;
      *(bf16x8*)(base + (((db * 2 + 1) ^ (r & 7)) << 3)) = e1;
    }
    {
      int d = t & 63, jg = t >> 6;
#pragma unroll
      for (int half = 0; half < 2; ++half) {
        int jb = jg + half * 4;
        bf16x8 e;
#pragma unroll
        for (int jj = 0; jj < 8; ++jj)
          e[jj] = f2bf(w2[((size_t)h_ * 256 + j0 + jb * 8 + jj) * 64 + d]);
        *(bf16x8*)(wls + d * 64 + ((jb ^ (d & 7)) << 3)) = e;
      }
    }
    __syncthreads();

    ushort* pw = pls[w];
#pragma unroll
    for (int sjt = 0; sjt < 4; ++sjt) {
      const int krow = sjt * 16 + lr;
      bf16x8 kf0 = *(const bf16x8*)(kls + krow * 64 + (((0 * 4 + lg) ^ (lr & 7)) << 3));
      bf16x8 kf1 = *(const bf16x8*)(kls + krow * 64 + (((1 * 4 + lg) ^ (lr & 7)) << 3));
#pragma unroll
      for (int rt = 0; rt < 4; ++rt) {
        f32x4 s = (f32x4){0.f, 0.f, 0.f, 0.f};
        s = __builtin_amdgcn_mfma_f32_16x16x32_bf16(qf[rt][0], kf0, s, 0, 0, 0);
        s = __builtin_amdgcn_mfma_f32_16x16x32_bf16(qf[rt][1], kf1, s, 0, 0, 0);
#pragma unroll
        for (int r = 0; r < 4; ++r) {
          int i  = rt * 16 + lg * 4 + r;
          int jj = sjt * 16 + lr;
          pw[i * 64 + ((((jj >> 3) ^ (i & 7)) << 3)) + (jj & 7)] = (short)f2bf(__expf(s[r]));
        }
      }
    }
    bf16x8 pf[4][2];
#pragma unroll
    for (int rt = 0; rt < 4; ++rt)
#pragma unroll
      for (int jc = 0; jc < 2; ++jc)
        pf[rt][jc] = *(const bf16x8*)(pw + (rt * 16 + lr) * 64 + (((jc * 4 + lg) ^ (lr & 7)) << 3));
#pragma unroll
    for (int dt = 0; dt < 5; ++dt) {
      const int vrow = dt * 16 + lr;
      bf16x8 vf0 = *(const bf16x8*)(wls + vrow * 64 + (((0 * 4 + lg) ^ (lr & 7)) << 3));
      bf16x8 vf1 = *(const bf16x8*)(wls + vrow * 64 + (((1 * 4 + lg) ^ (lr & 7)) << 3));
#pragma unroll
      for (int rt = 0; rt < 4; ++rt) {
        acc[rt][dt] = __builtin_amdgcn_mfma_f32_16x16x32_bf16(pf[rt][0], vf0, acc[rt][dt], 0, 0, 0);
        acc[rt][dt] = __builtin_amdgcn_mfma_f32_16x16x32_bf16(pf[rt][1], vf1, acc[rt][dt], 0, 0, 0);
      }
    }
  }

#pragma unroll
  for (int rt = 0; rt < 4; ++rt) {
#pragma unroll
    for (int r = 0; r < 4; ++r) {
      float dn = __shfl(acc[rt][4][r], l & 48);
      float inv = 1.f / dn;
      int gr = rb * 256 + w * 64 + rt * 16 + lg * 4 + r;
      float* op = attn + (size_t)gr * 512 + h_ * 64;
#pragma unroll
      for (int dt = 0; dt < 4; ++dt)
        op[dt * 16 + lr] = acc[rt][dt][r] * inv;
    }
  }
}

// ---------------- depthwise res conv (kernel 33): register sliding window ----------------
__global__ __launch_bounds__(256) void resconv_kernel(
    const float* __restrict__ qkv, const float* __restrict__ rw, float* __restrict__ attn)
{
  const int bid = blockIdx.x;                 // 0..2047 (2048 % 8 == 0 -> bijective)
  const int rb  = (bid & 7) * 256 + (bid >> 3);
  const int r0  = rb * 8;
  const int c   = blockIdx.y * 256 + threadIdx.x;
  const int h_  = c >> 6;

  float wreg[33];
#pragma unroll
  for (int tp = 0; tp < 33; ++tp) wreg[tp] = rw[h_ * 33 + tp];   // wave-uniform broadcast

  float v[40];
#pragma unroll
  for (int k = 0; k < 40; ++k) {
    int rr = r0 - 16 + k;
    v[k] = (rr >= 0 && rr < NPAD) ? qkv[(size_t)rr * 1536 + 1024 + c] : 0.f;
  }
#pragma unroll
  for (int i = 0; i < 8; ++i) {
    float s = 0.f;
#pragma unroll
    for (int tp = 0; tp < 33; ++tp)
      s = fmaf(v[i + tp], wreg[tp], s);
    attn[(size_t)(r0 + i) * 512 + c] += s;
  }
}

// ---------------- weight transpose for ppeg: wt[k*512+c] ----------------
__global__ __launch_bounds__(256) void wtrans_kernel(
    const float* __restrict__ w7, const float* __restrict__ w5,
    const float* __restrict__ w3, float* __restrict__ wt)
{
  int c = blockIdx.x * 256 + threadIdx.x;
  for (int k = 0; k < 49; ++k) wt[(size_t)k * 512 + c]        = w7[(size_t)c * 49 + k];
  for (int k = 0; k < 25; ++k) wt[(size_t)(49 + k) * 512 + c] = w5[(size_t)c * 25 + k];
  for (int k = 0; k < 9;  ++k) wt[(size_t)(74 + k) * 512 + c] = w3[(size_t)c * 9 + k];
}

// ---------------- PPEG: 64 ch/block, x-sliding window, column prefetch ----------------
__global__ __launch_bounds__(256) void ppeg_kernel(
    const float* __restrict__ h, float* __restrict__ tmp,
    const float* __restrict__ wt,
    const float* __restrict__ b7, const float* __restrict__ b5,
    const float* __restrict__ b3)
{
  __shared__ float wl[83 * 64];            // 21,248 B
  const int t  = threadIdx.x;
  const int tc = t & 63;
  const int xo = (blockIdx.x & 3) * 4 + (t >> 6);   // x-octet 0..15, wave-uniform
  const int y  = blockIdx.x >> 2;                    // 0..126
  const int c  = blockIdx.y * 64 + tc;
  for (int idx = t; idx < 83 * 64; idx += 256)
    wl[idx] = wt[(size_t)(idx >> 6) * 512 + blockIdx.y * 64 + (idx & 63)];
  const float bsum = b7[c] + b5[c] + b3[c];
  __syncthreads();

  const int x0 = xo * 8;
  float acc[8];
#pragma unroll
  for (int i = 0; i < 8; ++i) acc[i] = 0.f;

  float vcur[7];
  {
    int xx = x0 - 3;
    bool okx = (xx >= 0 && xx < SG);
#pragma unroll
    for (int ky = 0; ky < 7; ++ky) {
      int yy = y + ky - 3;
      vcur[ky] = (okx && yy >= 0 && yy < SG)
                   ? h[(size_t)(1 + yy * SG + xx) * DD + c] : 0.f;
    }
  }

#pragma unroll 1
  for (int j = 0; j < 14; ++j) {
    float vnext[7];
    if (j < 13) {                                    // wave-uniform
      int xx = x0 + j - 2;
      bool okx = (xx >= 0 && xx < SG);
#pragma unroll
      for (int ky = 0; ky < 7; ++ky) {
        int yy = y + ky - 3;
        vnext[ky] = (okx && yy >= 0 && yy < SG)
                      ? h[(size_t)(1 + yy * SG + xx) * DD + c] : 0.f;
      }
    }
#pragma unroll
    for (int i = 0; i < 8; ++i) {
      const int k7 = j - i;                          // runtime, but wl is LDS
      if (k7 >= 0 && k7 <= 6) {
        const float* w7p = wl + k7 * 64 + tc;
#pragma unroll
        for (int ky = 0; ky < 7; ++ky)
          acc[i] = fmaf(vcur[ky], w7p[ky * 7 * 64], acc[i]);
      }
      const int k5 = j - i - 1;
      if (k5 >= 0 && k5 <= 4) {
        const float* w5p = wl + (49 + k5) * 64 + tc;
#pragma unroll
        for (int ky = 0; ky < 5; ++ky)
          acc[i] = fmaf(vcur[ky + 1], w5p[ky * 5 * 64], acc[i]);
      }
      const int k3 = j - i - 2;
      if (k3 >= 0 && k3 <= 2) {
        const float* w3p = wl + (74 + k3) * 64 + tc;
#pragma unroll
        for (int ky = 0; ky < 3; ++ky)
          acc[i] = fmaf(vcur[ky + 2], w3p[ky * 3 * 64], acc[i]);
      }
    }
    if (j < 13) {
#pragma unroll
      for (int ky = 0; ky < 7; ++ky) vcur[ky] = vnext[ky];
    }
  }
#pragma unroll
  for (int i = 0; i < 8; ++i) {
    int x = x0 + i;
    if (x < SG) {
      int p = y * SG + x;
      tmp[(size_t)p * DD + c] = h[(size_t)(1 + p) * DD + c] + bsum + acc[i];
    }
  }
}

// ---------------- final: LN(row0) -> fc2 -> softmax/argmax ----------------
__global__ __launch_bounds__(256) void final_kernel(
    const float* __restrict__ h, const float* __restrict__ g, const float* __restrict__ b,
    const float* __restrict__ w, const float* __restrict__ bias, float* __restrict__ out)
{
  __shared__ float red[256];
  int t = threadIdx.x;
  float v0 = h[t], v1 = h[t + 256];
  red[t] = v0 + v1;
  __syncthreads();
  for (int s = 128; s > 0; s >>= 1) { if (t < s) red[t] += red[t + s]; __syncthreads(); }
  float mu = red[0] * (1.f / 512.f);
  __syncthreads();
  float d0 = v0 - mu, d1 = v1 - mu;
  red[t] = d0 * d0 + d1 * d1;
  __syncthreads();
  for (int s = 128; s > 0; s >>= 1) { if (t < s) red[t] += red[t + s]; __syncthreads(); }
  float rs = rsqrtf(red[0] * (1.f / 512.f) + 1e-5f);
  __syncthreads();
  float x0 = d0 * rs * g[t] + b[t];
  float x1 = d1 * rs * g[t + 256] + b[t + 256];
  red[t] = x0 * w[t * 2] + x1 * w[(t + 256) * 2];
  __syncthreads();
  for (int s = 128; s > 0; s >>= 1) { if (t < s) red[t] += red[t + s]; __syncthreads(); }
  float l0 = red[0] + bias[0];
  __syncthreads();
  red[t] = x0 * w[t * 2 + 1] + x1 * w[(t + 256) * 2 + 1];
  __syncthreads();
  for (int s = 128; s > 0; s >>= 1) { if (t < s) red[t] += red[t + s]; __syncthreads(); }
  float l1 = red[0] + bias[1];
  if (t == 0) {
    out[0] = l0; out[1] = l1;
    float mx = fmaxf(l0, l1);
    float e0 = __expf(l0 - mx), e1 = __expf(l1 - mx);
    float inv = 1.f / (e0 + e1);
    out[2] = e0 * inv; out[3] = e1 * inv;
    out[4] = (l1 > l0) ? 1.f : 0.f;
  }
}

extern "C" void kernel_launch(void* const* d_in, const int* in_sizes, int n_in,
                              void* d_out, int out_size, void* d_ws, size_t ws_size,
                              hipStream_t stream)
{
  const float* data   = (const float*)d_in[0];
  const float* fc1_w  = (const float*)d_in[1];
  const float* fc1_b  = (const float*)d_in[2];
  const float* cls    = (const float*)d_in[3];
  const float* l1_g   = (const float*)d_in[4];
  const float* l1_b   = (const float*)d_in[5];
  const float* l1_qkv = (const float*)d_in[6];
  const float* l1_ow  = (const float*)d_in[7];
  const float* l1_ob  = (const float*)d_in[8];
  const float* l1_rw  = (const float*)d_in[9];
  const float* w7     = (const float*)d_in[10];
  const float* b7     = (const float*)d_in[11];
  const float* w5     = (const float*)d_in[12];
  const float* b5     = (const float*)d_in[13];
  const float* w3     = (const float*)d_in[14];
  const float* b3     = (const float*)d_in[15];
  const float* l2_g   = (const float*)d_in[16];
  const float* l2_b   = (const float*)d_in[17];
  const float* l2_qkv = (const float*)d_in[18];
  const float* l2_ow  = (const float*)d_in[19];
  const float* l2_ob  = (const float*)d_in[20];
  const float* l2_rw  = (const float*)d_in[21];
  const float* ng     = (const float*)d_in[22];
  const float* nb     = (const float*)d_in[23];
  const float* fc2_w  = (const float*)d_in[24];
  const float* fc2_b  = (const float*)d_in[25];
  float* out = (float*)d_out;

  float* ws   = (float*)d_ws;
  float* h    = ws;
  float* xn   = h    + (size_t)16384 * 512;
  float* qkv  = xn   + (size_t)16384 * 512;
  float* attn = qkv  + (size_t)16384 * 1536;
  float* ql   = attn + (size_t)16384 * 512;
  float* kl   = ql   + 256 * 512;
  float* a2b  = kl   + 256 * 512;
  float* z0   = a2b  + 8 * 256 * 256;
  float* z1   = z0   + 8 * 256 * 256;
  float* xzb  = z1   + 8 * 256 * 256;
  float* tb   = xzb  + 8 * 256 * 256;
  float* ub   = tb   + 8 * 256 * 256;
  float* a3v  = ub   + 8 * 256 * 256;
  float* w2   = a3v  + 8 * 256 * 64;
  float* pacc = w2   + 8 * 256 * 64;           // dead region: 4,194,304 floats (16 MiB)
  float* pms  = pacc + (size_t)8 * 32 * 256 * 64;
  float* red  = pms  + (size_t)8 * 32 * 256 * 2;
  float* wtb  = red  + 32;                       // ppeg weights fp32 (83*512)

  // bf16 transposed weights at start of pacc region: 2.62M ushorts = 1.31M floats
  ushort* fc1_wt  = (ushort*)pacc;
  ushort* qkv_wt0 = fc1_wt + 512 * 1024;
  ushort* qkv_wt1 = qkv_wt0 + 1536 * 512;
  ushort* out_wt0 = qkv_wt1 + 1536 * 512;
  ushort* out_wt1 = out_wt0 + 512 * 512;

  // bf16 activations: xn region as bf16 LN output; data bf16 in qkv region (dead until
  // layer-0 qkv gemm).
  ushort* xnb    = (ushort*)xn;
  ushort* databf = (ushort*)qkv;

  // a3v MFMA partial buffers (alias xn scratch / pms)
  float* a3v_pacc = xn;
  float* a3v_den  = pms;

  // weight prep (bf16 transposes) + data cvt + fc1 + assemble
  wtrans_bf<<<dim3(16, 32), 256, 0, stream>>>(fc1_w, fc1_wt, 1024, 512);
  wtrans_bf<<<dim3(48, 16), 256, 0, stream>>>(l1_qkv, qkv_wt0, 512, 1536);
  wtrans_bf<<<dim3(48, 16), 256, 0, stream>>>(l2_qkv, qkv_wt1, 512, 1536);
  wtrans_bf<<<dim3(16, 16), 256, 0, stream>>>(l1_ow, out_wt0, 512, 512);
  wtrans_bf<<<dim3(16, 16), 256, 0, stream>>>(l2_ow, out_wt1, 512, 512);
  wtrans_kernel<<<2, 256, 0, stream>>>(w7, w5, w3, wtb);
  cvt_bf_kernel<<<8000, 256, 0, stream>>>(data, databf, 16000 * 1024);

  gemm_bb<<<dim3(4, 125), 256, 0, stream>>>(databf, 1024, fc1_wt, 1024, h + 512, 512,
                                            16000, 1024, 1, fc1_b);
  assemble_kernel<<<260, 256, 0, stream>>>(h, cls);

  for (int layer = 0; layer < 2; ++layer) {
    const float* gg = layer ? l2_g   : l1_g;
    const float* bb = layer ? l2_b   : l1_b;
    const ushort* qw = layer ? qkv_wt1 : qkv_wt0;
    const ushort* ow = layer ? out_wt1 : out_wt0;
    const float* ob = layer ? l2_ob  : l1_ob;
    const float* rw = layer ? l2_rw  : l1_rw;

    ln_pad_kernel<<<16384, 256, 0, stream>>>(h, xnb, gg, bb);
    gemm_bb<<<dim3(12, 128), 256, 0, stream>>>(xnb, 512, qw, 512, qkv, 1536,
                                               16384, 512, 2, nullptr);
    landmark_kernel<<<dim3(256, 4), 256, 0, stream>>>(qkv, ql, kl);
    a2_kernel<<<dim3(8, 256), 256, 0, stream>>>(ql, kl, a2b);
    pinv_red1<<<8, 256, 0, stream>>>(a2b, red);
    pinv_red2<<<1, 1, 0, stream>>>(red);
    pinv_init<<<dim3(8, 256), 256, 0, stream>>>(a2b, red, z0);
    float* zc = z0; float* zn = z1;
    for (int it = 0; it < 6; ++it) {
      nmm_kernel<<<dim3(4, 4, 8), 256, 0, stream>>>(a2b, zc, xzb, 0);  // xz = a2@z
      nmm_kernel<<<dim3(4, 4, 8), 256, 0, stream>>>(xzb, xzb, tb, 1);  // u1 = 7xz - xz@xz
      nmm_kernel<<<dim3(4, 4, 8), 256, 0, stream>>>(xzb, tb, ub, 2);   // u2 = 15xz - xz@u1
      nmm_kernel<<<dim3(4, 4, 8), 256, 0, stream>>>(zc, ub, zn, 3);    // z' = .25(13z - z@u2)
      float* sw = zc; zc = zn; zn = sw;
    }
    a3v_mfma<<<dim3(8, CHK), 256, 0, stream>>>(qkv, ql, a3v_pacc, a3v_den);
    a3v_merge_kernel<<<dim3(8, 256), 64, 0, stream>>>(a3v_pacc, a3v_den, a3v);
    mmb_kernel<<<dim3(1, 4, 8), 256, 0, stream>>>(zc, a3v, w2, 64, 1.f);
    a1_mfma<<<dim3(8, 64), 256, 0, stream>>>(qkv, kl, w2, attn);
    resconv_kernel<<<dim3(2048, 2), 256, 0, stream>>>(qkv, rw, attn);
    gemm_bt<<<dim3(4, 127), 256, 0, stream>>>(attn + (size_t)254 * 512, 512, ow, 512,
                                              h, 512, 16130, 512, 3, ob);
    if (layer == 0) {
      // ppeg -> qkv scratch (dead until layer-1 recomputes it), memcpy back
      ppeg_kernel<<<dim3(127 * 4, 8), 256, 0, stream>>>(h, qkv, wtb, b7, b5, b3);
      hipMemcpyAsync(h + 512, qkv, (size_t)16129 * 512 * 4,
                     hipMemcpyDeviceToDevice, stream);
    }
  }
  final_kernel<<<1, 256, 0, stream>>>(h, ng, nb, fc2_w, fc2_b, out);
}

// Round 19
// 1097.188 us; speedup vs baseline: 2.3680x; 1.1538x over previous
//
#include <hip/hip_runtime.h>
#include <math.h>

#define NPAD   16384
#define PADR   254
#define NTOK   16130
#define NPIX   16129
#define SG     127
#define DD     512
#define NH     8
#define CHK    64          // key-chunks per head for a3v

typedef __attribute__((ext_vector_type(8))) short bf16x8;
typedef __attribute__((ext_vector_type(4))) float f32x4;

__device__ __forceinline__ ushort f2bf(float f) {
  uint u = __float_as_uint(f);
  u = (u + 0x7fffu + ((u >> 16) & 1u)) >> 16;
  return (ushort)u;
}

// ---------------- elementwise fp32 -> bf16 (vectorized x8) ----------------
__global__ __launch_bounds__(256) void cvt_bf_kernel(
    const float* __restrict__ src, ushort* __restrict__ dst, int n)
{
  int i = (blockIdx.x * 256 + threadIdx.x) * 8;
  if (i >= n) return;
  float4 a = *(const float4*)(src + i);
  float4 b = *(const float4*)(src + i + 4);
  bf16x8 v;
  v[0] = f2bf(a.x); v[1] = f2bf(a.y); v[2] = f2bf(a.z); v[3] = f2bf(a.w);
  v[4] = f2bf(b.x); v[5] = f2bf(b.y); v[6] = f2bf(b.z); v[7] = f2bf(b.w);
  *(bf16x8*)(dst + i) = v;
}

// ---------------- weight transpose+cvt: src fp32 [K][N] -> dst bf16 [N][K] ----------------
__global__ __launch_bounds__(256) void wtrans_bf(
    const float* __restrict__ src, ushort* __restrict__ dst, int K, int N)
{
  __shared__ float tile[32][33];
  int tx = threadIdx.x & 31, ty = threadIdx.x >> 5;   // 32 x 8
#pragma unroll
  for (int i = 0; i < 4; ++i) {
    int k = blockIdx.y * 32 + ty + i * 8, n = blockIdx.x * 32 + tx;
    tile[ty + i * 8][tx] = src[(size_t)k * N + n];
  }
  __syncthreads();
#pragma unroll
  for (int i = 0; i < 4; ++i) {
    int n = blockIdx.x * 32 + ty + i * 8, k = blockIdx.y * 32 + tx;
    dst[(size_t)n * K + k] = f2bf(tile[tx][ty + i * 8]);
  }
}

// ---------------- bf16 MFMA GEMM (bf16 A): C fp32 = A_bf16 @ Bt_bf16^T ----------------
__global__ __launch_bounds__(256) void gemm_bb(
    const ushort* __restrict__ A, int lda,
    const ushort* __restrict__ Bt, int ldb,
    float* __restrict__ C, int ldc,
    int M, int K, int mode, const float* __restrict__ bias)
{
  const int t = threadIdx.x;
  const int w = t >> 6, l = t & 63, lr = l & 15, lg = l >> 4;
  const int wr = w >> 1, wc = w & 1;
  const int m0 = blockIdx.y * 128, n0 = blockIdx.x * 128;
  __shared__ __align__(16) ushort As[128 * 64];
  __shared__ __align__(16) ushort Bs[128 * 64];
  f32x4 acc[4][4];
#pragma unroll
  for (int i = 0; i < 4; ++i)
#pragma unroll
    for (int j = 0; j < 4; ++j) acc[i][j] = (f32x4){0.f, 0.f, 0.f, 0.f};

  for (int k0 = 0; k0 < K; k0 += 64) {
    __syncthreads();
#pragma unroll
    for (int i = 0; i < 4; ++i) {
      int id = t + i * 256;
      int r = id >> 3, blk = id & 7;
      int gr = m0 + r;
      bf16x8 v = (bf16x8){0, 0, 0, 0, 0, 0, 0, 0};
      if (gr < M) v = *(const bf16x8*)(A + (size_t)gr * lda + k0 + blk * 8);
      *(bf16x8*)(As + r * 64 + ((blk ^ (r & 7)) << 3)) = v;
    }
#pragma unroll
    for (int i = 0; i < 4; ++i) {
      int id = t + i * 256;
      int r = id >> 3, blk = id & 7;
      bf16x8 v = *(const bf16x8*)(Bt + (size_t)(n0 + r) * ldb + k0 + blk * 8);
      *(bf16x8*)(Bs + r * 64 + ((blk ^ (r & 7)) << 3)) = v;
    }
    __syncthreads();
    bf16x8 af[4][2], bfr[4][2];
#pragma unroll
    for (int rt = 0; rt < 4; ++rt) {
      int row = wr * 64 + rt * 16 + lr;
#pragma unroll
      for (int kc = 0; kc < 2; ++kc)
        af[rt][kc] = *(const bf16x8*)(As + row * 64 + (((kc * 4 + lg) ^ (row & 7)) << 3));
    }
#pragma unroll
    for (int nt = 0; nt < 4; ++nt) {
      int row = wc * 64 + nt * 16 + lr;
#pragma unroll
      for (int kc = 0; kc < 2; ++kc)
        bfr[nt][kc] = *(const bf16x8*)(Bs + row * 64 + (((kc * 4 + lg) ^ (row & 7)) << 3));
    }
#pragma unroll
    for (int rt = 0; rt < 4; ++rt)
#pragma unroll
      for (int nt = 0; nt < 4; ++nt) {
        acc[rt][nt] = __builtin_amdgcn_mfma_f32_16x16x32_bf16(af[rt][0], bfr[nt][0], acc[rt][nt], 0, 0, 0);
        acc[rt][nt] = __builtin_amdgcn_mfma_f32_16x16x32_bf16(af[rt][1], bfr[nt][1], acc[rt][nt], 0, 0, 0);
      }
  }
#pragma unroll
  for (int rt = 0; rt < 4; ++rt) {
#pragma unroll
    for (int r = 0; r < 4; ++r) {
      int gi = m0 + wr * 64 + rt * 16 + lg * 4 + r;
      if (gi >= M) continue;
#pragma unroll
      for (int nt = 0; nt < 4; ++nt) {
        int gj = n0 + wc * 64 + nt * 16 + lr;
        float d = acc[rt][nt][r];
        if (mode == 1) d = fmaxf(d + bias[gj], 0.f);
        else if (mode == 2) { if (gj < 512) d *= 0.125f; }
        else if (mode == 3) d += C[(size_t)gi * ldc + gj] + bias[gj];
        C[(size_t)gi * ldc + gj] = d;
      }
    }
  }
}

// ---------------- bf16 MFMA GEMM (fp32 A): C fp32 = A_f32 @ Bt_bf16^T ----------------
__global__ __launch_bounds__(256) void gemm_bt(
    const float* __restrict__ A, int lda,
    const ushort* __restrict__ Bt, int ldb,
    float* __restrict__ C, int ldc,
    int M, int K, int mode, const float* __restrict__ bias)
{
  const int t = threadIdx.x;
  const int w = t >> 6, l = t & 63, lr = l & 15, lg = l >> 4;
  const int wr = w >> 1, wc = w & 1;
  const int m0 = blockIdx.y * 128, n0 = blockIdx.x * 128;
  __shared__ __align__(16) ushort As[128 * 64];
  __shared__ __align__(16) ushort Bs[128 * 64];
  f32x4 acc[4][4];
#pragma unroll
  for (int i = 0; i < 4; ++i)
#pragma unroll
    for (int j = 0; j < 4; ++j) acc[i][j] = (f32x4){0.f, 0.f, 0.f, 0.f};

  for (int k0 = 0; k0 < K; k0 += 64) {
    __syncthreads();
#pragma unroll
    for (int i = 0; i < 2; ++i) {
      int id = t + i * 256;
      int r = id >> 2, db = id & 3;
      const float* src = A + (size_t)(m0 + r) * lda + k0 + db * 16;
      float4 g0 = *(const float4*)(src + 0);
      float4 g1 = *(const float4*)(src + 4);
      float4 g2 = *(const float4*)(src + 8);
      float4 g3 = *(const float4*)(src + 12);
      bf16x8 e0, e1;
      e0[0] = f2bf(g0.x); e0[1] = f2bf(g0.y); e0[2] = f2bf(g0.z); e0[3] = f2bf(g0.w);
      e0[4] = f2bf(g1.x); e0[5] = f2bf(g1.y); e0[6] = f2bf(g1.z); e0[7] = f2bf(g1.w);
      e1[0] = f2bf(g2.x); e1[1] = f2bf(g2.y); e1[2] = f2bf(g2.z); e1[3] = f2bf(g2.w);
      e1[4] = f2bf(g3.x); e1[5] = f2bf(g3.y); e1[6] = f2bf(g3.z); e1[7] = f2bf(g3.w);
      ushort* dst = As + r * 64;
      *(bf16x8*)(dst + (((db * 2 + 0) ^ (r & 7)) << 3)) = e0;
      *(bf16x8*)(dst + (((db * 2 + 1) ^ (r & 7)) << 3)) = e1;
    }
#pragma unroll
    for (int i = 0; i < 4; ++i) {
      int id = t + i * 256;
      int r = id >> 3, blk = id & 7;
      bf16x8 v = *(const bf16x8*)(Bt + (size_t)(n0 + r) * ldb + k0 + blk * 8);
      *(bf16x8*)(Bs + r * 64 + ((blk ^ (r & 7)) << 3)) = v;
    }
    __syncthreads();
    bf16x8 af[4][2], bfr[4][2];
#pragma unroll
    for (int rt = 0; rt < 4; ++rt) {
      int row = wr * 64 + rt * 16 + lr;
#pragma unroll
      for (int kc = 0; kc < 2; ++kc)
        af[rt][kc] = *(const bf16x8*)(As + row * 64 + (((kc * 4 + lg) ^ (row & 7)) << 3));
    }
#pragma unroll
    for (int nt = 0; nt < 4; ++nt) {
      int row = wc * 64 + nt * 16 + lr;
#pragma unroll
      for (int kc = 0; kc < 2; ++kc)
        bfr[nt][kc] = *(const bf16x8*)(Bs + row * 64 + (((kc * 4 + lg) ^ (row & 7)) << 3));
    }
#pragma unroll
    for (int rt = 0; rt < 4; ++rt)
#pragma unroll
      for (int nt = 0; nt < 4; ++nt) {
        acc[rt][nt] = __builtin_amdgcn_mfma_f32_16x16x32_bf16(af[rt][0], bfr[nt][0], acc[rt][nt], 0, 0, 0);
        acc[rt][nt] = __builtin_amdgcn_mfma_f32_16x16x32_bf16(af[rt][1], bfr[nt][1], acc[rt][nt], 0, 0, 0);
      }
  }
#pragma unroll
  for (int rt = 0; rt < 4; ++rt) {
#pragma unroll
    for (int r = 0; r < 4; ++r) {
      int gi = m0 + wr * 64 + rt * 16 + lg * 4 + r;
      if (gi >= M) continue;
#pragma unroll
      for (int nt = 0; nt < 4; ++nt) {
        int gj = n0 + wc * 64 + nt * 16 + lr;
        float d = acc[rt][nt][r];
        if (mode == 1) d = fmaxf(d + bias[gj], 0.f);
        else if (mode == 2) { if (gj < 512) d *= 0.125f; }
        else if (mode == 3) d += C[(size_t)gi * ldc + gj] + bias[gj];
        C[(size_t)gi * ldc + gj] = d;
      }
    }
  }
}

// ==== pinv launch-train (restructured: 3 dependent stages/iter instead of 4) ====
// z' = 0.25*z@(13I - Y@(15I - Y@(7I - Y))), Y=a2@z  ==  0.25*(13z -15W +G@W)
// with Z=z@a2, W=Z@z, G=7Z-Z@Z  (exact reassociation; W,G both depend only on Z
// -> one dual-job launch). [rounds 15-17: all cross-block/single-CU fusions of
// this chain were 3-8x slower; the graph-replayed launch train is measured-best.]

// stage 1 (also generic): D = A@B per head, mode 0: C=D ; 1: C=7A-D
__global__ __launch_bounds__(256) void nmm_kernel(
    const float* __restrict__ A, const float* __restrict__ B,
    float* __restrict__ C, int mode)
{
  const int h_ = blockIdx.z;
  const int m0 = blockIdx.y * 64, n0 = blockIdx.x * 64;
  const float* Ah = A + (size_t)h_ * 65536;
  const float* Bh = B + (size_t)h_ * 65536;
  float* Ch = C + (size_t)h_ * 65536;
  const int t = threadIdx.x, w = t >> 6, l = t & 63, lr = l & 15, lg = l >> 4;
  __shared__ __align__(16) ushort Xs[64 * 64];
  __shared__ __align__(16) ushort Ys[64 * 64];
  f32x4 acc[4];
#pragma unroll
  for (int nt = 0; nt < 4; ++nt) acc[nt] = (f32x4){0.f, 0.f, 0.f, 0.f};

  for (int k0 = 0; k0 < 256; k0 += 64) {
    __syncthreads();
    {
      int r = t >> 2, db = t & 3;
      const float* src = Ah + (size_t)(m0 + r) * 256 + k0 + db * 16;
      float4 g0 = *(const float4*)(src + 0);
      float4 g1 = *(const float4*)(src + 4);
      float4 g2 = *(const float4*)(src + 8);
      float4 g3 = *(const float4*)(src + 12);
      bf16x8 e0, e1;
      e0[0] = f2bf(g0.x); e0[1] = f2bf(g0.y); e0[2] = f2bf(g0.z); e0[3] = f2bf(g0.w);
      e0[4] = f2bf(g1.x); e0[5] = f2bf(g1.y); e0[6] = f2bf(g1.z); e0[7] = f2bf(g1.w);
      e1[0] = f2bf(g2.x); e1[1] = f2bf(g2.y); e1[2] = f2bf(g2.z); e1[3] = f2bf(g2.w);
      e1[4] = f2bf(g3.x); e1[5] = f2bf(g3.y); e1[6] = f2bf(g3.z); e1[7] = f2bf(g3.w);
      ushort* dst = Xs + r * 64;
      *(bf16x8*)(dst + (((db * 2 + 0) ^ (r & 7)) << 3)) = e0;
      *(bf16x8*)(dst + (((db * 2 + 1) ^ (r & 7)) << 3)) = e1;
    }
#pragma unroll
    for (int i = 0; i < 4; ++i) {
      int id = t + i * 256;
      int k = id >> 4, q = id & 15;
      float4 v = *(const float4*)(Bh + (size_t)(k0 + k) * 256 + n0 + q * 4);
      int kb = k >> 3, ke = k & 7;
      Ys[(q * 4 + 0) * 64 + ((kb ^ ((q * 4 + 0) & 7)) << 3) + ke] = f2bf(v.x);
      Ys[(q * 4 + 1) * 64 + ((kb ^ ((q * 4 + 1) & 7)) << 3) + ke] = f2bf(v.y);
      Ys[(q * 4 + 2) * 64 + ((kb ^ ((q * 4 + 2) & 7)) << 3) + ke] = f2bf(v.z);
      Ys[(q * 4 + 3) * 64 + ((kb ^ ((q * 4 + 3) & 7)) << 3) + ke] = f2bf(v.w);
    }
    __syncthreads();
    int arow = w * 16 + lr;
    bf16x8 af0 = *(const bf16x8*)(Xs + arow * 64 + (((0 + lg) ^ (arow & 7)) << 3));
    bf16x8 af1 = *(const bf16x8*)(Xs + arow * 64 + (((4 + lg) ^ (arow & 7)) << 3));
#pragma unroll
    for (int nt = 0; nt < 4; ++nt) {
      int brow = nt * 16 + lr;
      bf16x8 bf0 = *(const bf16x8*)(Ys + brow * 64 + (((0 + lg) ^ (brow & 7)) << 3));
      bf16x8 bf1 = *(const bf16x8*)(Ys + brow * 64 + (((4 + lg) ^ (brow & 7)) << 3));
      acc[nt] = __builtin_amdgcn_mfma_f32_16x16x32_bf16(af0, bf0, acc[nt], 0, 0, 0);
      acc[nt] = __builtin_amdgcn_mfma_f32_16x16x32_bf16(af1, bf1, acc[nt], 0, 0, 0);
    }
  }
#pragma unroll
  for (int nt = 0; nt < 4; ++nt) {
#pragma unroll
    for (int r = 0; r < 4; ++r) {
      int gi = m0 + w * 16 + lg * 4 + r;
      int gj = n0 + nt * 16 + lr;
      float d = acc[nt][r];
      if (mode == 1) d = 7.f * Ah[(size_t)gi * 256 + gj] - d;
      Ch[(size_t)gi * 256 + gj] = d;
    }
  }
}

// stage 2 (dual job): job0: W = Z@z ; job1: G = 7Z - Z@Z.  grid (4,4,16)
__global__ __launch_bounds__(256) void nmm_s2(
    const float* __restrict__ Z, const float* __restrict__ z,
    float* __restrict__ W, float* __restrict__ G)
{
  const int h_ = blockIdx.z & 7;
  const int job = blockIdx.z >> 3;
  const int m0 = blockIdx.y * 64, n0 = blockIdx.x * 64;
  const float* Ah = Z + (size_t)h_ * 65536;
  const float* Bh = (job == 0 ? z : Z) + (size_t)h_ * 65536;
  float* Ch = (job == 0 ? W : G) + (size_t)h_ * 65536;
  const int t = threadIdx.x, w = t >> 6, l = t & 63, lr = l & 15, lg = l >> 4;
  __shared__ __align__(16) ushort Xs[64 * 64];
  __shared__ __align__(16) ushort Ys[64 * 64];
  f32x4 acc[4];
#pragma unroll
  for (int nt = 0; nt < 4; ++nt) acc[nt] = (f32x4){0.f, 0.f, 0.f, 0.f};

  for (int k0 = 0; k0 < 256; k0 += 64) {
    __syncthreads();
    {
      int r = t >> 2, db = t & 3;
      const float* src = Ah + (size_t)(m0 + r) * 256 + k0 + db * 16;
      float4 g0 = *(const float4*)(src + 0);
      float4 g1 = *(const float4*)(src + 4);
      float4 g2 = *(const float4*)(src + 8);
      float4 g3 = *(const float4*)(src + 12);
      bf16x8 e0, e1;
      e0[0] = f2bf(g0.x); e0[1] = f2bf(g0.y); e0[2] = f2bf(g0.z); e0[3] = f2bf(g0.w);
      e0[4] = f2bf(g1.x); e0[5] = f2bf(g1.y); e0[6] = f2bf(g1.z); e0[7] = f2bf(g1.w);
      e1[0] = f2bf(g2.x); e1[1] = f2bf(g2.y); e1[2] = f2bf(g2.z); e1[3] = f2bf(g2.w);
      e1[4] = f2bf(g3.x); e1[5] = f2bf(g3.y); e1[6] = f2bf(g3.z); e1[7] = f2bf(g3.w);
      ushort* dst = Xs + r * 64;
      *(bf16x8*)(dst + (((db * 2 + 0) ^ (r & 7)) << 3)) = e0;
      *(bf16x8*)(dst + (((db * 2 + 1) ^ (r & 7)) << 3)) = e1;
    }
#pragma unroll
    for (int i = 0; i < 4; ++i) {
      int id = t + i * 256;
      int k = id >> 4, q = id & 15;
      float4 v = *(const float4*)(Bh + (size_t)(k0 + k) * 256 + n0 + q * 4);
      int kb = k >> 3, ke = k & 7;
      Ys[(q * 4 + 0) * 64 + ((kb ^ ((q * 4 + 0) & 7)) << 3) + ke] = f2bf(v.x);
      Ys[(q * 4 + 1) * 64 + ((kb ^ ((q * 4 + 1) & 7)) << 3) + ke] = f2bf(v.y);
      Ys[(q * 4 + 2) * 64 + ((kb ^ ((q * 4 + 2) & 7)) << 3) + ke] = f2bf(v.z);
      Ys[(q * 4 + 3) * 64 + ((kb ^ ((q * 4 + 3) & 7)) << 3) + ke] = f2bf(v.w);
    }
    __syncthreads();
    int arow = w * 16 + lr;
    bf16x8 af0 = *(const bf16x8*)(Xs + arow * 64 + (((0 + lg) ^ (arow & 7)) << 3));
    bf16x8 af1 = *(const bf16x8*)(Xs + arow * 64 + (((4 + lg) ^ (arow & 7)) << 3));
#pragma unroll
    for (int nt = 0; nt < 4; ++nt) {
      int brow = nt * 16 + lr;
      bf16x8 bf0 = *(const bf16x8*)(Ys + brow * 64 + (((0 + lg) ^ (brow & 7)) << 3));
      bf16x8 bf1 = *(const bf16x8*)(Ys + brow * 64 + (((4 + lg) ^ (brow & 7)) << 3));
      acc[nt] = __builtin_amdgcn_mfma_f32_16x16x32_bf16(af0, bf0, acc[nt], 0, 0, 0);
      acc[nt] = __builtin_amdgcn_mfma_f32_16x16x32_bf16(af1, bf1, acc[nt], 0, 0, 0);
    }
  }
#pragma unroll
  for (int nt = 0; nt < 4; ++nt) {
#pragma unroll
    for (int r = 0; r < 4; ++r) {
      int gi = m0 + w * 16 + lg * 4 + r;
      int gj = n0 + nt * 16 + lr;
      float d = acc[nt][r];
      if (job == 1) d = 7.f * Ah[(size_t)gi * 256 + gj] - d;
      Ch[(size_t)gi * 256 + gj] = d;
    }
  }
}

// stage 3: zn = 0.25*(13*zc - 15*W + G@W).  grid (4,4,8)
__global__ __launch_bounds__(256) void nmm_s3(
    const float* __restrict__ G, const float* __restrict__ W,
    const float* __restrict__ zc, float* __restrict__ zn)
{
  const int h_ = blockIdx.z;
  const int m0 = blockIdx.y * 64, n0 = blockIdx.x * 64;
  const float* Ah = G + (size_t)h_ * 65536;
  const float* Bh = W + (size_t)h_ * 65536;
  const float* Eh = zc + (size_t)h_ * 65536;
  float* Ch = zn + (size_t)h_ * 65536;
  const int t = threadIdx.x, w = t >> 6, l = t & 63, lr = l & 15, lg = l >> 4;
  __shared__ __align__(16) ushort Xs[64 * 64];
  __shared__ __align__(16) ushort Ys[64 * 64];
  f32x4 acc[4];
#pragma unroll
  for (int nt = 0; nt < 4; ++nt) acc[nt] = (f32x4){0.f, 0.f, 0.f, 0.f};

  for (int k0 = 0; k0 < 256; k0 += 64) {
    __syncthreads();
    {
      int r = t >> 2, db = t & 3;
      const float* src = Ah + (size_t)(m0 + r) * 256 + k0 + db * 16;
      float4 g0 = *(const float4*)(src + 0);
      float4 g1 = *(const float4*)(src + 4);
      float4 g2 = *(const float4*)(src + 8);
      float4 g3 = *(const float4*)(src + 12);
      bf16x8 e0, e1;
      e0[0] = f2bf(g0.x); e0[1] = f2bf(g0.y); e0[2] = f2bf(g0.z); e0[3] = f2bf(g0.w);
      e0[4] = f2bf(g1.x); e0[5] = f2bf(g1.y); e0[6] = f2bf(g1.z); e0[7] = f2bf(g1.w);
      e1[0] = f2bf(g2.x); e1[1] = f2bf(g2.y); e1[2] = f2bf(g2.z); e1[3] = f2bf(g2.w);
      e1[4] = f2bf(g3.x); e1[5] = f2bf(g3.y); e1[6] = f2bf(g3.z); e1[7] = f2bf(g3.w);
      ushort* dst = Xs + r * 64;
      *(bf16x8*)(dst + (((db * 2 + 0) ^ (r & 7)) << 3)) = e0;
      *(bf16x8*)(dst + (((db * 2 + 1) ^ (r & 7)) << 3)) = e1;
    }
#pragma unroll
    for (int i = 0; i < 4; ++i) {
      int id = t + i * 256;
      int k = id >> 4, q = id & 15;
      float4 v = *(const float4*)(Bh + (size_t)(k0 + k) * 256 + n0 + q * 4);
      int kb = k >> 3, ke = k & 7;
      Ys[(q * 4 + 0) * 64 + ((kb ^ ((q * 4 + 0) & 7)) << 3) + ke] = f2bf(v.x);
      Ys[(q * 4 + 1) * 64 + ((kb ^ ((q * 4 + 1) & 7)) << 3) + ke] = f2bf(v.y);
      Ys[(q * 4 + 2) * 64 + ((kb ^ ((q * 4 + 2) & 7)) << 3) + ke] = f2bf(v.z);
      Ys[(q * 4 + 3) * 64 + ((kb ^ ((q * 4 + 3) & 7)) << 3) + ke] = f2bf(v.w);
    }
    __syncthreads();
    int arow = w * 16 + lr;
    bf16x8 af0 = *(const bf16x8*)(Xs + arow * 64 + (((0 + lg) ^ (arow & 7)) << 3));
    bf16x8 af1 = *(const bf16x8*)(Xs + arow * 64 + (((4 + lg) ^ (arow & 7)) << 3));
#pragma unroll
    for (int nt = 0; nt < 4; ++nt) {
      int brow = nt * 16 + lr;
      bf16x8 bf0 = *(const bf16x8*)(Ys + brow * 64 + (((0 + lg) ^ (brow & 7)) << 3));
      bf16x8 bf1 = *(const bf16x8*)(Ys + brow * 64 + (((4 + lg) ^ (brow & 7)) << 3));
      acc[nt] = __builtin_amdgcn_mfma_f32_16x16x32_bf16(af0, bf0, acc[nt], 0, 0, 0);
      acc[nt] = __builtin_amdgcn_mfma_f32_16x16x32_bf16(af1, bf1, acc[nt], 0, 0, 0);
    }
  }
#pragma unroll
  for (int nt = 0; nt < 4; ++nt) {
#pragma unroll
    for (int r = 0; r < 4; ++r) {
      int gi = m0 + w * 16 + lg * 4 + r;
      int gj = n0 + nt * 16 + lr;
      size_t o = (size_t)gi * 256 + gj;
      Ch[o] = 0.25f * (13.f * Eh[o] - 15.f * Bh[o] + acc[nt][r]);
    }
  }
}

// ---------------- assemble: h[0]=cls, h[16001+i]=h[1+i] (i<129) ----------------
__global__ __launch_bounds__(256) void assemble_kernel(float* __restrict__ h,
                                                       const float* __restrict__ cls)
{
  int idx = blockIdx.x * 256 + threadIdx.x;
  if (idx < 512) { h[idx] = cls[idx]; return; }
  idx -= 512;
  int i = idx >> 9, c = idx & 511;
  h[(size_t)(16001 + i) * DD + c] = h[(size_t)(1 + i) * DD + c];
}

// ---------------- LayerNorm rows of h -> xn (bf16 out; front-padded) ----------------
__global__ __launch_bounds__(256) void ln_pad_kernel(
    const float* __restrict__ h, ushort* __restrict__ xn,
    const float* __restrict__ g, const float* __restrict__ b)
{
  int row = blockIdx.x;
  int t = threadIdx.x;
  if (row < PADR) {
    xn[(size_t)row * DD + t] = 0;
    xn[(size_t)row * DD + t + 256] = 0;
    return;
  }
  const float* x = h + (size_t)(row - PADR) * DD;
  __shared__ float red[256];
  float v0 = x[t], v1 = x[t + 256];
  red[t] = v0 + v1;
  __syncthreads();
  for (int s = 128; s > 0; s >>= 1) { if (t < s) red[t] += red[t + s]; __syncthreads(); }
  float mu = red[0] * (1.f / 512.f);
  __syncthreads();
  float d0 = v0 - mu, d1 = v1 - mu;
  red[t] = d0 * d0 + d1 * d1;
  __syncthreads();
  for (int s = 128; s > 0; s >>= 1) { if (t < s) red[t] += red[t + s]; __syncthreads(); }
  float rs = rsqrtf(red[0] * (1.f / 512.f) + 1e-5f);
  ushort* o = xn + (size_t)row * DD;
  o[t]       = f2bf(d0 * rs * g[t] + b[t]);
  o[t + 256] = f2bf(d1 * rs * g[t + 256] + b[t + 256]);
}

// ---------------- landmarks ----------------
__global__ __launch_bounds__(256) void landmark_kernel(
    const float* __restrict__ qkv, float* __restrict__ ql, float* __restrict__ kl)
{
  int i = blockIdx.x;
  int c = blockIdx.y * 256 + threadIdx.x;
  const float* p = qkv + (size_t)(i * 64) * 1536 + c;
  float s = 0.f;
  for (int j = 0; j < 64; ++j) s += p[(size_t)j * 1536];
  s *= (1.f / 64.f);
  if (c < 512) ql[(size_t)i * 512 + c] = s;
  else         kl[(size_t)i * 512 + (c - 512)] = s;
}

// ---------------- a2 = softmax(ql . kl^T) per head ----------------
__global__ __launch_bounds__(256) void a2_kernel(
    const float* __restrict__ ql, const float* __restrict__ kl, float* __restrict__ a2)
{
  int h_ = blockIdx.x, i = blockIdx.y;
  int t = threadIdx.x;
  __shared__ float q[64];
  __shared__ float red[256];
  if (t < 64) q[t] = ql[(size_t)i * 512 + h_ * 64 + t];
  __syncthreads();
  const float* kr = kl + (size_t)t * 512 + h_ * 64;
  float s = 0.f;
#pragma unroll
  for (int d = 0; d < 64; ++d) s = fmaf(q[d], kr[d], s);
  red[t] = s;
  __syncthreads();
  for (int st = 128; st > 0; st >>= 1) { if (t < st) red[t] = fmaxf(red[t], red[t + st]); __syncthreads(); }
  float mx = red[0];
  __syncthreads();
  float e = __expf(s - mx);
  red[t] = e;
  __syncthreads();
  for (int st = 128; st > 0; st >>= 1) { if (t < st) red[t] += red[t + st]; __syncthreads(); }
  a2[((size_t)h_ * 256 + i) * 256 + t] = e / red[0];
}

// ---------------- pinv init reductions ----------------
__global__ __launch_bounds__(256) void pinv_red1(const float* __restrict__ a2, float* __restrict__ red)
{
  int h_ = blockIdx.x, t = threadIdx.x;
  const float* X = a2 + (size_t)h_ * 65536;
  float rs = 0.f, cs = 0.f;
  for (int j = 0; j < 256; ++j) rs += fabsf(X[(size_t)t * 256 + j]);
  for (int i = 0; i < 256; ++i) cs += fabsf(X[(size_t)i * 256 + t]);
  __shared__ float r1[256], r2[256];
  r1[t] = rs; r2[t] = cs;
  __syncthreads();
  for (int s = 128; s > 0; s >>= 1) {
    if (t < s) { r1[t] = fmaxf(r1[t], r1[t + s]); r2[t] = fmaxf(r2[t], r2[t + s]); }
    __syncthreads();
  }
  if (t == 0) { red[h_ * 2] = r1[0]; red[h_ * 2 + 1] = r2[0]; }
}
// init z0 = a2^T / (max_row * max_col); red2 folded in (each thread scans 16 vals)
__global__ __launch_bounds__(256) void pinv_init(
    const float* __restrict__ a2, const float* __restrict__ red, float* __restrict__ z)
{
  int h_ = blockIdx.x, i = blockIdx.y, j = threadIdx.x;
  float mr = 0.f, mc = 0.f;
#pragma unroll
  for (int k = 0; k < 8; ++k) { mr = fmaxf(mr, red[k * 2]); mc = fmaxf(mc, red[k * 2 + 1]); }
  float inv = 1.f / (mr * mc);
  z[((size_t)h_ * 256 + i) * 256 + j] = a2[((size_t)h_ * 256 + j) * 256 + i] * inv;
}

// ---------------- batched matmul per head: C = alpha*(A @ B), A 256x256, B 256xN ----------------
__global__ __launch_bounds__(256) void mmb_kernel(
    const float* __restrict__ A, const float* __restrict__ B, float* __restrict__ C,
    int N, float alpha)
{
  int h_ = blockIdx.z;
  const float* Ah = A + (size_t)h_ * 256 * 256;
  const float* Bh = B + (size_t)h_ * 256 * N;
  float* Ch = C + (size_t)h_ * 256 * N;
  int m0 = blockIdx.y * 64, n0 = blockIdx.x * 64;
  __shared__ float As[16][68];
  __shared__ float Bs[16][68];
  int tid = threadIdx.x, tx = tid & 15, ty = tid >> 4;
  float acc[4][4];
#pragma unroll
  for (int i = 0; i < 4; ++i)
#pragma unroll
    for (int j = 0; j < 4; ++j) acc[i][j] = 0.f;
  for (int k0 = 0; k0 < 256; k0 += 16) {
    {
      int row = tid >> 2, k4 = (tid & 3) << 2;
      float4 v = *(const float4*)(Ah + (size_t)(m0 + row) * 256 + k0 + k4);
      As[k4 + 0][row] = v.x; As[k4 + 1][row] = v.y;
      As[k4 + 2][row] = v.z; As[k4 + 3][row] = v.w;
    }
    {
      int row = tid >> 4, c4 = (tid & 15) << 2;
      *(float4*)&Bs[row][c4] = *(const float4*)(Bh + (size_t)(k0 + row) * N + n0 + c4);
    }
    __syncthreads();
#pragma unroll
    for (int k = 0; k < 16; ++k) {
      float a[4], b[4];
      *(float4*)a = *(const float4*)&As[k][ty * 4];
      *(float4*)b = *(const float4*)&Bs[k][tx * 4];
#pragma unroll
      for (int i = 0; i < 4; ++i)
#pragma unroll
        for (int j = 0; j < 4; ++j) acc[i][j] = fmaf(a[i], b[j], acc[i][j]);
    }
    __syncthreads();
  }
#pragma unroll
  for (int i = 0; i < 4; ++i) {
    float4 r;
    r.x = alpha * acc[i][0]; r.y = alpha * acc[i][1];
    r.z = alpha * acc[i][2]; r.w = alpha * acc[i][3];
    *(float4*)(Ch + (size_t)(m0 + ty * 4 + i) * N + n0 + tx * 4) = r;
  }
}

// ---------------- a3@v partials via bf16 MFMA flash (no-max exp, ones-column den) ----------
__global__ __launch_bounds__(256) void a3v_mfma(
    const float* __restrict__ qkv, const float* __restrict__ ql,
    float* __restrict__ pacc, float* __restrict__ den)
{
  const int h_ = blockIdx.x;
  const int ch = blockIdx.y;
  const int t  = threadIdx.x;
  const int w  = t >> 6;
  const int l  = t & 63;
  const int lr = l & 15;
  const int lg = l >> 4;

  __shared__ __align__(16) ushort kls[64 * 64];
  __shared__ __align__(16) ushort vls[80 * 64];
  __shared__ __align__(16) ushort pls[4][64 * 64];

  bf16x8 qf[4][2];
#pragma unroll
  for (int rt = 0; rt < 4; ++rt)
#pragma unroll
    for (int dc = 0; dc < 2; ++dc) {
      const float* p = ql + (size_t)(64 * w + rt * 16 + lr) * 512 + h_ * 64 + dc * 32 + lg * 8;
      float4 f0 = *(const float4*)p;
      float4 f1 = *(const float4*)(p + 4);
      bf16x8 v;
      v[0] = f2bf(f0.x); v[1] = f2bf(f0.y); v[2] = f2bf(f0.z); v[3] = f2bf(f0.w);
      v[4] = f2bf(f1.x); v[5] = f2bf(f1.y); v[6] = f2bf(f1.z); v[7] = f2bf(f1.w);
      qf[rt][dc] = v;
    }

  if (t < 128) {
    int rr = t >> 3, cb = t & 7;
    ushort val = (rr == 0) ? (ushort)0x3f80 : (ushort)0;
    bf16x8 vv;
#pragma unroll
    for (int k = 0; k < 8; ++k) vv[k] = (short)val;
    *(bf16x8*)(vls + (64 + rr) * 64 + ((cb ^ (rr & 7)) << 3)) = vv;
  }

  f32x4 acc[4][5];
#pragma unroll
  for (int rt = 0; rt < 4; ++rt)
#pragma unroll
    for (int dt = 0; dt < 5; ++dt) acc[rt][dt] = (f32x4){0.f, 0.f, 0.f, 0.f};

  const int j0base = ch * 256;
  for (int jt = 0; jt < 4; ++jt) {
    const int j0 = j0base + jt * 64;
    __syncthreads();
    {
      int r = t >> 2, db = t & 3;
      const float* src = qkv + (size_t)(j0 + r) * 1536 + 512 + h_ * 64 + db * 16;
      float4 g0 = *(const float4*)(src + 0);
      float4 g1 = *(const float4*)(src + 4);
      float4 g2 = *(const float4*)(src + 8);
      float4 g3 = *(const float4*)(src + 12);
      bf16x8 e0, e1;
      e0[0] = f2bf(g0.x); e0[1] = f2bf(g0.y); e0[2] = f2bf(g0.z); e0[3] = f2bf(g0.w);
      e0[4] = f2bf(g1.x); e0[5] = f2bf(g1.y); e0[6] = f2bf(g1.z); e0[7] = f2bf(g1.w);
      e1[0] = f2bf(g2.x); e1[1] = f2bf(g2.y); e1[2] = f2bf(g2.z); e1[3] = f2bf(g2.w);
      e1[4] = f2bf(g3.x); e1[5] = f2bf(g3.y); e1[6] = f2bf(g3.z); e1[7] = f2bf(g3.w);
      ushort* base = kls + r * 64;
      *(bf16x8*)(base + (((db * 2 + 0) ^ (r & 7)) << 3)) = e0;
      *(bf16x8*)(base + (((db * 2 + 1) ^ (r & 7)) << 3)) = e1;
    }
    {
      int d = t & 63, jg = t >> 6;
#pragma unroll
      for (int half = 0; half < 2; ++half) {
        int jb = jg + half * 4;
        bf16x8 e;
#pragma unroll
        for (int jj = 0; jj < 8; ++jj)
          e[jj] = f2bf(qkv[(size_t)(j0 + jb * 8 + jj) * 1536 + 1024 + h_ * 64 + d]);
        *(bf16x8*)(vls + d * 64 + ((jb ^ (d & 7)) << 3)) = e;
      }
    }
    __syncthreads();

    ushort* pw = pls[w];
#pragma unroll
    for (int sjt = 0; sjt < 4; ++sjt) {
      const int krow = sjt * 16 + lr;
      bf16x8 kf0 = *(const bf16x8*)(kls + krow * 64 + (((0 * 4 + lg) ^ (lr & 7)) << 3));
      bf16x8 kf1 = *(const bf16x8*)(kls + krow * 64 + (((1 * 4 + lg) ^ (lr & 7)) << 3));
#pragma unroll
      for (int rt = 0; rt < 4; ++rt) {
        f32x4 s = (f32x4){0.f, 0.f, 0.f, 0.f};
        s = __builtin_amdgcn_mfma_f32_16x16x32_bf16(qf[rt][0], kf0, s, 0, 0, 0);
        s = __builtin_amdgcn_mfma_f32_16x16x32_bf16(qf[rt][1], kf1, s, 0, 0, 0);
#pragma unroll
        for (int r = 0; r < 4; ++r) {
          int i  = rt * 16 + lg * 4 + r;
          int jj = sjt * 16 + lr;
          pw[i * 64 + ((((jj >> 3) ^ (i & 7)) << 3)) + (jj & 7)] = (short)f2bf(__expf(s[r]));
        }
      }
    }
    bf16x8 pf[4][2];
#pragma unroll
    for (int rt = 0; rt < 4; ++rt)
#pragma unroll
      for (int jc = 0; jc < 2; ++jc)
        pf[rt][jc] = *(const bf16x8*)(pw + (rt * 16 + lr) * 64 + (((jc * 4 + lg) ^ (lr & 7)) << 3));
#pragma unroll
    for (int dt = 0; dt < 5; ++dt) {
      const int vrow = dt * 16 + lr;
      bf16x8 vf0 = *(const bf16x8*)(vls + vrow * 64 + (((0 * 4 + lg) ^ (lr & 7)) << 3));
      bf16x8 vf1 = *(const bf16x8*)(vls + vrow * 64 + (((1 * 4 + lg) ^ (lr & 7)) << 3));
#pragma unroll
      for (int rt = 0; rt < 4; ++rt) {
        acc[rt][dt] = __builtin_amdgcn_mfma_f32_16x16x32_bf16(pf[rt][0], vf0, acc[rt][dt], 0, 0, 0);
        acc[rt][dt] = __builtin_amdgcn_mfma_f32_16x16x32_bf16(pf[rt][1], vf1, acc[rt][dt], 0, 0, 0);
      }
    }
  }

  const size_t pbase = (size_t)(h_ * CHK + ch) * 256;
#pragma unroll
  for (int rt = 0; rt < 4; ++rt) {
    int i = 64 * w + rt * 16 + lg * 4;
#pragma unroll
    for (int dt = 0; dt < 4; ++dt)
#pragma unroll
      for (int r = 0; r < 4; ++r)
        pacc[(pbase + i + r) * 64 + dt * 16 + lr] = acc[rt][dt][r];
    if (lr == 0) {
#pragma unroll
      for (int r = 0; r < 4; ++r)
        den[pbase + i + r] = acc[rt][4][r];
    }
  }
}

// ---------------- merge a3v partials ----------------
__global__ __launch_bounds__(64) void a3v_merge_kernel(
    const float* __restrict__ pacc, const float* __restrict__ den, float* __restrict__ a3v)
{
  int h_ = blockIdx.x, i = blockIdx.y, d = threadIdx.x;
  float S = 0.f, o = 0.f;
  for (int c = 0; c < CHK; ++c) {
    size_t b = (size_t)(h_ * CHK + c) * 256 + i;
    o += pacc[b * 64 + d];
    S += den[b];
  }
  a3v[((size_t)h_ * 256 + i) * 64 + d] = o / S;
}

// ---------------- a1: out = softmax(q . kl^T) @ w2 via bf16 MFMA ----------------
__global__ __launch_bounds__(256) void a1_mfma(
    const float* __restrict__ qkv, const float* __restrict__ kl,
    const float* __restrict__ w2, float* __restrict__ attn)
{
  const int h_ = blockIdx.x;
  const int rb = blockIdx.y;
  const int t  = threadIdx.x;
  const int w  = t >> 6, l = t & 63, lr = l & 15, lg = l >> 4;

  __shared__ __align__(16) ushort kls[64 * 64];
  __shared__ __align__(16) ushort wls[80 * 64];
  __shared__ __align__(16) ushort pls[4][64 * 64];

  bf16x8 qf[4][2];
#pragma unroll
  for (int rt = 0; rt < 4; ++rt)
#pragma unroll
    for (int dc = 0; dc < 2; ++dc) {
      const float* p = qkv + (size_t)(rb * 256 + w * 64 + rt * 16 + lr) * 1536 + h_ * 64 + dc * 32 + lg * 8;
      float4 f0 = *(const float4*)p;
      float4 f1 = *(const float4*)(p + 4);
      bf16x8 v;
      v[0] = f2bf(f0.x); v[1] = f2bf(f0.y); v[2] = f2bf(f0.z); v[3] = f2bf(f0.w);
      v[4] = f2bf(f1.x); v[5] = f2bf(f1.y); v[6] = f2bf(f1.z); v[7] = f2bf(f1.w);
      qf[rt][dc] = v;
    }

  if (t < 128) {
    int rr = t >> 3, cb = t & 7;
    ushort val = (rr == 0) ? (ushort)0x3f80 : (ushort)0;
    bf16x8 vv;
#pragma unroll
    for (int k = 0; k < 8; ++k) vv[k] = (short)val;
    *(bf16x8*)(wls + (64 + rr) * 64 + ((cb ^ (rr & 7)) << 3)) = vv;
  }

  f32x4 acc[4][5];
#pragma unroll
  for (int rt = 0; rt < 4; ++rt)
#pragma unroll
    for (int dt = 0; dt < 5; ++dt) acc[rt][dt] = (f32x4){0.f, 0.f, 0.f, 0.f};

  for (int kc = 0; kc < 4; ++kc) {
    const int j0 = kc * 64;
    __syncthreads();
    {
      int r = t >> 2, db = t & 3;
      const float* src = kl + (size_t)(j0 + r) * 512 + h_ * 64 + db * 16;
      float4 g0 = *(const float4*)(src + 0);
      float4 g1 = *(const float4*)(src + 4);
      float4 g2 = *(const float4*)(src + 8);
      float4 g3 = *(const float4*)(src + 12);
      bf16x8 e0, e1;
      e0[0] = f2bf(g0.x); e0[1] = f2bf(g0.y); e0[2] = f2bf(g0.z); e0[3] = f2bf(g0.w);
      e0[4] = f2bf(g1.x); e0[5] = f2bf(g1.y); e0[6] = f2bf(g1.z); e0[7] = f2bf(g1.w);
      e1[0] = f2bf(g2.x); e1[1] = f2bf(g2.y); e1[2] = f2bf(g2.z); e1[3] = f2bf(g2.w);
      e1[4] = f2bf(g3.x); e1[5] = f2bf(g3.y); e1[6] = f2bf(g3.z); e1[7] = f2bf(g3.w);
      ushort* base = kls + r * 64;
      *(bf16x8*)(base + (((db * 2 + 0) ^ (r & 7)) << 3)) = e0;
      *(bf16x8*)(base + (((db * 2 + 1) ^ (r & 7)) << 3)) = e1;
    }
    {
      int d = t & 63, jg = t >> 6;
#pragma unroll
      for (int half = 0; half < 2; ++half) {
        int jb = jg + half * 4;
        bf16x8 e;
#pragma unroll
        for (int jj = 0; jj < 8; ++jj)
          e[jj] = f2bf(w2[((size_t)h_ * 256 + j0 + jb * 8 + jj) * 64 + d]);
        *(bf16x8*)(wls + d * 64 + ((jb ^ (d & 7)) << 3)) = e;
      }
    }
    __syncthreads();

    ushort* pw = pls[w];
#pragma unroll
    for (int sjt = 0; sjt < 4; ++sjt) {
      const int krow = sjt * 16 + lr;
      bf16x8 kf0 = *(const bf16x8*)(kls + krow * 64 + (((0 * 4 + lg) ^ (lr & 7)) << 3));
      bf16x8 kf1 = *(const bf16x8*)(kls + krow * 64 + (((1 * 4 + lg) ^ (lr & 7)) << 3));
#pragma unroll
      for (int rt = 0; rt < 4; ++rt) {
        f32x4 s = (f32x4){0.f, 0.f, 0.f, 0.f};
        s = __builtin_amdgcn_mfma_f32_16x16x32_bf16(qf[rt][0], kf0, s, 0, 0, 0);
        s = __builtin_amdgcn_mfma_f32_16x16x32_bf16(qf[rt][1], kf1, s, 0, 0, 0);
#pragma unroll
        for (int r = 0; r < 4; ++r) {
          int i  = rt * 16 + lg * 4 + r;
          int jj = sjt * 16 + lr;
          pw[i * 64 + ((((jj >> 3) ^ (i & 7)) << 3)) + (jj & 7)] = (short)f2bf(__expf(s[r]));
        }
      }
    }
    bf16x8 pf[4][2];
#pragma unroll
    for (int rt = 0; rt < 4; ++rt)
#pragma unroll
      for (int jc = 0; jc < 2; ++jc)
        pf[rt][jc] = *(const bf16x8*)(pw + (rt * 16 + lr) * 64 + (((jc * 4 + lg) ^ (lr & 7)) << 3));
#pragma unroll
    for (int dt = 0; dt < 5; ++dt) {
      const int vrow = dt * 16 + lr;
      bf16x8 vf0 = *(const bf16x8*)(wls + vrow * 64 + (((0 * 4 + lg) ^ (lr & 7)) << 3));
      bf16x8 vf1 = *(const bf16x8*)(wls + vrow * 64 + (((1 * 4 + lg) ^ (lr & 7)) << 3));
#pragma unroll
      for (int rt = 0; rt < 4; ++rt) {
        acc[rt][dt] = __builtin_amdgcn_mfma_f32_16x16x32_bf16(pf[rt][0], vf0, acc[rt][dt], 0, 0, 0);
        acc[rt][dt] = __builtin_amdgcn_mfma_f32_16x16x32_bf16(pf[rt][1], vf1, acc[rt][dt], 0, 0, 0);
      }
    }
  }

#pragma unroll
  for (int rt = 0; rt < 4; ++rt) {
#pragma unroll
    for (int r = 0; r < 4; ++r) {
      float dn = __shfl(acc[rt][4][r], l & 48);
      float inv = 1.f / dn;
      int gr = rb * 256 + w * 64 + rt * 16 + lg * 4 + r;
      float* op = attn + (size_t)gr * 512 + h_ * 64;
#pragma unroll
      for (int dt = 0; dt < 4; ++dt)
        op[dt * 16 + lr] = acc[rt][dt][r] * inv;
    }
  }
}

// ---------------- depthwise res conv (kernel 33): register sliding window ----------------
__global__ __launch_bounds__(256) void resconv_kernel(
    const float* __restrict__ qkv, const float* __restrict__ rw, float* __restrict__ attn)
{
  const int bid = blockIdx.x;                 // 0..2047 (2048 % 8 == 0 -> bijective)
  const int rb  = (bid & 7) * 256 + (bid >> 3);
  const int r0  = rb * 8;
  const int c   = blockIdx.y * 256 + threadIdx.x;
  const int h_  = c >> 6;

  float wreg[33];
#pragma unroll
  for (int tp = 0; tp < 33; ++tp) wreg[tp] = rw[h_ * 33 + tp];   // wave-uniform broadcast

  float v[40];
#pragma unroll
  for (int k = 0; k < 40; ++k) {
    int rr = r0 - 16 + k;
    v[k] = (rr >= 0 && rr < NPAD) ? qkv[(size_t)rr * 1536 + 1024 + c] : 0.f;
  }
#pragma unroll
  for (int i = 0; i < 8; ++i) {
    float s = 0.f;
#pragma unroll
    for (int tp = 0; tp < 33; ++tp)
      s = fmaf(v[i + tp], wreg[tp], s);
    attn[(size_t)(r0 + i) * 512 + c] += s;
  }
}

// ---------------- weight transpose for ppeg: wt[k*512+c] ----------------
__global__ __launch_bounds__(256) void wtrans_kernel(
    const float* __restrict__ w7, const float* __restrict__ w5,
    const float* __restrict__ w3, float* __restrict__ wt)
{
  int c = blockIdx.x * 256 + threadIdx.x;
  for (int k = 0; k < 49; ++k) wt[(size_t)k * 512 + c]        = w7[(size_t)c * 49 + k];
  for (int k = 0; k < 25; ++k) wt[(size_t)(49 + k) * 512 + c] = w5[(size_t)c * 25 + k];
  for (int k = 0; k < 9;  ++k) wt[(size_t)(74 + k) * 512 + c] = w3[(size_t)c * 9 + k];
}

// ---------------- PPEG: 64 ch/block, x-sliding window, column prefetch ----------------
__global__ __launch_bounds__(256) void ppeg_kernel(
    const float* __restrict__ h, float* __restrict__ tmp,
    const float* __restrict__ wt,
    const float* __restrict__ b7, const float* __restrict__ b5,
    const float* __restrict__ b3)
{
  __shared__ float wl[83 * 64];            // 21,248 B
  const int t  = threadIdx.x;
  const int tc = t & 63;
  const int xo = (blockIdx.x & 3) * 4 + (t >> 6);   // x-octet 0..15, wave-uniform
  const int y  = blockIdx.x >> 2;                    // 0..126
  const int c  = blockIdx.y * 64 + tc;
  for (int idx = t; idx < 83 * 64; idx += 256)
    wl[idx] = wt[(size_t)(idx >> 6) * 512 + blockIdx.y * 64 + (idx & 63)];
  const float bsum = b7[c] + b5[c] + b3[c];
  __syncthreads();

  const int x0 = xo * 8;
  float acc[8];
#pragma unroll
  for (int i = 0; i < 8; ++i) acc[i] = 0.f;

  float vcur[7];
  {
    int xx = x0 - 3;
    bool okx = (xx >= 0 && xx < SG);
#pragma unroll
    for (int ky = 0; ky < 7; ++ky) {
      int yy = y + ky - 3;
      vcur[ky] = (okx && yy >= 0 && yy < SG)
                   ? h[(size_t)(1 + yy * SG + xx) * DD + c] : 0.f;
    }
  }

#pragma unroll 1
  for (int j = 0; j < 14; ++j) {
    float vnext[7];
    if (j < 13) {                                    // wave-uniform
      int xx = x0 + j - 2;
      bool okx = (xx >= 0 && xx < SG);
#pragma unroll
      for (int ky = 0; ky < 7; ++ky) {
        int yy = y + ky - 3;
        vnext[ky] = (okx && yy >= 0 && yy < SG)
                      ? h[(size_t)(1 + yy * SG + xx) * DD + c] : 0.f;
      }
    }
#pragma unroll
    for (int i = 0; i < 8; ++i) {
      const int k7 = j - i;                          // runtime, but wl is LDS
      if (k7 >= 0 && k7 <= 6) {
        const float* w7p = wl + k7 * 64 + tc;
#pragma unroll
        for (int ky = 0; ky < 7; ++ky)
          acc[i] = fmaf(vcur[ky], w7p[ky * 7 * 64], acc[i]);
      }
      const int k5 = j - i - 1;
      if (k5 >= 0 && k5 <= 4) {
        const float* w5p = wl + (49 + k5) * 64 + tc;
#pragma unroll
        for (int ky = 0; ky < 5; ++ky)
          acc[i] = fmaf(vcur[ky + 1], w5p[ky * 5 * 64], acc[i]);
      }
      const int k3 = j - i - 2;
      if (k3 >= 0 && k3 <= 2) {
        const float* w3p = wl + (74 + k3) * 64 + tc;
#pragma unroll
        for (int ky = 0; ky < 3; ++ky)
          acc[i] = fmaf(vcur[ky + 2], w3p[ky * 3 * 64], acc[i]);
      }
    }
    if (j < 13) {
#pragma unroll
      for (int ky = 0; ky < 7; ++ky) vcur[ky] = vnext[ky];
    }
  }
#pragma unroll
  for (int i = 0; i < 8; ++i) {
    int x = x0 + i;
    if (x < SG) {
      int p = y * SG + x;
      tmp[(size_t)p * DD + c] = h[(size_t)(1 + p) * DD + c] + bsum + acc[i];
    }
  }
}

// ---------------- final: LN(row0) -> fc2 -> softmax/argmax ----------------
__global__ __launch_bounds__(256) void final_kernel(
    const float* __restrict__ h, const float* __restrict__ g, const float* __restrict__ b,
    const float* __restrict__ w, const float* __restrict__ bias, float* __restrict__ out)
{
  __shared__ float red[256];
  int t = threadIdx.x;
  float v0 = h[t], v1 = h[t + 256];
  red[t] = v0 + v1;
  __syncthreads();
  for (int s = 128; s > 0; s >>= 1) { if (t < s) red[t] += red[t + s]; __syncthreads(); }
  float mu = red[0] * (1.f / 512.f);
  __syncthreads();
  float d0 = v0 - mu, d1 = v1 - mu;
  red[t] = d0 * d0 + d1 * d1;
  __syncthreads();
  for (int s = 128; s > 0; s >>= 1) { if (t < s) red[t] += red[t + s]; __syncthreads(); }
  float rs = rsqrtf(red[0] * (1.f / 512.f) + 1e-5f);
  __syncthreads();
  float x0 = d0 * rs * g[t] + b[t];
  float x1 = d1 * rs * g[t + 256] + b[t + 256];
  red[t] = x0 * w[t * 2] + x1 * w[(t + 256) * 2];
  __syncthreads();
  for (int s = 128; s > 0; s >>= 1) { if (t < s) red[t] += red[t + s]; __syncthreads(); }
  float l0 = red[0] + bias[0];
  __syncthreads();
  red[t] = x0 * w[t * 2 + 1] + x1 * w[(t + 256) * 2 + 1];
  __syncthreads();
  for (int s = 128; s > 0; s >>= 1) { if (t < s) red[t] += red[t + s]; __syncthreads(); }
  float l1 = red[0] + bias[1];
  if (t == 0) {
    out[0] = l0; out[1] = l1;
    float mx = fmaxf(l0, l1);
    float e0 = __expf(l0 - mx), e1 = __expf(l1 - mx);
    float inv = 1.f / (e0 + e1);
    out[2] = e0 * inv; out[3] = e1 * inv;
    out[4] = (l1 > l0) ? 1.f : 0.f;
  }
}

extern "C" void kernel_launch(void* const* d_in, const int* in_sizes, int n_in,
                              void* d_out, int out_size, void* d_ws, size_t ws_size,
                              hipStream_t stream)
{
  const float* data   = (const float*)d_in[0];
  const float* fc1_w  = (const float*)d_in[1];
  const float* fc1_b  = (const float*)d_in[2];
  const float* cls    = (const float*)d_in[3];
  const float* l1_g   = (const float*)d_in[4];
  const float* l1_b   = (const float*)d_in[5];
  const float* l1_qkv = (const float*)d_in[6];
  const float* l1_ow  = (const float*)d_in[7];
  const float* l1_ob  = (const float*)d_in[8];
  const float* l1_rw  = (const float*)d_in[9];
  const float* w7     = (const float*)d_in[10];
  const float* b7     = (const float*)d_in[11];
  const float* w5     = (const float*)d_in[12];
  const float* b5     = (const float*)d_in[13];
  const float* w3     = (const float*)d_in[14];
  const float* b3     = (const float*)d_in[15];
  const float* l2_g   = (const float*)d_in[16];
  const float* l2_b   = (const float*)d_in[17];
  const float* l2_qkv = (const float*)d_in[18];
  const float* l2_ow  = (const float*)d_in[19];
  const float* l2_ob  = (const float*)d_in[20];
  const float* l2_rw  = (const float*)d_in[21];
  const float* ng     = (const float*)d_in[22];
  const float* nb     = (const float*)d_in[23];
  const float* fc2_w  = (const float*)d_in[24];
  const float* fc2_b  = (const float*)d_in[25];
  float* out = (float*)d_out;

  float* ws   = (float*)d_ws;
  float* h    = ws;
  float* xn   = h    + (size_t)16384 * 512;
  float* qkv  = xn   + (size_t)16384 * 512;
  float* attn = qkv  + (size_t)16384 * 1536;
  float* ql   = attn + (size_t)16384 * 512;
  float* kl   = ql   + 256 * 512;
  float* a2b  = kl   + 256 * 512;
  float* z0   = a2b  + 8 * 256 * 256;
  float* z1   = z0   + 8 * 256 * 256;
  float* xzb  = z1   + 8 * 256 * 256;
  float* tb   = xzb  + 8 * 256 * 256;
  float* ub   = tb   + 8 * 256 * 256;
  float* a3v  = ub   + 8 * 256 * 256;
  float* w2   = a3v  + 8 * 256 * 64;
  float* pacc = w2   + 8 * 256 * 64;           // dead region: 4,194,304 floats (16 MiB)
  float* pms  = pacc + (size_t)8 * 32 * 256 * 64;
  float* red  = pms  + (size_t)8 * 32 * 256 * 2;
  float* wtb  = red  + 32;                       // ppeg weights fp32 (83*512)

  // bf16 transposed weights at start of pacc region: 2.62M ushorts = 1.31M floats
  ushort* fc1_wt  = (ushort*)pacc;
  ushort* qkv_wt0 = fc1_wt + 512 * 1024;
  ushort* qkv_wt1 = qkv_wt0 + 1536 * 512;
  ushort* out_wt0 = qkv_wt1 + 1536 * 512;
  ushort* out_wt1 = out_wt0 + 512 * 512;

  // bf16 activations: xn region as bf16 LN output; data bf16 in qkv region
  ushort* xnb    = (ushort*)xn;
  ushort* databf = (ushort*)qkv;

  // a3v MFMA partial buffers (alias xn scratch / pms)
  float* a3v_pacc = xn;
  float* a3v_den  = pms;

  // weight prep (bf16 transposes) + data cvt + fc1 + assemble
  wtrans_bf<<<dim3(16, 32), 256, 0, stream>>>(fc1_w, fc1_wt, 1024, 512);
  wtrans_bf<<<dim3(48, 16), 256, 0, stream>>>(l1_qkv, qkv_wt0, 512, 1536);
  wtrans_bf<<<dim3(48, 16), 256, 0, stream>>>(l2_qkv, qkv_wt1, 512, 1536);
  wtrans_bf<<<dim3(16, 16), 256, 0, stream>>>(l1_ow, out_wt0, 512, 512);
  wtrans_bf<<<dim3(16, 16), 256, 0, stream>>>(l2_ow, out_wt1, 512, 512);
  wtrans_kernel<<<2, 256, 0, stream>>>(w7, w5, w3, wtb);
  cvt_bf_kernel<<<8000, 256, 0, stream>>>(data, databf, 16000 * 1024);

  gemm_bb<<<dim3(4, 125), 256, 0, stream>>>(databf, 1024, fc1_wt, 1024, h + 512, 512,
                                            16000, 1024, 1, fc1_b);
  assemble_kernel<<<260, 256, 0, stream>>>(h, cls);

  for (int layer = 0; layer < 2; ++layer) {
    const float* gg = layer ? l2_g   : l1_g;
    const float* bb = layer ? l2_b   : l1_b;
    const ushort* qw = layer ? qkv_wt1 : qkv_wt0;
    const ushort* ow = layer ? out_wt1 : out_wt0;
    const float* ob = layer ? l2_ob  : l1_ob;
    const float* rw = layer ? l2_rw  : l1_rw;

    ln_pad_kernel<<<16384, 256, 0, stream>>>(h, xnb, gg, bb);
    gemm_bb<<<dim3(12, 128), 256, 0, stream>>>(xnb, 512, qw, 512, qkv, 1536,
                                               16384, 512, 2, nullptr);
    landmark_kernel<<<dim3(256, 4), 256, 0, stream>>>(qkv, ql, kl);
    a2_kernel<<<dim3(8, 256), 256, 0, stream>>>(ql, kl, a2b);
    pinv_red1<<<8, 256, 0, stream>>>(a2b, red);
    pinv_init<<<dim3(8, 256), 256, 0, stream>>>(a2b, red, z0);   // red2 folded in
    float* zc = z0; float* zn = z1;
    for (int it = 0; it < 6; ++it) {
      nmm_kernel<<<dim3(4, 4, 8), 256, 0, stream>>>(zc, a2b, xzb, 0);   // Z = z@a2
      nmm_s2<<<dim3(4, 4, 16), 256, 0, stream>>>(xzb, zc, tb, ub);      // W=Z@z ; G=7Z-Z@Z
      nmm_s3<<<dim3(4, 4, 8), 256, 0, stream>>>(ub, tb, zc, zn);        // zn=.25(13z-15W+G@W)
      float* sw = zc; zc = zn; zn = sw;
    }
    a3v_mfma<<<dim3(8, CHK), 256, 0, stream>>>(qkv, ql, a3v_pacc, a3v_den);
    a3v_merge_kernel<<<dim3(8, 256), 64, 0, stream>>>(a3v_pacc, a3v_den, a3v);
    mmb_kernel<<<dim3(1, 4, 8), 256, 0, stream>>>(zc, a3v, w2, 64, 1.f);
    a1_mfma<<<dim3(8, 64), 256, 0, stream>>>(qkv, kl, w2, attn);
    resconv_kernel<<<dim3(2048, 2), 256, 0, stream>>>(qkv, rw, attn);
    gemm_bt<<<dim3(4, 127), 256, 0, stream>>>(attn + (size_t)254 * 512, 512, ow, 512,
                                              h, 512, 16130, 512, 3, ob);
    if (layer == 0) {
      // ppeg -> qkv scratch (dead until layer-1 recomputes it), memcpy back
      ppeg_kernel<<<dim3(127 * 4, 8), 256, 0, stream>>>(h, qkv, wtb, b7, b5, b3);
      hipMemcpyAsync(h + 512, qkv, (size_t)16129 * 512 * 4,
                     hipMemcpyDeviceToDevice, stream);
    }
  }
  final_kernel<<<1, 256, 0, stream>>>(h, ng, nb, fc2_w, fc2_b, out);
}

// Round 20
// 946.749 us; speedup vs baseline: 2.7443x; 1.1589x over previous
//
#include <hip/hip_runtime.h>
#include <math.h>

#define NPAD   16384
#define PADR   254
#define NTOK   16130
#define NPIX   16129
#define SG     127
#define DD     512
#define NH     8
#define CHK    64          // key-chunks per head for a3v

typedef __attribute__((ext_vector_type(8))) short bf16x8;
typedef __attribute__((ext_vector_type(4))) float f32x4;

__device__ __forceinline__ ushort f2bf(float f) {
  uint u = __float_as_uint(f);
  u = (u + 0x7fffu + ((u >> 16) & 1u)) >> 16;
  return (ushort)u;
}

// ---------------- elementwise fp32 -> bf16 (vectorized x8) ----------------
__global__ __launch_bounds__(256) void cvt_bf_kernel(
    const float* __restrict__ src, ushort* __restrict__ dst, int n)
{
  int i = (blockIdx.x * 256 + threadIdx.x) * 8;
  if (i >= n) return;
  float4 a = *(const float4*)(src + i);
  float4 b = *(const float4*)(src + i + 4);
  bf16x8 v;
  v[0] = f2bf(a.x); v[1] = f2bf(a.y); v[2] = f2bf(a.z); v[3] = f2bf(a.w);
  v[4] = f2bf(b.x); v[5] = f2bf(b.y); v[6] = f2bf(b.z); v[7] = f2bf(b.w);
  *(bf16x8*)(dst + i) = v;
}

// ---------------- weight transpose+cvt: src fp32 [K][N] -> dst bf16 [N][K] ----------------
__global__ __launch_bounds__(256) void wtrans_bf(
    const float* __restrict__ src, ushort* __restrict__ dst, int K, int N)
{
  __shared__ float tile[32][33];
  int tx = threadIdx.x & 31, ty = threadIdx.x >> 5;   // 32 x 8
#pragma unroll
  for (int i = 0; i < 4; ++i) {
    int k = blockIdx.y * 32 + ty + i * 8, n = blockIdx.x * 32 + tx;
    tile[ty + i * 8][tx] = src[(size_t)k * N + n];
  }
  __syncthreads();
#pragma unroll
  for (int i = 0; i < 4; ++i) {
    int n = blockIdx.x * 32 + ty + i * 8, k = blockIdx.y * 32 + tx;
    dst[(size_t)n * K + k] = f2bf(tile[tx][ty + i * 8]);
  }
}

// ---------------- bf16 MFMA GEMM (bf16 A): C fp32 = A_bf16 @ Bt_bf16^T ----------------
__global__ __launch_bounds__(256) void gemm_bb(
    const ushort* __restrict__ A, int lda,
    const ushort* __restrict__ Bt, int ldb,
    float* __restrict__ C, int ldc,
    int M, int K, int mode, const float* __restrict__ bias)
{
  const int t = threadIdx.x;
  const int w = t >> 6, l = t & 63, lr = l & 15, lg = l >> 4;
  const int wr = w >> 1, wc = w & 1;
  const int m0 = blockIdx.y * 128, n0 = blockIdx.x * 128;
  __shared__ __align__(16) ushort As[128 * 64];
  __shared__ __align__(16) ushort Bs[128 * 64];
  f32x4 acc[4][4];
#pragma unroll
  for (int i = 0; i < 4; ++i)
#pragma unroll
    for (int j = 0; j < 4; ++j) acc[i][j] = (f32x4){0.f, 0.f, 0.f, 0.f};

  for (int k0 = 0; k0 < K; k0 += 64) {
    __syncthreads();
#pragma unroll
    for (int i = 0; i < 4; ++i) {
      int id = t + i * 256;
      int r = id >> 3, blk = id & 7;
      int gr = m0 + r;
      bf16x8 v = (bf16x8){0, 0, 0, 0, 0, 0, 0, 0};
      if (gr < M) v = *(const bf16x8*)(A + (size_t)gr * lda + k0 + blk * 8);
      *(bf16x8*)(As + r * 64 + ((blk ^ (r & 7)) << 3)) = v;
    }
#pragma unroll
    for (int i = 0; i < 4; ++i) {
      int id = t + i * 256;
      int r = id >> 3, blk = id & 7;
      bf16x8 v = *(const bf16x8*)(Bt + (size_t)(n0 + r) * ldb + k0 + blk * 8);
      *(bf16x8*)(Bs + r * 64 + ((blk ^ (r & 7)) << 3)) = v;
    }
    __syncthreads();
    bf16x8 af[4][2], bfr[4][2];
#pragma unroll
    for (int rt = 0; rt < 4; ++rt) {
      int row = wr * 64 + rt * 16 + lr;
#pragma unroll
      for (int kc = 0; kc < 2; ++kc)
        af[rt][kc] = *(const bf16x8*)(As + row * 64 + (((kc * 4 + lg) ^ (row & 7)) << 3));
    }
#pragma unroll
    for (int nt = 0; nt < 4; ++nt) {
      int row = wc * 64 + nt * 16 + lr;
#pragma unroll
      for (int kc = 0; kc < 2; ++kc)
        bfr[nt][kc] = *(const bf16x8*)(Bs + row * 64 + (((kc * 4 + lg) ^ (row & 7)) << 3));
    }
#pragma unroll
    for (int rt = 0; rt < 4; ++rt)
#pragma unroll
      for (int nt = 0; nt < 4; ++nt) {
        acc[rt][nt] = __builtin_amdgcn_mfma_f32_16x16x32_bf16(af[rt][0], bfr[nt][0], acc[rt][nt], 0, 0, 0);
        acc[rt][nt] = __builtin_amdgcn_mfma_f32_16x16x32_bf16(af[rt][1], bfr[nt][1], acc[rt][nt], 0, 0, 0);
      }
  }
#pragma unroll
  for (int rt = 0; rt < 4; ++rt) {
#pragma unroll
    for (int r = 0; r < 4; ++r) {
      int gi = m0 + wr * 64 + rt * 16 + lg * 4 + r;
      if (gi >= M) continue;
#pragma unroll
      for (int nt = 0; nt < 4; ++nt) {
        int gj = n0 + wc * 64 + nt * 16 + lr;
        float d = acc[rt][nt][r];
        if (mode == 1) d = fmaxf(d + bias[gj], 0.f);
        else if (mode == 2) { if (gj < 512) d *= 0.125f; }
        else if (mode == 3) d += C[(size_t)gi * ldc + gj] + bias[gj];
        C[(size_t)gi * ldc + gj] = d;
      }
    }
  }
}

// ---------------- bf16 MFMA GEMM (fp32 A): C fp32 = A_f32 @ Bt_bf16^T ----------------
__global__ __launch_bounds__(256) void gemm_bt(
    const float* __restrict__ A, int lda,
    const ushort* __restrict__ Bt, int ldb,
    float* __restrict__ C, int ldc,
    int M, int K, int mode, const float* __restrict__ bias)
{
  const int t = threadIdx.x;
  const int w = t >> 6, l = t & 63, lr = l & 15, lg = l >> 4;
  const int wr = w >> 1, wc = w & 1;
  const int m0 = blockIdx.y * 128, n0 = blockIdx.x * 128;
  __shared__ __align__(16) ushort As[128 * 64];
  __shared__ __align__(16) ushort Bs[128 * 64];
  f32x4 acc[4][4];
#pragma unroll
  for (int i = 0; i < 4; ++i)
#pragma unroll
    for (int j = 0; j < 4; ++j) acc[i][j] = (f32x4){0.f, 0.f, 0.f, 0.f};

  for (int k0 = 0; k0 < K; k0 += 64) {
    __syncthreads();
#pragma unroll
    for (int i = 0; i < 2; ++i) {
      int id = t + i * 256;
      int r = id >> 2, db = id & 3;
      const float* src = A + (size_t)(m0 + r) * lda + k0 + db * 16;
      float4 g0 = *(const float4*)(src + 0);
      float4 g1 = *(const float4*)(src + 4);
      float4 g2 = *(const float4*)(src + 8);
      float4 g3 = *(const float4*)(src + 12);
      bf16x8 e0, e1;
      e0[0] = f2bf(g0.x); e0[1] = f2bf(g0.y); e0[2] = f2bf(g0.z); e0[3] = f2bf(g0.w);
      e0[4] = f2bf(g1.x); e0[5] = f2bf(g1.y); e0[6] = f2bf(g1.z); e0[7] = f2bf(g1.w);
      e1[0] = f2bf(g2.x); e1[1] = f2bf(g2.y); e1[2] = f2bf(g2.z); e1[3] = f2bf(g2.w);
      e1[4] = f2bf(g3.x); e1[5] = f2bf(g3.y); e1[6] = f2bf(g3.z); e1[7] = f2bf(g3.w);
      ushort* dst = As + r * 64;
      *(bf16x8*)(dst + (((db * 2 + 0) ^ (r & 7)) << 3)) = e0;
      *(bf16x8*)(dst + (((db * 2 + 1) ^ (r & 7)) << 3)) = e1;
    }
#pragma unroll
    for (int i = 0; i < 4; ++i) {
      int id = t + i * 256;
      int r = id >> 3, blk = id & 7;
      bf16x8 v = *(const bf16x8*)(Bt + (size_t)(n0 + r) * ldb + k0 + blk * 8);
      *(bf16x8*)(Bs + r * 64 + ((blk ^ (r & 7)) << 3)) = v;
    }
    __syncthreads();
    bf16x8 af[4][2], bfr[4][2];
#pragma unroll
    for (int rt = 0; rt < 4; ++rt) {
      int row = wr * 64 + rt * 16 + lr;
#pragma unroll
      for (int kc = 0; kc < 2; ++kc)
        af[rt][kc] = *(const bf16x8*)(As + row * 64 + (((kc * 4 + lg) ^ (row & 7)) << 3));
    }
#pragma unroll
    for (int nt = 0; nt < 4; ++nt) {
      int row = wc * 64 + nt * 16 + lr;
#pragma unroll
      for (int kc = 0; kc < 2; ++kc)
        bfr[nt][kc] = *(const bf16x8*)(Bs + row * 64 + (((kc * 4 + lg) ^ (row & 7)) << 3));
    }
#pragma unroll
    for (int rt = 0; rt < 4; ++rt)
#pragma unroll
      for (int nt = 0; nt < 4; ++nt) {
        acc[rt][nt] = __builtin_amdgcn_mfma_f32_16x16x32_bf16(af[rt][0], bfr[nt][0], acc[rt][nt], 0, 0, 0);
        acc[rt][nt] = __builtin_amdgcn_mfma_f32_16x16x32_bf16(af[rt][1], bfr[nt][1], acc[rt][nt], 0, 0, 0);
      }
  }
#pragma unroll
  for (int rt = 0; rt < 4; ++rt) {
#pragma unroll
    for (int r = 0; r < 4; ++r) {
      int gi = m0 + wr * 64 + rt * 16 + lg * 4 + r;
      if (gi >= M) continue;
#pragma unroll
      for (int nt = 0; nt < 4; ++nt) {
        int gj = n0 + wc * 64 + nt * 16 + lr;
        float d = acc[rt][nt][r];
        if (mode == 1) d = fmaxf(d + bias[gj], 0.f);
        else if (mode == 2) { if (gj < 512) d *= 0.125f; }
        else if (mode == 3) d += C[(size_t)gi * ldc + gj] + bias[gj];
        C[(size_t)gi * ldc + gj] = d;
      }
    }
  }
}

// ==== pinv launch-train: 2 dependent stages/iter via Y-recurrence ====
// Y = a2@z iterated alongside z:  U = z@Y, Y2 = Y@Y  (dual launch A);
// z' = 0.25(13z - 15U + (7z-U)@Y2), Y' = 0.25(13Y - 15Y2 + (7Y-Y2)@Y2)
// (dual launch B; Y' = a2@z' exactly in exact arithmetic -> next iter needs no
// fresh a2@z matmul). Newton map has zero derivative at its fixed point, so
// bf16 drift in the Y-recurrence self-damps.
// [rounds 15-17: cross-block/single-CU fusions 3-8x slower; launch train best.]

// seed: grid (4,4,8): Y0 = inv*(a2@a2^T) tile + z0 = inv*a2^T tile (init folded)
__global__ __launch_bounds__(256) void pinv_seed(
    const float* __restrict__ a2, const float* __restrict__ red,
    float* __restrict__ z0, float* __restrict__ Y0)
{
  const int h_ = blockIdx.z;
  const int m0 = blockIdx.y * 64, n0 = blockIdx.x * 64;
  const float* Ah = a2 + (size_t)h_ * 65536;
  float* zh = z0 + (size_t)h_ * 65536;
  float* Yh = Y0 + (size_t)h_ * 65536;
  float mr = 0.f, mc = 0.f;
#pragma unroll
  for (int k = 0; k < 8; ++k) { mr = fmaxf(mr, red[k * 2]); mc = fmaxf(mc, red[k * 2 + 1]); }
  const float inv = 1.f / (mr * mc);
  const int t = threadIdx.x, w = t >> 6, l = t & 63, lr = l & 15, lg = l >> 4;
  __shared__ __align__(16) ushort Xs[64 * 64];
  __shared__ __align__(16) ushort Ys[64 * 64];
  f32x4 acc[4];
#pragma unroll
  for (int nt = 0; nt < 4; ++nt) acc[nt] = (f32x4){0.f, 0.f, 0.f, 0.f};

  for (int k0 = 0; k0 < 256; k0 += 64) {
    __syncthreads();
    {
      int r = t >> 2, db = t & 3;
      const float* src = Ah + (size_t)(m0 + r) * 256 + k0 + db * 16;
      float4 g0 = *(const float4*)(src + 0);
      float4 g1 = *(const float4*)(src + 4);
      float4 g2 = *(const float4*)(src + 8);
      float4 g3 = *(const float4*)(src + 12);
      bf16x8 e0, e1;
      e0[0] = f2bf(g0.x); e0[1] = f2bf(g0.y); e0[2] = f2bf(g0.z); e0[3] = f2bf(g0.w);
      e0[4] = f2bf(g1.x); e0[5] = f2bf(g1.y); e0[6] = f2bf(g1.z); e0[7] = f2bf(g1.w);
      e1[0] = f2bf(g2.x); e1[1] = f2bf(g2.y); e1[2] = f2bf(g2.z); e1[3] = f2bf(g2.w);
      e1[4] = f2bf(g3.x); e1[5] = f2bf(g3.y); e1[6] = f2bf(g3.z); e1[7] = f2bf(g3.w);
      ushort* dst = Xs + r * 64;
      *(bf16x8*)(dst + (((db * 2 + 0) ^ (r & 7)) << 3)) = e0;
      *(bf16x8*)(dst + (((db * 2 + 1) ^ (r & 7)) << 3)) = e1;
    }
    // B = a2^T: Ys[n][k] = a2[n][k]  (A-style staging of rows n0+r into Ys)
    {
      int r = t >> 2, db = t & 3;
      const float* src = Ah + (size_t)(n0 + r) * 256 + k0 + db * 16;
      float4 g0 = *(const float4*)(src + 0);
      float4 g1 = *(const float4*)(src + 4);
      float4 g2 = *(const float4*)(src + 8);
      float4 g3 = *(const float4*)(src + 12);
      bf16x8 e0, e1;
      e0[0] = f2bf(g0.x); e0[1] = f2bf(g0.y); e0[2] = f2bf(g0.z); e0[3] = f2bf(g0.w);
      e0[4] = f2bf(g1.x); e0[5] = f2bf(g1.y); e0[6] = f2bf(g1.z); e0[7] = f2bf(g1.w);
      e1[0] = f2bf(g2.x); e1[1] = f2bf(g2.y); e1[2] = f2bf(g2.z); e1[3] = f2bf(g2.w);
      e1[4] = f2bf(g3.x); e1[5] = f2bf(g3.y); e1[6] = f2bf(g3.z); e1[7] = f2bf(g3.w);
      ushort* dst = Ys + r * 64;
      *(bf16x8*)(dst + (((db * 2 + 0) ^ (r & 7)) << 3)) = e0;
      *(bf16x8*)(dst + (((db * 2 + 1) ^ (r & 7)) << 3)) = e1;
    }
    __syncthreads();
    int arow = w * 16 + lr;
    bf16x8 af0 = *(const bf16x8*)(Xs + arow * 64 + (((0 + lg) ^ (arow & 7)) << 3));
    bf16x8 af1 = *(const bf16x8*)(Xs + arow * 64 + (((4 + lg) ^ (arow & 7)) << 3));
#pragma unroll
    for (int nt = 0; nt < 4; ++nt) {
      int brow = nt * 16 + lr;
      bf16x8 bf0 = *(const bf16x8*)(Ys + brow * 64 + (((0 + lg) ^ (brow & 7)) << 3));
      bf16x8 bf1 = *(const bf16x8*)(Ys + brow * 64 + (((4 + lg) ^ (brow & 7)) << 3));
      acc[nt] = __builtin_amdgcn_mfma_f32_16x16x32_bf16(af0, bf0, acc[nt], 0, 0, 0);
      acc[nt] = __builtin_amdgcn_mfma_f32_16x16x32_bf16(af1, bf1, acc[nt], 0, 0, 0);
    }
  }
#pragma unroll
  for (int nt = 0; nt < 4; ++nt) {
#pragma unroll
    for (int r = 0; r < 4; ++r) {
      int gi = m0 + w * 16 + lg * 4 + r;
      int gj = n0 + nt * 16 + lr;
      Yh[(size_t)gi * 256 + gj] = inv * acc[nt][r];
    }
  }
  // z0 tile: z0[m0+i][n0+j] = inv * a2[n0+j][m0+i]
#pragma unroll
  for (int e = 0; e < 16; ++e) {
    int id = e * 256 + t;
    int i = id >> 6, j = id & 63;
    zh[(size_t)(m0 + i) * 256 + n0 + j] = inv * Ah[(size_t)(n0 + j) * 256 + m0 + i];
  }
}

// launch A (dual): job0: U = z@Y ; job1: Y2 = Y@Y.  grid (4,4,16)
__global__ __launch_bounds__(256) void nmm_A(
    const float* __restrict__ z, const float* __restrict__ Y,
    float* __restrict__ U, float* __restrict__ Y2)
{
  const int h_ = blockIdx.z & 7;
  const int job = blockIdx.z >> 3;
  const int m0 = blockIdx.y * 64, n0 = blockIdx.x * 64;
  const float* Ah = (job == 0 ? z : Y) + (size_t)h_ * 65536;
  const float* Bh = Y + (size_t)h_ * 65536;
  float* Ch = (job == 0 ? U : Y2) + (size_t)h_ * 65536;
  const int t = threadIdx.x, w = t >> 6, l = t & 63, lr = l & 15, lg = l >> 4;
  __shared__ __align__(16) ushort Xs[64 * 64];
  __shared__ __align__(16) ushort Ys[64 * 64];
  f32x4 acc[4];
#pragma unroll
  for (int nt = 0; nt < 4; ++nt) acc[nt] = (f32x4){0.f, 0.f, 0.f, 0.f};

  for (int k0 = 0; k0 < 256; k0 += 64) {
    __syncthreads();
    {
      int r = t >> 2, db = t & 3;
      const float* src = Ah + (size_t)(m0 + r) * 256 + k0 + db * 16;
      float4 g0 = *(const float4*)(src + 0);
      float4 g1 = *(const float4*)(src + 4);
      float4 g2 = *(const float4*)(src + 8);
      float4 g3 = *(const float4*)(src + 12);
      bf16x8 e0, e1;
      e0[0] = f2bf(g0.x); e0[1] = f2bf(g0.y); e0[2] = f2bf(g0.z); e0[3] = f2bf(g0.w);
      e0[4] = f2bf(g1.x); e0[5] = f2bf(g1.y); e0[6] = f2bf(g1.z); e0[7] = f2bf(g1.w);
      e1[0] = f2bf(g2.x); e1[1] = f2bf(g2.y); e1[2] = f2bf(g2.z); e1[3] = f2bf(g2.w);
      e1[4] = f2bf(g3.x); e1[5] = f2bf(g3.y); e1[6] = f2bf(g3.z); e1[7] = f2bf(g3.w);
      ushort* dst = Xs + r * 64;
      *(bf16x8*)(dst + (((db * 2 + 0) ^ (r & 7)) << 3)) = e0;
      *(bf16x8*)(dst + (((db * 2 + 1) ^ (r & 7)) << 3)) = e1;
    }
#pragma unroll
    for (int i = 0; i < 4; ++i) {
      int id = t + i * 256;
      int k = id >> 4, q = id & 15;
      float4 v = *(const float4*)(Bh + (size_t)(k0 + k) * 256 + n0 + q * 4);
      int kb = k >> 3, ke = k & 7;
      Ys[(q * 4 + 0) * 64 + ((kb ^ ((q * 4 + 0) & 7)) << 3) + ke] = f2bf(v.x);
      Ys[(q * 4 + 1) * 64 + ((kb ^ ((q * 4 + 1) & 7)) << 3) + ke] = f2bf(v.y);
      Ys[(q * 4 + 2) * 64 + ((kb ^ ((q * 4 + 2) & 7)) << 3) + ke] = f2bf(v.z);
      Ys[(q * 4 + 3) * 64 + ((kb ^ ((q * 4 + 3) & 7)) << 3) + ke] = f2bf(v.w);
    }
    __syncthreads();
    int arow = w * 16 + lr;
    bf16x8 af0 = *(const bf16x8*)(Xs + arow * 64 + (((0 + lg) ^ (arow & 7)) << 3));
    bf16x8 af1 = *(const bf16x8*)(Xs + arow * 64 + (((4 + lg) ^ (arow & 7)) << 3));
#pragma unroll
    for (int nt = 0; nt < 4; ++nt) {
      int brow = nt * 16 + lr;
      bf16x8 bf0 = *(const bf16x8*)(Ys + brow * 64 + (((0 + lg) ^ (brow & 7)) << 3));
      bf16x8 bf1 = *(const bf16x8*)(Ys + brow * 64 + (((4 + lg) ^ (brow & 7)) << 3));
      acc[nt] = __builtin_amdgcn_mfma_f32_16x16x32_bf16(af0, bf0, acc[nt], 0, 0, 0);
      acc[nt] = __builtin_amdgcn_mfma_f32_16x16x32_bf16(af1, bf1, acc[nt], 0, 0, 0);
    }
  }
#pragma unroll
  for (int nt = 0; nt < 4; ++nt) {
#pragma unroll
    for (int r = 0; r < 4; ++r) {
      int gi = m0 + w * 16 + lg * 4 + r;
      int gj = n0 + nt * 16 + lr;
      Ch[(size_t)gi * 256 + gj] = acc[nt][r];
    }
  }
}

// launch B (dual): job0: zn = 0.25(13z - 15U + (7z-U)@Y2)
//                  job1: yn = 0.25(13Y - 15Y2 + (7Y-Y2)@Y2).  grid (4,4,16)
__global__ __launch_bounds__(256) void nmm_B(
    const float* __restrict__ z, const float* __restrict__ Y,
    const float* __restrict__ U, const float* __restrict__ Y2,
    float* __restrict__ zn, float* __restrict__ yn)
{
  const int h_ = blockIdx.z & 7;
  const int job = blockIdx.z >> 3;
  const int m0 = blockIdx.y * 64, n0 = blockIdx.x * 64;
  const float* X1 = (job == 0 ? z : Y) + (size_t)h_ * 65536;
  const float* X2 = (job == 0 ? U : Y2) + (size_t)h_ * 65536;
  const float* Bh = Y2 + (size_t)h_ * 65536;
  float* Ch = (job == 0 ? zn : yn) + (size_t)h_ * 65536;
  const int t = threadIdx.x, w = t >> 6, l = t & 63, lr = l & 15, lg = l >> 4;
  __shared__ __align__(16) ushort Xs[64 * 64];
  __shared__ __align__(16) ushort Ys[64 * 64];
  f32x4 acc[4];
#pragma unroll
  for (int nt = 0; nt < 4; ++nt) acc[nt] = (f32x4){0.f, 0.f, 0.f, 0.f};

  for (int k0 = 0; k0 < 256; k0 += 64) {
    __syncthreads();
    // A-operand = 7*X1 - X2, computed during staging
    {
      int r = t >> 2, db = t & 3;
      const float* s1 = X1 + (size_t)(m0 + r) * 256 + k0 + db * 16;
      const float* s2 = X2 + (size_t)(m0 + r) * 256 + k0 + db * 16;
      float4 a0 = *(const float4*)(s1 + 0),  b0 = *(const float4*)(s2 + 0);
      float4 a1 = *(const float4*)(s1 + 4),  b1 = *(const float4*)(s2 + 4);
      float4 a2v = *(const float4*)(s1 + 8), b2 = *(const float4*)(s2 + 8);
      float4 a3 = *(const float4*)(s1 + 12), b3 = *(const float4*)(s2 + 12);
      bf16x8 e0, e1;
      e0[0] = f2bf(7.f * a0.x - b0.x); e0[1] = f2bf(7.f * a0.y - b0.y);
      e0[2] = f2bf(7.f * a0.z - b0.z); e0[3] = f2bf(7.f * a0.w - b0.w);
      e0[4] = f2bf(7.f * a1.x - b1.x); e0[5] = f2bf(7.f * a1.y - b1.y);
      e0[6] = f2bf(7.f * a1.z - b1.z); e0[7] = f2bf(7.f * a1.w - b1.w);
      e1[0] = f2bf(7.f * a2v.x - b2.x); e1[1] = f2bf(7.f * a2v.y - b2.y);
      e1[2] = f2bf(7.f * a2v.z - b2.z); e1[3] = f2bf(7.f * a2v.w - b2.w);
      e1[4] = f2bf(7.f * a3.x - b3.x); e1[5] = f2bf(7.f * a3.y - b3.y);
      e1[6] = f2bf(7.f * a3.z - b3.z); e1[7] = f2bf(7.f * a3.w - b3.w);
      ushort* dst = Xs + r * 64;
      *(bf16x8*)(dst + (((db * 2 + 0) ^ (r & 7)) << 3)) = e0;
      *(bf16x8*)(dst + (((db * 2 + 1) ^ (r & 7)) << 3)) = e1;
    }
#pragma unroll
    for (int i = 0; i < 4; ++i) {
      int id = t + i * 256;
      int k = id >> 4, q = id & 15;
      float4 v = *(const float4*)(Bh + (size_t)(k0 + k) * 256 + n0 + q * 4);
      int kb = k >> 3, ke = k & 7;
      Ys[(q * 4 + 0) * 64 + ((kb ^ ((q * 4 + 0) & 7)) << 3) + ke] = f2bf(v.x);
      Ys[(q * 4 + 1) * 64 + ((kb ^ ((q * 4 + 1) & 7)) << 3) + ke] = f2bf(v.y);
      Ys[(q * 4 + 2) * 64 + ((kb ^ ((q * 4 + 2) & 7)) << 3) + ke] = f2bf(v.z);
      Ys[(q * 4 + 3) * 64 + ((kb ^ ((q * 4 + 3) & 7)) << 3) + ke] = f2bf(v.w);
    }
    __syncthreads();
    int arow = w * 16 + lr;
    bf16x8 af0 = *(const bf16x8*)(Xs + arow * 64 + (((0 + lg) ^ (arow & 7)) << 3));
    bf16x8 af1 = *(const bf16x8*)(Xs + arow * 64 + (((4 + lg) ^ (arow & 7)) << 3));
#pragma unroll
    for (int nt = 0; nt < 4; ++nt) {
      int brow = nt * 16 + lr;
      bf16x8 bf0 = *(const bf16x8*)(Ys + brow * 64 + (((0 + lg) ^ (brow & 7)) << 3));
      bf16x8 bf1 = *(const bf16x8*)(Ys + brow * 64 + (((4 + lg) ^ (brow & 7)) << 3));
      acc[nt] = __builtin_amdgcn_mfma_f32_16x16x32_bf16(af0, bf0, acc[nt], 0, 0, 0);
      acc[nt] = __builtin_amdgcn_mfma_f32_16x16x32_bf16(af1, bf1, acc[nt], 0, 0, 0);
    }
  }
#pragma unroll
  for (int nt = 0; nt < 4; ++nt) {
#pragma unroll
    for (int r = 0; r < 4; ++r) {
      int gi = m0 + w * 16 + lg * 4 + r;
      int gj = n0 + nt * 16 + lr;
      size_t o = (size_t)gi * 256 + gj;
      Ch[o] = 0.25f * (13.f * X1[o] - 15.f * X2[o] + acc[nt][r]);
    }
  }
}

// ---------------- assemble: h[0]=cls, h[16001+i]=h[1+i] (i<129) ----------------
__global__ __launch_bounds__(256) void assemble_kernel(float* __restrict__ h,
                                                       const float* __restrict__ cls)
{
  int idx = blockIdx.x * 256 + threadIdx.x;
  if (idx < 512) { h[idx] = cls[idx]; return; }
  idx -= 512;
  int i = idx >> 9, c = idx & 511;
  h[(size_t)(16001 + i) * DD + c] = h[(size_t)(1 + i) * DD + c];
}

// ---------------- LayerNorm rows of h -> xn (bf16 out; front-padded) ----------------
__global__ __launch_bounds__(256) void ln_pad_kernel(
    const float* __restrict__ h, ushort* __restrict__ xn,
    const float* __restrict__ g, const float* __restrict__ b)
{
  int row = blockIdx.x;
  int t = threadIdx.x;
  if (row < PADR) {
    xn[(size_t)row * DD + t] = 0;
    xn[(size_t)row * DD + t + 256] = 0;
    return;
  }
  const float* x = h + (size_t)(row - PADR) * DD;
  __shared__ float red[256];
  float v0 = x[t], v1 = x[t + 256];
  red[t] = v0 + v1;
  __syncthreads();
  for (int s = 128; s > 0; s >>= 1) { if (t < s) red[t] += red[t + s]; __syncthreads(); }
  float mu = red[0] * (1.f / 512.f);
  __syncthreads();
  float d0 = v0 - mu, d1 = v1 - mu;
  red[t] = d0 * d0 + d1 * d1;
  __syncthreads();
  for (int s = 128; s > 0; s >>= 1) { if (t < s) red[t] += red[t + s]; __syncthreads(); }
  float rs = rsqrtf(red[0] * (1.f / 512.f) + 1e-5f);
  ushort* o = xn + (size_t)row * DD;
  o[t]       = f2bf(d0 * rs * g[t] + b[t]);
  o[t + 256] = f2bf(d1 * rs * g[t + 256] + b[t + 256]);
}

// ---------------- landmarks ----------------
__global__ __launch_bounds__(256) void landmark_kernel(
    const float* __restrict__ qkv, float* __restrict__ ql, float* __restrict__ kl)
{
  int i = blockIdx.x;
  int c = blockIdx.y * 256 + threadIdx.x;
  const float* p = qkv + (size_t)(i * 64) * 1536 + c;
  float s = 0.f;
  for (int j = 0; j < 64; ++j) s += p[(size_t)j * 1536];
  s *= (1.f / 64.f);
  if (c < 512) ql[(size_t)i * 512 + c] = s;
  else         kl[(size_t)i * 512 + (c - 512)] = s;
}

// ---------------- a2 = softmax(ql . kl^T) per head ----------------
__global__ __launch_bounds__(256) void a2_kernel(
    const float* __restrict__ ql, const float* __restrict__ kl, float* __restrict__ a2)
{
  int h_ = blockIdx.x, i = blockIdx.y;
  int t = threadIdx.x;
  __shared__ float q[64];
  __shared__ float red[256];
  if (t < 64) q[t] = ql[(size_t)i * 512 + h_ * 64 + t];
  __syncthreads();
  const float* kr = kl + (size_t)t * 512 + h_ * 64;
  float s = 0.f;
#pragma unroll
  for (int d = 0; d < 64; ++d) s = fmaf(q[d], kr[d], s);
  red[t] = s;
  __syncthreads();
  for (int st = 128; st > 0; st >>= 1) { if (t < st) red[t] = fmaxf(red[t], red[t + st]); __syncthreads(); }
  float mx = red[0];
  __syncthreads();
  float e = __expf(s - mx);
  red[t] = e;
  __syncthreads();
  for (int st = 128; st > 0; st >>= 1) { if (t < st) red[t] += red[t + st]; __syncthreads(); }
  a2[((size_t)h_ * 256 + i) * 256 + t] = e / red[0];
}

// ---------------- pinv init reductions ----------------
__global__ __launch_bounds__(256) void pinv_red1(const float* __restrict__ a2, float* __restrict__ red)
{
  int h_ = blockIdx.x, t = threadIdx.x;
  const float* X = a2 + (size_t)h_ * 65536;
  float rs = 0.f, cs = 0.f;
  for (int j = 0; j < 256; ++j) rs += fabsf(X[(size_t)t * 256 + j]);
  for (int i = 0; i < 256; ++i) cs += fabsf(X[(size_t)i * 256 + t]);
  __shared__ float r1[256], r2[256];
  r1[t] = rs; r2[t] = cs;
  __syncthreads();
  for (int s = 128; s > 0; s >>= 1) {
    if (t < s) { r1[t] = fmaxf(r1[t], r1[t + s]); r2[t] = fmaxf(r2[t], r2[t + s]); }
    __syncthreads();
  }
  if (t == 0) { red[h_ * 2] = r1[0]; red[h_ * 2 + 1] = r2[0]; }
}

// ---------------- batched matmul per head: C = alpha*(A @ B), A 256x256, B 256xN ----------------
__global__ __launch_bounds__(256) void mmb_kernel(
    const float* __restrict__ A, const float* __restrict__ B, float* __restrict__ C,
    int N, float alpha)
{
  int h_ = blockIdx.z;
  const float* Ah = A + (size_t)h_ * 256 * 256;
  const float* Bh = B + (size_t)h_ * 256 * N;
  float* Ch = C + (size_t)h_ * 256 * N;
  int m0 = blockIdx.y * 64, n0 = blockIdx.x * 64;
  __shared__ float As[16][68];
  __shared__ float Bs[16][68];
  int tid = threadIdx.x, tx = tid & 15, ty = tid >> 4;
  float acc[4][4];
#pragma unroll
  for (int i = 0; i < 4; ++i)
#pragma unroll
    for (int j = 0; j < 4; ++j) acc[i][j] = 0.f;
  for (int k0 = 0; k0 < 256; k0 += 16) {
    {
      int row = tid >> 2, k4 = (tid & 3) << 2;
      float4 v = *(const float4*)(Ah + (size_t)(m0 + row) * 256 + k0 + k4);
      As[k4 + 0][row] = v.x; As[k4 + 1][row] = v.y;
      As[k4 + 2][row] = v.z; As[k4 + 3][row] = v.w;
    }
    {
      int row = tid >> 4, c4 = (tid & 15) << 2;
      *(float4*)&Bs[row][c4] = *(const float4*)(Bh + (size_t)(k0 + row) * N + n0 + c4);
    }
    __syncthreads();
#pragma unroll
    for (int k = 0; k < 16; ++k) {
      float a[4], b[4];
      *(float4*)a = *(const float4*)&As[k][ty * 4];
      *(float4*)b = *(const float4*)&Bs[k][tx * 4];
#pragma unroll
      for (int i = 0; i < 4; ++i)
#pragma unroll
        for (int j = 0; j < 4; ++j) acc[i][j] = fmaf(a[i], b[j], acc[i][j]);
    }
    __syncthreads();
  }
#pragma unroll
  for (int i = 0; i < 4; ++i) {
    float4 r;
    r.x = alpha * acc[i][0]; r.y = alpha * acc[i][1];
    r.z = alpha * acc[i][2]; r.w = alpha * acc[i][3];
    *(float4*)(Ch + (size_t)(m0 + ty * 4 + i) * N + n0 + tx * 4) = r;
  }
}

// ---------------- a3@v partials via bf16 MFMA flash (no-max exp, ones-column den) ----------
__global__ __launch_bounds__(256) void a3v_mfma(
    const float* __restrict__ qkv, const float* __restrict__ ql,
    float* __restrict__ pacc, float* __restrict__ den)
{
  const int h_ = blockIdx.x;
  const int ch = blockIdx.y;
  const int t  = threadIdx.x;
  const int w  = t >> 6;
  const int l  = t & 63;
  const int lr = l & 15;
  const int lg = l >> 4;

  __shared__ __align__(16) ushort kls[64 * 64];
  __shared__ __align__(16) ushort vls[80 * 64];
  __shared__ __align__(16) ushort pls[4][64 * 64];

  bf16x8 qf[4][2];
#pragma unroll
  for (int rt = 0; rt < 4; ++rt)
#pragma unroll
    for (int dc = 0; dc < 2; ++dc) {
      const float* p = ql + (size_t)(64 * w + rt * 16 + lr) * 512 + h_ * 64 + dc * 32 + lg * 8;
      float4 f0 = *(const float4*)p;
      float4 f1 = *(const float4*)(p + 4);
      bf16x8 v;
      v[0] = f2bf(f0.x); v[1] = f2bf(f0.y); v[2] = f2bf(f0.z); v[3] = f2bf(f0.w);
      v[4] = f2bf(f1.x); v[5] = f2bf(f1.y); v[6] = f2bf(f1.z); v[7] = f2bf(f1.w);
      qf[rt][dc] = v;
    }

  if (t < 128) {
    int rr = t >> 3, cb = t & 7;
    ushort val = (rr == 0) ? (ushort)0x3f80 : (ushort)0;
    bf16x8 vv;
#pragma unroll
    for (int k = 0; k < 8; ++k) vv[k] = (short)val;
    *(bf16x8*)(vls + (64 + rr) * 64 + ((cb ^ (rr & 7)) << 3)) = vv;
  }

  f32x4 acc[4][5];
#pragma unroll
  for (int rt = 0; rt < 4; ++rt)
#pragma unroll
    for (int dt = 0; dt < 5; ++dt) acc[rt][dt] = (f32x4){0.f, 0.f, 0.f, 0.f};

  const int j0base = ch * 256;
  for (int jt = 0; jt < 4; ++jt) {
    const int j0 = j0base + jt * 64;
    __syncthreads();
    {
      int r = t >> 2, db = t & 3;
      const float* src = qkv + (size_t)(j0 + r) * 1536 + 512 + h_ * 64 + db * 16;
      float4 g0 = *(const float4*)(src + 0);
      float4 g1 = *(const float4*)(src + 4);
      float4 g2 = *(const float4*)(src + 8);
      float4 g3 = *(const float4*)(src + 12);
      bf16x8 e0, e1;
      e0[0] = f2bf(g0.x); e0[1] = f2bf(g0.y); e0[2] = f2bf(g0.z); e0[3] = f2bf(g0.w);
      e0[4] = f2bf(g1.x); e0[5] = f2bf(g1.y); e0[6] = f2bf(g1.z); e0[7] = f2bf(g1.w);
      e1[0] = f2bf(g2.x); e1[1] = f2bf(g2.y); e1[2] = f2bf(g2.z); e1[3] = f2bf(g2.w);
      e1[4] = f2bf(g3.x); e1[5] = f2bf(g3.y); e1[6] = f2bf(g3.z); e1[7] = f2bf(g3.w);
      ushort* base = kls + r * 64;
      *(bf16x8*)(base + (((db * 2 + 0) ^ (r & 7)) << 3)) = e0;
      *(bf16x8*)(base + (((db * 2 + 1) ^ (r & 7)) << 3)) = e1;
    }
    {
      int d = t & 63, jg = t >> 6;
#pragma unroll
      for (int half = 0; half < 2; ++half) {
        int jb = jg + half * 4;
        bf16x8 e;
#pragma unroll
        for (int jj = 0; jj < 8; ++jj)
          e[jj] = f2bf(qkv[(size_t)(j0 + jb * 8 + jj) * 1536 + 1024 + h_ * 64 + d]);
        *(bf16x8*)(vls + d * 64 + ((jb ^ (d & 7)) << 3)) = e;
      }
    }
    __syncthreads();

    ushort* pw = pls[w];
#pragma unroll
    for (int sjt = 0; sjt < 4; ++sjt) {
      const int krow = sjt * 16 + lr;
      bf16x8 kf0 = *(const bf16x8*)(kls + krow * 64 + (((0 * 4 + lg) ^ (lr & 7)) << 3));
      bf16x8 kf1 = *(const bf16x8*)(kls + krow * 64 + (((1 * 4 + lg) ^ (lr & 7)) << 3));
#pragma unroll
      for (int rt = 0; rt < 4; ++rt) {
        f32x4 s = (f32x4){0.f, 0.f, 0.f, 0.f};
        s = __builtin_amdgcn_mfma_f32_16x16x32_bf16(qf[rt][0], kf0, s, 0, 0, 0);
        s = __builtin_amdgcn_mfma_f32_16x16x32_bf16(qf[rt][1], kf1, s, 0, 0, 0);
#pragma unroll
        for (int r = 0; r < 4; ++r) {
          int i  = rt * 16 + lg * 4 + r;
          int jj = sjt * 16 + lr;
          pw[i * 64 + ((((jj >> 3) ^ (i & 7)) << 3)) + (jj & 7)] = (short)f2bf(__expf(s[r]));
        }
      }
    }
    bf16x8 pf[4][2];
#pragma unroll
    for (int rt = 0; rt < 4; ++rt)
#pragma unroll
      for (int jc = 0; jc < 2; ++jc)
        pf[rt][jc] = *(const bf16x8*)(pw + (rt * 16 + lr) * 64 + (((jc * 4 + lg) ^ (lr & 7)) << 3));
#pragma unroll
    for (int dt = 0; dt < 5; ++dt) {
      const int vrow = dt * 16 + lr;
      bf16x8 vf0 = *(const bf16x8*)(vls + vrow * 64 + (((0 * 4 + lg) ^ (lr & 7)) << 3));
      bf16x8 vf1 = *(const bf16x8*)(vls + vrow * 64 + (((1 * 4 + lg) ^ (lr & 7)) << 3));
#pragma unroll
      for (int rt = 0; rt < 4; ++rt) {
        acc[rt][dt] = __builtin_amdgcn_mfma_f32_16x16x32_bf16(pf[rt][0], vf0, acc[rt][dt], 0, 0, 0);
        acc[rt][dt] = __builtin_amdgcn_mfma_f32_16x16x32_bf16(pf[rt][1], vf1, acc[rt][dt], 0, 0, 0);
      }
    }
  }

  const size_t pbase = (size_t)(h_ * CHK + ch) * 256;
#pragma unroll
  for (int rt = 0; rt < 4; ++rt) {
    int i = 64 * w + rt * 16 + lg * 4;
#pragma unroll
    for (int dt = 0; dt < 4; ++dt)
#pragma unroll
      for (int r = 0; r < 4; ++r)
        pacc[(pbase + i + r) * 64 + dt * 16 + lr] = acc[rt][dt][r];
    if (lr == 0) {
#pragma unroll
      for (int r = 0; r < 4; ++r)
        den[pbase + i + r] = acc[rt][4][r];
    }
  }
}

// ---------------- merge a3v partials ----------------
__global__ __launch_bounds__(64) void a3v_merge_kernel(
    const float* __restrict__ pacc, const float* __restrict__ den, float* __restrict__ a3v)
{
  int h_ = blockIdx.x, i = blockIdx.y, d = threadIdx.x;
  float S = 0.f, o = 0.f;
  for (int c = 0; c < CHK; ++c) {
    size_t b = (size_t)(h_ * CHK + c) * 256 + i;
    o += pacc[b * 64 + d];
    S += den[b];
  }
  a3v[((size_t)h_ * 256 + i) * 64 + d] = o / S;
}

// ---------------- a1: out = softmax(q . kl^T) @ w2 via bf16 MFMA ----------------
__global__ __launch_bounds__(256) void a1_mfma(
    const float* __restrict__ qkv, const float* __restrict__ kl,
    const float* __restrict__ w2, float* __restrict__ attn)
{
  const int h_ = blockIdx.x;
  const int rb = blockIdx.y;
  const int t  = threadIdx.x;
  const int w  = t >> 6, l = t & 63, lr = l & 15, lg = l >> 4;

  __shared__ __align__(16) ushort kls[64 * 64];
  __shared__ __align__(16) ushort wls[80 * 64];
  __shared__ __align__(16) ushort pls[4][64 * 64];

  bf16x8 qf[4][2];
#pragma unroll
  for (int rt = 0; rt < 4; ++rt)
#pragma unroll
    for (int dc = 0; dc < 2; ++dc) {
      const float* p = qkv + (size_t)(rb * 256 + w * 64 + rt * 16 + lr) * 1536 + h_ * 64 + dc * 32 + lg * 8;
      float4 f0 = *(const float4*)p;
      float4 f1 = *(const float4*)(p + 4);
      bf16x8 v;
      v[0] = f2bf(f0.x); v[1] = f2bf(f0.y); v[2] = f2bf(f0.z); v[3] = f2bf(f0.w);
      v[4] = f2bf(f1.x); v[5] = f2bf(f1.y); v[6] = f2bf(f1.z); v[7] = f2bf(f1.w);
      qf[rt][dc] = v;
    }

  if (t < 128) {
    int rr = t >> 3, cb = t & 7;
    ushort val = (rr == 0) ? (ushort)0x3f80 : (ushort)0;
    bf16x8 vv;
#pragma unroll
    for (int k = 0; k < 8; ++k) vv[k] = (short)val;
    *(bf16x8*)(wls + (64 + rr) * 64 + ((cb ^ (rr & 7)) << 3)) = vv;
  }

  f32x4 acc[4][5];
#pragma unroll
  for (int rt = 0; rt < 4; ++rt)
#pragma unroll
    for (int dt = 0; dt < 5; ++dt) acc[rt][dt] = (f32x4){0.f, 0.f, 0.f, 0.f};

  for (int kc = 0; kc < 4; ++kc) {
    const int j0 = kc * 64;
    __syncthreads();
    {
      int r = t >> 2, db = t & 3;
      const float* src = kl + (size_t)(j0 + r) * 512 + h_ * 64 + db * 16;
      float4 g0 = *(const float4*)(src + 0);
      float4 g1 = *(const float4*)(src + 4);
      float4 g2 = *(const float4*)(src + 8);
      float4 g3 = *(const float4*)(src + 12);
      bf16x8 e0, e1;
      e0[0] = f2bf(g0.x); e0[1] = f2bf(g0.y); e0[2] = f2bf(g0.z); e0[3] = f2bf(g0.w);
      e0[4] = f2bf(g1.x); e0[5] = f2bf(g1.y); e0[6] = f2bf(g1.z); e0[7] = f2bf(g1.w);
      e1[0] = f2bf(g2.x); e1[1] = f2bf(g2.y); e1[2] = f2bf(g2.z); e1[3] = f2bf(g2.w);
      e1[4] = f2bf(g3.x); e1[5] = f2bf(g3.y); e1[6] = f2bf(g3.z); e1[7] = f2bf(g3.w);
      ushort* base = kls + r * 64;
      *(bf16x8*)(base + (((db * 2 + 0) ^ (r & 7)) << 3)) = e0;
      *(bf16x8*)(base + (((db * 2 + 1) ^ (r & 7)) << 3)) = e1;
    }
    {
      int d = t & 63, jg = t >> 6;
#pragma unroll
      for (int half = 0; half < 2; ++half) {
        int jb = jg + half * 4;
        bf16x8 e;
#pragma unroll
        for (int jj = 0; jj < 8; ++jj)
          e[jj] = f2bf(w2[((size_t)h_ * 256 + j0 + jb * 8 + jj) * 64 + d]);
        *(bf16x8*)(wls + d * 64 + ((jb ^ (d & 7)) << 3)) = e;
      }
    }
    __syncthreads();

    ushort* pw = pls[w];
#pragma unroll
    for (int sjt = 0; sjt < 4; ++sjt) {
      const int krow = sjt * 16 + lr;
      bf16x8 kf0 = *(const bf16x8*)(kls + krow * 64 + (((0 * 4 + lg) ^ (lr & 7)) << 3));
      bf16x8 kf1 = *(const bf16x8*)(kls + krow * 64 + (((1 * 4 + lg) ^ (lr & 7)) << 3));
#pragma unroll
      for (int rt = 0; rt < 4; ++rt) {
        f32x4 s = (f32x4){0.f, 0.f, 0.f, 0.f};
        s = __builtin_amdgcn_mfma_f32_16x16x32_bf16(qf[rt][0], kf0, s, 0, 0, 0);
        s = __builtin_amdgcn_mfma_f32_16x16x32_bf16(qf[rt][1], kf1, s, 0, 0, 0);
#pragma unroll
        for (int r = 0; r < 4; ++r) {
          int i  = rt * 16 + lg * 4 + r;
          int jj = sjt * 16 + lr;
          pw[i * 64 + ((((jj >> 3) ^ (i & 7)) << 3)) + (jj & 7)] = (short)f2bf(__expf(s[r]));
        }
      }
    }
    bf16x8 pf[4][2];
#pragma unroll
    for (int rt = 0; rt < 4; ++rt)
#pragma unroll
      for (int jc = 0; jc < 2; ++jc)
        pf[rt][jc] = *(const bf16x8*)(pw + (rt * 16 + lr) * 64 + (((jc * 4 + lg) ^ (lr & 7)) << 3));
#pragma unroll
    for (int dt = 0; dt < 5; ++dt) {
      const int vrow = dt * 16 + lr;
      bf16x8 vf0 = *(const bf16x8*)(wls + vrow * 64 + (((0 * 4 + lg) ^ (lr & 7)) << 3));
      bf16x8 vf1 = *(const bf16x8*)(wls + vrow * 64 + (((1 * 4 + lg) ^ (lr & 7)) << 3));
#pragma unroll
      for (int rt = 0; rt < 4; ++rt) {
        acc[rt][dt] = __builtin_amdgcn_mfma_f32_16x16x32_bf16(pf[rt][0], vf0, acc[rt][dt], 0, 0, 0);
        acc[rt][dt] = __builtin_amdgcn_mfma_f32_16x16x32_bf16(pf[rt][1], vf1, acc[rt][dt], 0, 0, 0);
      }
    }
  }

#pragma unroll
  for (int rt = 0; rt < 4; ++rt) {
#pragma unroll
    for (int r = 0; r < 4; ++r) {
      float dn = __shfl(acc[rt][4][r], l & 48);
      float inv = 1.f / dn;
      int gr = rb * 256 + w * 64 + rt * 16 + lg * 4 + r;
      float* op = attn + (size_t)gr * 512 + h_ * 64;
#pragma unroll
      for (int dt = 0; dt < 4; ++dt)
        op[dt * 16 + lr] = acc[rt][dt][r] * inv;
    }
  }
}

// ---------------- depthwise res conv (kernel 33): register sliding window ----------------
__global__ __launch_bounds__(256) void resconv_kernel(
    const float* __restrict__ qkv, const float* __restrict__ rw, float* __restrict__ attn)
{
  const int bid = blockIdx.x;                 // 0..2047 (2048 % 8 == 0 -> bijective)
  const int rb  = (bid & 7) * 256 + (bid >> 3);
  const int r0  = rb * 8;
  const int c   = blockIdx.y * 256 + threadIdx.x;
  const int h_  = c >> 6;

  float wreg[33];
#pragma unroll
  for (int tp = 0; tp < 33; ++tp) wreg[tp] = rw[h_ * 33 + tp];   // wave-uniform broadcast

  float v[40];
#pragma unroll
  for (int k = 0; k < 40; ++k) {
    int rr = r0 - 16 + k;
    v[k] = (rr >= 0 && rr < NPAD) ? qkv[(size_t)rr * 1536 + 1024 + c] : 0.f;
  }
#pragma unroll
  for (int i = 0; i < 8; ++i) {
    float s = 0.f;
#pragma unroll
    for (int tp = 0; tp < 33; ++tp)
      s = fmaf(v[i + tp], wreg[tp], s);
    attn[(size_t)(r0 + i) * 512 + c] += s;
  }
}

// ---------------- weight transpose for ppeg: wt[k*512+c] ----------------
__global__ __launch_bounds__(256) void wtrans_kernel(
    const float* __restrict__ w7, const float* __restrict__ w5,
    const float* __restrict__ w3, float* __restrict__ wt)
{
  int c = blockIdx.x * 256 + threadIdx.x;
  for (int k = 0; k < 49; ++k) wt[(size_t)k * 512 + c]        = w7[(size_t)c * 49 + k];
  for (int k = 0; k < 25; ++k) wt[(size_t)(49 + k) * 512 + c] = w5[(size_t)c * 25 + k];
  for (int k = 0; k < 9;  ++k) wt[(size_t)(74 + k) * 512 + c] = w3[(size_t)c * 9 + k];
}

// ---------------- PPEG: 64 ch/block, x-sliding window, column prefetch ----------------
__global__ __launch_bounds__(256) void ppeg_kernel(
    const float* __restrict__ h, float* __restrict__ tmp,
    const float* __restrict__ wt,
    const float* __restrict__ b7, const float* __restrict__ b5,
    const float* __restrict__ b3)
{
  __shared__ float wl[83 * 64];            // 21,248 B
  const int t  = threadIdx.x;
  const int tc = t & 63;
  const int xo = (blockIdx.x & 3) * 4 + (t >> 6);   // x-octet 0..15, wave-uniform
  const int y  = blockIdx.x >> 2;                    // 0..126
  const int c  = blockIdx.y * 64 + tc;
  for (int idx = t; idx < 83 * 64; idx += 256)
    wl[idx] = wt[(size_t)(idx >> 6) * 512 + blockIdx.y * 64 + (idx & 63)];
  const float bsum = b7[c] + b5[c] + b3[c];
  __syncthreads();

  const int x0 = xo * 8;
  float acc[8];
#pragma unroll
  for (int i = 0; i < 8; ++i) acc[i] = 0.f;

  float vcur[7];
  {
    int xx = x0 - 3;
    bool okx = (xx >= 0 && xx < SG);
#pragma unroll
    for (int ky = 0; ky < 7; ++ky) {
      int yy = y + ky - 3;
      vcur[ky] = (okx && yy >= 0 && yy < SG)
                   ? h[(size_t)(1 + yy * SG + xx) * DD + c] : 0.f;
    }
  }

#pragma unroll 1
  for (int j = 0; j < 14; ++j) {
    float vnext[7];
    if (j < 13) {                                    // wave-uniform
      int xx = x0 + j - 2;
      bool okx = (xx >= 0 && xx < SG);
#pragma unroll
      for (int ky = 0; ky < 7; ++ky) {
        int yy = y + ky - 3;
        vnext[ky] = (okx && yy >= 0 && yy < SG)
                      ? h[(size_t)(1 + yy * SG + xx) * DD + c] : 0.f;
      }
    }
#pragma unroll
    for (int i = 0; i < 8; ++i) {
      const int k7 = j - i;                          // runtime, but wl is LDS
      if (k7 >= 0 && k7 <= 6) {
        const float* w7p = wl + k7 * 64 + tc;
#pragma unroll
        for (int ky = 0; ky < 7; ++ky)
          acc[i] = fmaf(vcur[ky], w7p[ky * 7 * 64], acc[i]);
      }
      const int k5 = j - i - 1;
      if (k5 >= 0 && k5 <= 4) {
        const float* w5p = wl + (49 + k5) * 64 + tc;
#pragma unroll
        for (int ky = 0; ky < 5; ++ky)
          acc[i] = fmaf(vcur[ky + 1], w5p[ky * 5 * 64], acc[i]);
      }
      const int k3 = j - i - 2;
      if (k3 >= 0 && k3 <= 2) {
        const float* w3p = wl + (74 + k3) * 64 + tc;
#pragma unroll
        for (int ky = 0; ky < 3; ++ky)
          acc[i] = fmaf(vcur[ky + 2], w3p[ky * 3 * 64], acc[i]);
      }
    }
    if (j < 13) {
#pragma unroll
      for (int ky = 0; ky < 7; ++ky) vcur[ky] = vnext[ky];
    }
  }
#pragma unroll
  for (int i = 0; i < 8; ++i) {
    int x = x0 + i;
    if (x < SG) {
      int p = y * SG + x;
      tmp[(size_t)p * DD + c] = h[(size_t)(1 + p) * DD + c] + bsum + acc[i];
    }
  }
}

// ---------------- final: LN(row0) -> fc2 -> softmax/argmax ----------------
__global__ __launch_bounds__(256) void final_kernel(
    const float* __restrict__ h, const float* __restrict__ g, const float* __restrict__ b,
    const float* __restrict__ w, const float* __restrict__ bias, float* __restrict__ out)
{
  __shared__ float red[256];
  int t = threadIdx.x;
  float v0 = h[t], v1 = h[t + 256];
  red[t] = v0 + v1;
  __syncthreads();
  for (int s = 128; s > 0; s >>= 1) { if (t < s) red[t] += red[t + s]; __syncthreads(); }
  float mu = red[0] * (1.f / 512.f);
  __syncthreads();
  float d0 = v0 - mu, d1 = v1 - mu;
  red[t] = d0 * d0 + d1 * d1;
  __syncthreads();
  for (int s = 128; s > 0; s >>= 1) { if (t < s) red[t] += red[t + s]; __syncthreads(); }
  float rs = rsqrtf(red[0] * (1.f / 512.f) + 1e-5f);
  __syncthreads();
  float x0 = d0 * rs * g[t] + b[t];
  float x1 = d1 * rs * g[t + 256] + b[t + 256];
  red[t] = x0 * w[t * 2] + x1 * w[(t + 256) * 2];
  __syncthreads();
  for (int s = 128; s > 0; s >>= 1) { if (t < s) red[t] += red[t + s]; __syncthreads(); }
  float l0 = red[0] + bias[0];
  __syncthreads();
  red[t] = x0 * w[t * 2 + 1] + x1 * w[(t + 256) * 2 + 1];
  __syncthreads();
  for (int s = 128; s > 0; s >>= 1) { if (t < s) red[t] += red[t + s]; __syncthreads(); }
  float l1 = red[0] + bias[1];
  if (t == 0) {
    out[0] = l0; out[1] = l1;
    float mx = fmaxf(l0, l1);
    float e0 = __expf(l0 - mx), e1 = __expf(l1 - mx);
    float inv = 1.f / (e0 + e1);
    out[2] = e0 * inv; out[3] = e1 * inv;
    out[4] = (l1 > l0) ? 1.f : 0.f;
  }
}

extern "C" void kernel_launch(void* const* d_in, const int* in_sizes, int n_in,
                              void* d_out, int out_size, void* d_ws, size_t ws_size,
                              hipStream_t stream)
{
  const float* data   = (const float*)d_in[0];
  const float* fc1_w  = (const float*)d_in[1];
  const float* fc1_b  = (const float*)d_in[2];
  const float* cls    = (const float*)d_in[3];
  const float* l1_g   = (const float*)d_in[4];
  const float* l1_b   = (const float*)d_in[5];
  const float* l1_qkv = (const float*)d_in[6];
  const float* l1_ow  = (const float*)d_in[7];
  const float* l1_ob  = (const float*)d_in[8];
  const float* l1_rw  = (const float*)d_in[9];
  const float* w7     = (const float*)d_in[10];
  const float* b7     = (const float*)d_in[11];
  const float* w5     = (const float*)d_in[12];
  const float* b5     = (const float*)d_in[13];
  const float* w3     = (const float*)d_in[14];
  const float* b3     = (const float*)d_in[15];
  const float* l2_g   = (const float*)d_in[16];
  const float* l2_b   = (const float*)d_in[17];
  const float* l2_qkv = (const float*)d_in[18];
  const float* l2_ow  = (const float*)d_in[19];
  const float* l2_ob  = (const float*)d_in[20];
  const float* l2_rw  = (const float*)d_in[21];
  const float* ng     = (const float*)d_in[22];
  const float* nb     = (const float*)d_in[23];
  const float* fc2_w  = (const float*)d_in[24];
  const float* fc2_b  = (const float*)d_in[25];
  float* out = (float*)d_out;

  float* ws   = (float*)d_ws;
  float* h    = ws;
  float* xn   = h    + (size_t)16384 * 512;
  float* qkv  = xn   + (size_t)16384 * 512;
  float* attn = qkv  + (size_t)16384 * 1536;
  float* ql   = attn + (size_t)16384 * 512;
  float* kl   = ql   + 256 * 512;
  float* a2b  = kl   + 256 * 512;
  float* z0   = a2b  + 8 * 256 * 256;
  float* z1   = z0   + 8 * 256 * 256;
  float* xzb  = z1   + 8 * 256 * 256;   // (unused this round; kept for layout stability)
  float* tb   = xzb  + 8 * 256 * 256;
  float* ub   = tb   + 8 * 256 * 256;
  float* a3v  = ub   + 8 * 256 * 256;
  float* w2   = a3v  + 8 * 256 * 64;
  float* pacc = w2   + 8 * 256 * 64;           // dead region: 4,194,304 floats (16 MiB)
  float* pms  = pacc + (size_t)8 * 32 * 256 * 64;
  float* red  = pms  + (size_t)8 * 32 * 256 * 2;
  float* wtb  = red  + 32;                       // ppeg weights fp32 (83*512)

  // bf16 transposed weights at start of pacc region: 2.62M ushorts = 1.31M floats
  ushort* fc1_wt  = (ushort*)pacc;
  ushort* qkv_wt0 = fc1_wt + 512 * 1024;
  ushort* qkv_wt1 = qkv_wt0 + 1536 * 512;
  ushort* out_wt0 = qkv_wt1 + 1536 * 512;
  ushort* out_wt1 = out_wt0 + 512 * 512;

  // Y-recurrence buffers in the free tail of the pacc region (after weights)
  float* yb0 = pacc + 1310720;                 // 2.62M ushorts = 1,310,720 floats used
  float* yb1 = yb0 + 8 * 256 * 256;            // ends at 2,359,296 < 4,194,304 ok

  // bf16 activations: xn region as bf16 LN output; data bf16 in qkv region
  ushort* xnb    = (ushort*)xn;
  ushort* databf = (ushort*)qkv;

  // a3v MFMA partial buffers (alias xn scratch / pms)
  float* a3v_pacc = xn;
  float* a3v_den  = pms;

  // weight prep (bf16 transposes) + data cvt + fc1 + assemble
  wtrans_bf<<<dim3(16, 32), 256, 0, stream>>>(fc1_w, fc1_wt, 1024, 512);
  wtrans_bf<<<dim3(48, 16), 256, 0, stream>>>(l1_qkv, qkv_wt0, 512, 1536);
  wtrans_bf<<<dim3(48, 16), 256, 0, stream>>>(l2_qkv, qkv_wt1, 512, 1536);
  wtrans_bf<<<dim3(16, 16), 256, 0, stream>>>(l1_ow, out_wt0, 512, 512);
  wtrans_bf<<<dim3(16, 16), 256, 0, stream>>>(l2_ow, out_wt1, 512, 512);
  wtrans_kernel<<<2, 256, 0, stream>>>(w7, w5, w3, wtb);
  cvt_bf_kernel<<<8000, 256, 0, stream>>>(data, databf, 16000 * 1024);

  gemm_bb<<<dim3(4, 125), 256, 0, stream>>>(databf, 1024, fc1_wt, 1024, h + 512, 512,
                                            16000, 1024, 1, fc1_b);
  assemble_kernel<<<260, 256, 0, stream>>>(h, cls);

  for (int layer = 0; layer < 2; ++layer) {
    const float* gg = layer ? l2_g   : l1_g;
    const float* bb = layer ? l2_b   : l1_b;
    const ushort* qw = layer ? qkv_wt1 : qkv_wt0;
    const ushort* ow = layer ? out_wt1 : out_wt0;
    const float* ob = layer ? l2_ob  : l1_ob;
    const float* rw = layer ? l2_rw  : l1_rw;

    ln_pad_kernel<<<16384, 256, 0, stream>>>(h, xnb, gg, bb);
    gemm_bb<<<dim3(12, 128), 256, 0, stream>>>(xnb, 512, qw, 512, qkv, 1536,
                                               16384, 512, 2, nullptr);
    landmark_kernel<<<dim3(256, 4), 256, 0, stream>>>(qkv, ql, kl);
    a2_kernel<<<dim3(8, 256), 256, 0, stream>>>(ql, kl, a2b);
    pinv_red1<<<8, 256, 0, stream>>>(a2b, red);
    pinv_seed<<<dim3(4, 4, 8), 256, 0, stream>>>(a2b, red, z0, yb0);  // z0 + Y0
    float* zc = z0; float* zn = z1; float* yc = yb0; float* yn = yb1;
    for (int it = 0; it < 6; ++it) {
      nmm_A<<<dim3(4, 4, 16), 256, 0, stream>>>(zc, yc, ub, tb);           // U=z@Y ; Y2=Y@Y
      nmm_B<<<dim3(4, 4, 16), 256, 0, stream>>>(zc, yc, ub, tb, zn, yn);   // z',Y'
      float* s = zc; zc = zn; zn = s;
      s = yc; yc = yn; yn = s;
    }
    a3v_mfma<<<dim3(8, CHK), 256, 0, stream>>>(qkv, ql, a3v_pacc, a3v_den);
    a3v_merge_kernel<<<dim3(8, 256), 64, 0, stream>>>(a3v_pacc, a3v_den, a3v);
    mmb_kernel<<<dim3(1, 4, 8), 256, 0, stream>>>(zc, a3v, w2, 64, 1.f);
    a1_mfma<<<dim3(8, 64), 256, 0, stream>>>(qkv, kl, w2, attn);
    resconv_kernel<<<dim3(2048, 2), 256, 0, stream>>>(qkv, rw, attn);
    gemm_bt<<<dim3(4, 127), 256, 0, stream>>>(attn + (size_t)254 * 512, 512, ow, 512,
                                              h, 512, 16130, 512, 3, ob);
    if (layer == 0) {
      // ppeg -> qkv scratch (dead until layer-1 recomputes it), memcpy back
      ppeg_kernel<<<dim3(127 * 4, 8), 256, 0, stream>>>(h, qkv, wtb, b7, b5, b3);
      hipMemcpyAsync(h + 512, qkv, (size_t)16129 * 512 * 4,
                     hipMemcpyDeviceToDevice, stream);
    }
  }
  final_kernel<<<1, 256, 0, stream>>>(h, ng, nb, fc2_w, fc2_b, out);
}